// Round 1
// baseline (1722.273 us; speedup 1.0000x reference)
//
#include <hip/hip_runtime.h>
#include <hip/hip_bf16.h>
#include <math.h>

#define NFR 128
#define IND 256
#define ONODES 512

static constexpr float SM_SCALE = 0.08838834764831845f; // 128^-0.5

__device__ __forceinline__ unsigned short f2bf(float f){
    unsigned int b = __float_as_uint(f);
    b = (b + 0x7fffu + ((b >> 16) & 1u)) >> 16;
    return (unsigned short)b;
}
__device__ __forceinline__ float bf2f(unsigned short u){
    return __uint_as_float(((unsigned int)u) << 16);
}

// ---------------- G[m] = W_m * W_m^T (256x256). m<128: w1 (K=256); else w2 (K=512)
__global__ __launch_bounds__(256) void kG(const float* __restrict__ w1, const float* __restrict__ w2,
                                          float* __restrict__ G){
    int wg = blockIdx.x;
    int m = wg >> 4, tile = wg & 15;
    int tr = (tile >> 2) * 64, tc = (tile & 3) * 64;
    const float* W; int K;
    if (m < NFR){ W = w1 + (size_t)m * IND * IND; K = IND; }
    else        { W = w2 + (size_t)(m - NFR) * IND * ONODES; K = ONODES; }
    __shared__ float Al[32][68];
    __shared__ float Bl[32][68];
    int t = threadIdx.x;
    int tx = t & 15, ty = t >> 4;
    float acc[4][4] = {};
    for (int k0 = 0; k0 < K; k0 += 32){
        #pragma unroll
        for (int p = 0; p < 8; ++p){
            int i = t + p * 256;
            int r = i >> 5, kk = i & 31;
            Al[kk][r] = W[(size_t)(tr + r) * K + k0 + kk];
            Bl[kk][r] = W[(size_t)(tc + r) * K + k0 + kk];
        }
        __syncthreads();
        #pragma unroll
        for (int kk = 0; kk < 32; ++kk){
            float4 a = *(const float4*)&Al[kk][ty * 4];
            float4 b = *(const float4*)&Bl[kk][tx * 4];
            float av[4] = {a.x, a.y, a.z, a.w};
            float bv[4] = {b.x, b.y, b.z, b.w};
            #pragma unroll
            for (int i = 0; i < 4; ++i)
                #pragma unroll
                for (int j = 0; j < 4; ++j) acc[i][j] += av[i] * bv[j];
        }
        __syncthreads();
    }
    float* go = G + (size_t)m * 65536;
    #pragma unroll
    for (int i = 0; i < 4; ++i){
        *(float4*)&go[(size_t)(tr + ty * 4 + i) * 256 + tc + tx * 4] =
            make_float4(acc[i][0], acc[i][1], acc[i][2], acc[i][3]);
    }
}

// ---------------- power iteration on G (bf16 in LDS) + Rayleigh vs fp32 W
__global__ __launch_bounds__(256) void kP(const float* __restrict__ w1, const float* __restrict__ w2,
                                          const float* __restrict__ G, float* __restrict__ inv_s){
    extern __shared__ char smem[];
    unsigned short* Gl = (unsigned short*)smem;            // 65536 ushorts = 131072 B
    float* yred = (float*)(smem + 131072);                 // 1024 floats
    float* xv   = yred + 1024;                             // 256 floats
    float* red  = xv + 256;                                // 16 floats
    int m = blockIdx.x, t = threadIdx.x;
    const float* Gm = G + (size_t)m * 65536;
    for (int i = t; i < 65536; i += 256) Gl[i] = f2bf(Gm[i]);
    {
        unsigned int h = (unsigned int)t * 2654435761u ^ 0x9e3779b9u;
        h ^= h >> 13; h *= 0x85ebca6bu; h ^= h >> 16;
        xv[t] = 0.5f + (float)(h & 0xffffu) * (1.0f / 65536.0f);
    }
    __syncthreads();
    int rid = t & 63, jq = t >> 6;
    int base_j = jq * 64;
    for (int it = 0; it < 128; ++it){
        float a0 = 0.f, a1 = 0.f, a2 = 0.f, a3 = 0.f;
        for (int j = base_j; j < base_j + 64; ++j){
            float xb = xv[j];
            uint2 g = *(const uint2*)&Gl[(size_t)j * 256 + 4 * rid];
            a0 += bf2f((unsigned short)(g.x & 0xffffu)) * xb;
            a1 += bf2f((unsigned short)(g.x >> 16)) * xb;
            a2 += bf2f((unsigned short)(g.y & 0xffffu)) * xb;
            a3 += bf2f((unsigned short)(g.y >> 16)) * xb;
        }
        *(float4*)&yred[jq * 256 + 4 * rid] = make_float4(a0, a1, a2, a3);
        __syncthreads();
        float yv = yred[t] + yred[256 + t] + yred[512 + t] + yred[768 + t];
        float ss = yv * yv;
        #pragma unroll
        for (int off = 32; off; off >>= 1) ss += __shfl_xor(ss, off);
        if ((t & 63) == 0) red[t >> 6] = ss;
        __syncthreads();
        ss = red[0] + red[1] + red[2] + red[3];
        float rs = rsqrtf(ss);
        __syncthreads();
        xv[t] = yv * rs;
        __syncthreads();
    }
    const float* W; int K;
    if (m < NFR){ W = w1 + (size_t)m * IND * IND; K = IND; }
    else        { W = w2 + (size_t)(m - NFR) * IND * ONODES; K = ONODES; }
    float zsq = 0.f;
    for (int o = t; o < K; o += 256){
        float z = 0.f;
        for (int d = 0; d < 256; ++d) z += W[(size_t)d * K + o] * xv[d];
        zsq += z * z;
    }
    #pragma unroll
    for (int off = 32; off; off >>= 1) zsq += __shfl_xor(zsq, off);
    if ((t & 63) == 0) red[4 + (t >> 6)] = zsq;
    __syncthreads();
    if (t == 0){
        float rho = red[4] + red[5] + red[6] + red[7];
        float sg = sqrtf(fmaxf(rho, 0.f));
        inv_s[m] = 1.0f / fmaxf(sg, 1e-6f);
    }
}

// ---------------- per-frame MLP, writes node_features transposed [b][node][frame]
__global__ __launch_bounds__(256) void kMLP(const float* __restrict__ inp, const float* __restrict__ w1,
                                            const float* __restrict__ b1, const float* __restrict__ w2,
                                            const float* __restrict__ b2, const float* __restrict__ inv_s,
                                            float* __restrict__ nf){
    int n = blockIdx.x, t = threadIdx.x;
    __shared__ float xl[16][IND];
    __shared__ float hl[16][IND];
    float i1 = inv_s[n], i2 = inv_s[NFR + n];
    for (int i = t; i < 16 * IND; i += 256){
        int b = i >> 8, d = i & 255;
        xl[b][d] = inp[(size_t)b * (NFR * IND) + (size_t)n * IND + d];
    }
    __syncthreads();
    const float* W1 = w1 + (size_t)n * IND * IND;
    float acc[16] = {};
    for (int d = 0; d < IND; ++d){
        float w = W1[(size_t)d * IND + t];
        #pragma unroll
        for (int b = 0; b < 16; ++b) acc[b] += xl[b][d] * w;
    }
    float bb = b1[(size_t)n * IND + t];
    #pragma unroll
    for (int b = 0; b < 16; ++b){
        float h = acc[b] * i1 + bb;
        h = 0.5f * h * (1.0f + erff(h * 0.70710678118654752f));
        hl[b][t] = h;
    }
    __syncthreads();
    const float* W2 = w2 + (size_t)n * IND * ONODES;
    float o0[16] = {}, o1[16] = {};
    for (int d = 0; d < IND; ++d){
        float wa = W2[(size_t)d * ONODES + t];
        float wb = W2[(size_t)d * ONODES + t + 256];
        #pragma unroll
        for (int b = 0; b < 16; ++b){ float h = hl[b][d]; o0[b] += h * wa; o1[b] += h * wb; }
    }
    float bb0 = b2[(size_t)n * ONODES + t], bb1 = b2[(size_t)n * ONODES + t + 256];
    #pragma unroll
    for (int b = 0; b < 16; ++b){
        nf[(size_t)b * (ONODES * NFR) + (size_t)t * NFR + n]         = o0[b] * i2 + bb0;
        nf[(size_t)b * (ONODES * NFR) + (size_t)(t + 256) * NFR + n] = o1[b] * i2 + bb1;
    }
}

// ---------------- qk projection: q/k [b][c][node][f]
__global__ __launch_bounds__(256) void kQK(const float* __restrict__ nf, const float* __restrict__ wqk,
                                           float* __restrict__ qb, float* __restrict__ kb){
    int b = blockIdx.x, nb = blockIdx.y, t = threadIdx.x;
    __shared__ float xs[32][132];
    __shared__ float wl[128][68];
    for (int i = t; i < 32 * 128; i += 256){
        int r = i >> 7, f = i & 127;
        xs[r][f] = nf[(size_t)b * 65536 + (size_t)(nb * 32 + r) * 128 + f];
    }
    int r = t >> 3, g = t & 7;
    for (int jt = 0; jt < 32; ++jt){
        __syncthreads();
        for (int i = t; i < 64 * 128; i += 256){
            int f = i >> 6, jl = i & 63;
            wl[f][jl] = wqk[(size_t)f * 2048 + jt * 64 + jl];
        }
        __syncthreads();
        float acc[8] = {};
        for (int f = 0; f < 128; ++f){
            float xvv = xs[r][f];
            float4 w0 = *(const float4*)&wl[f][g * 8];
            float4 w1v = *(const float4*)&wl[f][g * 8 + 4];
            acc[0] += xvv * w0.x; acc[1] += xvv * w0.y; acc[2] += xvv * w0.z; acc[3] += xvv * w0.w;
            acc[4] += xvv * w1v.x; acc[5] += xvv * w1v.y; acc[6] += xvv * w1v.z; acc[7] += xvv * w1v.w;
        }
        int j0 = jt * 64 + g * 8;
        int s = j0 >> 10, c = (j0 >> 7) & 7, fc = j0 & 127;
        float* dst = (s ? kb : qb) + ((size_t)(b * 8 + c) * 512 + nb * 32 + r) * 128 + fc;
        *(float4*)dst = make_float4(acc[0], acc[1], acc[2], acc[3]);
        *(float4*)(dst + 4) = make_float4(acc[4], acc[5], acc[6], acc[7]);
    }
}

// ---------------- scores + softmax -> attn [b][c][n][m]
__global__ __launch_bounds__(256) void kS(const float* __restrict__ qb, const float* __restrict__ kb,
                                          float* __restrict__ attn){
    int b = blockIdx.x, c = blockIdx.y, nb = blockIdx.z, t = threadIdx.x;
    __shared__ float ql[32][132];
    __shared__ float kl[128][68]; // kl[f][mr]
    size_t bc = (size_t)(b * 8 + c) * 512;
    for (int i = t; i < 32 * 128; i += 256){
        int r = i >> 7, f = i & 127;
        ql[r][f] = qb[(bc + nb * 32 + r) * 128 + f];
    }
    int r = t >> 3, g = t & 7;
    float sreg[8][8];
    #pragma unroll
    for (int mt = 0; mt < 8; ++mt){
        __syncthreads();
        for (int i = t; i < 64 * 128; i += 256){
            int mr = i >> 7, f = i & 127;
            kl[f][mr] = kb[(bc + mt * 64 + mr) * 128 + f];
        }
        __syncthreads();
        float acc[8] = {};
        for (int f = 0; f < 128; ++f){
            float qv = ql[r][f];
            float4 k0 = *(const float4*)&kl[f][g * 8];
            float4 k1 = *(const float4*)&kl[f][g * 8 + 4];
            acc[0] += qv * k0.x; acc[1] += qv * k0.y; acc[2] += qv * k0.z; acc[3] += qv * k0.w;
            acc[4] += qv * k1.x; acc[5] += qv * k1.y; acc[6] += qv * k1.z; acc[7] += qv * k1.w;
        }
        #pragma unroll
        for (int q = 0; q < 8; ++q) sreg[mt][q] = acc[q];
    }
    float mx = -1e30f;
    #pragma unroll
    for (int mt = 0; mt < 8; ++mt)
        #pragma unroll
        for (int q = 0; q < 8; ++q) mx = fmaxf(mx, sreg[mt][q]);
    mx = fmaxf(mx, __shfl_xor(mx, 1));
    mx = fmaxf(mx, __shfl_xor(mx, 2));
    mx = fmaxf(mx, __shfl_xor(mx, 4));
    float em = mx * SM_SCALE;
    float sum = 0.f;
    #pragma unroll
    for (int mt = 0; mt < 8; ++mt)
        #pragma unroll
        for (int q = 0; q < 8; ++q){
            float p = __expf(sreg[mt][q] * SM_SCALE - em);
            sreg[mt][q] = p;
            sum += p;
        }
    sum += __shfl_xor(sum, 1);
    sum += __shfl_xor(sum, 2);
    sum += __shfl_xor(sum, 4);
    float inv = 1.0f / sum;
    size_t rowb = (bc + nb * 32 + r) * 512;
    #pragma unroll
    for (int mt = 0; mt < 8; ++mt){
        *(float4*)&attn[rowb + mt * 64 + g * 8] =
            make_float4(sreg[mt][0] * inv, sreg[mt][1] * inv, sreg[mt][2] * inv, sreg[mt][3] * inv);
        *(float4*)&attn[rowb + mt * 64 + g * 8 + 4] =
            make_float4(sreg[mt][4] * inv, sreg[mt][5] * inv, sreg[mt][6] * inv, sreg[mt][7] * inv);
    }
}

// ---------------- top-32 (of channel-sum) per (b,n) row -> bitmask, + diagonal
__global__ __launch_bounds__(256) void kT(const float* __restrict__ attn, unsigned long long* __restrict__ mask){
    int wid = threadIdx.x >> 6, lane = threadIdx.x & 63;
    int row = blockIdx.x * 4 + wid;
    int b = row >> 9, n = row & 511;
    float v[8];
    #pragma unroll
    for (int j = 0; j < 8; ++j){
        float s = 0.f;
        #pragma unroll
        for (int c = 0; c < 8; ++c)
            s += attn[((size_t)(b * 8 + c) * 512 + n) * 512 + j * 64 + lane];
        v[j] = s;
    }
    unsigned int chosen = 0;
    for (int iter = 0; iter < 32; ++iter){
        float bv = -1e30f; int bm = 0x7fffffff;
        #pragma unroll
        for (int j = 0; j < 8; ++j){
            int mm = j * 64 + lane;
            if (v[j] > bv){ bv = v[j]; bm = mm; }
        }
        #pragma unroll
        for (int off = 1; off < 64; off <<= 1){
            float ov = __shfl_xor(bv, off);
            int om = __shfl_xor(bm, off);
            if (ov > bv || (ov == bv && om < bm)){ bv = ov; bm = om; }
        }
        if (lane == (bm & 63)){
            int jj = bm >> 6;
            #pragma unroll
            for (int j = 0; j < 8; ++j) if (j == jj) v[j] = -1e30f;
            chosen |= 1u << jj;
        }
    }
    #pragma unroll
    for (int j = 0; j < 8; ++j){
        unsigned long long bm64 = __ballot((chosen >> j) & 1u);
        if (lane == j){
            if ((n >> 6) == j) bm64 |= 1ull << (n & 63);
            mask[((size_t)b * 512 + n) * 8 + j] = bm64;
        }
    }
}

// ---------------- row-normalize masked attn in place
__global__ __launch_bounds__(256) void kN(float* __restrict__ attn, const unsigned long long* __restrict__ mask){
    int wid = threadIdx.x >> 6, lane = threadIdx.x & 63;
    int row = blockIdx.x * 4 + wid; // 0..65535
    int b = row >> 12, c = (row >> 9) & 7, n = row & 511;
    size_t base = ((size_t)(b * 8 + c) * 512 + n) * 512;
    const unsigned long long* mrow = mask + ((size_t)b * 512 + n) * 8;
    float e[8]; float rs = 0.f;
    #pragma unroll
    for (int j = 0; j < 8; ++j){
        float a = attn[base + j * 64 + lane];
        bool keep = (mrow[j] >> lane) & 1ull;
        e[j] = keep ? a : 0.0f;
        rs += e[j];
    }
    #pragma unroll
    for (int off = 1; off < 64; off <<= 1) rs += __shfl_xor(rs, off);
    float inv = 1.0f / (rs + 1e-6f);
    #pragma unroll
    for (int j = 0; j < 8; ++j) attn[base + j * 64 + lane] = e[j] * inv;
}

// ---------------- column sums of norm_row
__global__ __launch_bounds__(256) void kC(const float* __restrict__ attn, float* __restrict__ cs){
    int b = blockIdx.x, c = blockIdx.y, mb = blockIdx.z, t = threadIdx.x;
    int m = mb * 64 + (t & 63), ch = t >> 6;
    size_t base = (size_t)(b * 8 + c) * 512 * 512;
    float s = 0.f;
    for (int n = ch * 128; n < ch * 128 + 128; ++n)
        s += attn[base + (size_t)n * 512 + m];
    __shared__ float red[4][64];
    red[ch][t & 63] = s;
    __syncthreads();
    if (t < 64){
        float tot = red[0][t] + red[1][t] + red[2][t] + red[3][t];
        cs[(size_t)(b * 8 + c) * 512 + mb * 64 + t] = tot;
    }
}

// ---------------- out = (NR * D) * NR^T, D = 1/(colsum+1e-6). 128x128 tiles.
__global__ __launch_bounds__(256) void kF(const float* __restrict__ nr, const float* __restrict__ cs,
                                          float* __restrict__ oe){
    int b = blockIdx.x, c = blockIdx.y, tz = blockIdx.z;
    int tr = (tz >> 2) * 128, tc = (tz & 3) * 128;
    size_t mb = (size_t)(b * 8 + c) * 512;
    const float* M = nr + mb * 512;
    __shared__ float dl[512];
    __shared__ float Al[32][132];
    __shared__ float Bl[32][132];
    int t = threadIdx.x;
    for (int i = t; i < 512; i += 256){ float v = cs[mb + i]; dl[i] = 1.0f / (v + 1e-6f); }
    __syncthreads();
    int tx = t & 15, ty = t >> 4;
    float acc[8][8] = {};
    for (int k0 = 0; k0 < 512; k0 += 32){
        #pragma unroll
        for (int p = 0; p < 16; ++p){
            int i = t + p * 256;
            int r = i >> 5, kk = i & 31;
            Al[kk][r] = M[(size_t)(tr + r) * 512 + k0 + kk] * dl[k0 + kk];
            Bl[kk][r] = M[(size_t)(tc + r) * 512 + k0 + kk];
        }
        __syncthreads();
        #pragma unroll
        for (int kk = 0; kk < 32; ++kk){
            float4 a0 = *(const float4*)&Al[kk][ty * 4];
            float4 a1 = *(const float4*)&Al[kk][64 + ty * 4];
            float4 b0 = *(const float4*)&Bl[kk][tx * 4];
            float4 b1 = *(const float4*)&Bl[kk][64 + tx * 4];
            float av[8] = {a0.x, a0.y, a0.z, a0.w, a1.x, a1.y, a1.z, a1.w};
            float bv[8] = {b0.x, b0.y, b0.z, b0.w, b1.x, b1.y, b1.z, b1.w};
            #pragma unroll
            for (int i = 0; i < 8; ++i)
                #pragma unroll
                for (int j = 0; j < 8; ++j) acc[i][j] += av[i] * bv[j];
        }
        __syncthreads();
    }
    #pragma unroll
    for (int i = 0; i < 8; ++i){
        int rr = tr + ((i < 4) ? (ty * 4 + i) : (64 + ty * 4 + (i - 4)));
        float* orow = oe + (mb + rr) * 512;
        *(float4*)&orow[tc + tx * 4]      = make_float4(acc[i][0], acc[i][1], acc[i][2], acc[i][3]);
        *(float4*)&orow[tc + 64 + tx * 4] = make_float4(acc[i][4], acc[i][5], acc[i][6], acc[i][7]);
    }
}

extern "C" void kernel_launch(void* const* d_in, const int* in_sizes, int n_in,
                              void* d_out, int out_size, void* d_ws, size_t ws_size,
                              hipStream_t stream) {
    const float* inp = (const float*)d_in[0];
    const float* w1  = (const float*)d_in[1];
    const float* b1  = (const float*)d_in[2];
    const float* w2  = (const float*)d_in[3];
    const float* b2  = (const float*)d_in[4];
    const float* wqk = (const float*)d_in[5];

    float* out_nf   = (float*)d_out;                       // [16][512][128]
    float* out_edge = out_nf + (size_t)16 * 512 * 128;     // [16][8][512][512]

    char* ws = (char*)d_ws;
    float* inv_s = (float*)ws;                             // 256 floats
    float* q_buf = (float*)(ws + 4096);                    // [16][8][512][128]
    float* k_buf = q_buf + (size_t)16 * 8 * 512 * 128;
    float* attn  = k_buf + (size_t)16 * 8 * 512 * 128;     // [16][8][512][512]
    float* Gbuf  = attn;                                   // alias: G used before attn written
    float* csum  = attn + (size_t)16 * 8 * 512 * 512;      // [16][8][512]
    unsigned long long* mask = (unsigned long long*)(csum + (size_t)16 * 8 * 512); // [16][512][8]

    kG  <<<4096, 256, 0, stream>>>(w1, w2, Gbuf);
    kP  <<<256, 256, 136256, stream>>>(w1, w2, Gbuf, inv_s);
    kMLP<<<128, 256, 0, stream>>>(inp, w1, b1, w2, b2, inv_s, out_nf);
    kQK <<<dim3(16, 16), 256, 0, stream>>>(out_nf, wqk, q_buf, k_buf);
    kS  <<<dim3(16, 8, 16), 256, 0, stream>>>(q_buf, k_buf, attn);
    kT  <<<2048, 256, 0, stream>>>(attn, mask);
    kN  <<<16384, 256, 0, stream>>>(attn, mask);
    kC  <<<dim3(16, 8, 8), 256, 0, stream>>>(attn, csum);
    kF  <<<dim3(16, 8, 16), 256, 0, stream>>>(attn, csum, out_edge);
}

// Round 2
// 1212.193 us; speedup vs baseline: 1.4208x; 1.4208x over previous
//
#include <hip/hip_runtime.h>
#include <hip/hip_bf16.h>
#include <math.h>

#define NFR 128
#define IND 256
#define ONODES 512

static constexpr float SM_SCALE = 0.08838834764831845f; // 128^-0.5

typedef __attribute__((ext_vector_type(8))) short bf16x8;
typedef __attribute__((ext_vector_type(4))) float f32x4;
typedef __attribute__((ext_vector_type(8))) unsigned short ushort8;

__device__ __forceinline__ unsigned short f2bf(float f){
    unsigned int b = __float_as_uint(f);
    b = (b + 0x7fffu + ((b >> 16) & 1u)) >> 16;
    return (unsigned short)b;
}
__device__ __forceinline__ float bf2f(unsigned short u){
    return __uint_as_float(((unsigned int)u) << 16);
}

// ---------------- G[m] = W_m * W_m^T (256x256) via bf16 MFMA; fp32 output.
// One block (512 thr, 8 waves) per matrix. Shared W tile is both A and B operand.
__global__ __launch_bounds__(512) void kG(const float* __restrict__ w1, const float* __restrict__ w2,
                                          float* __restrict__ G){
    int m = blockIdx.x;
    const float* W; int K;
    if (m < NFR){ W = w1 + (size_t)m * IND * IND; K = IND; }
    else        { W = w2 + (size_t)(m - NFR) * IND * ONODES; K = ONODES; }
    __shared__ unsigned short Wt[256 * 64]; // rows x 64 k, bf16, granule-swizzled
    int t = threadIdx.x;
    int w = t >> 6, l = t & 63;
    int wr = (w >> 2) * 128, wc = (w & 3) * 64;
    f32x4 acc[8][4] = {};
    int srow = t >> 3, sg = t & 7;
    for (int kb = 0; kb < K; kb += 64){
        __syncthreads();
        #pragma unroll
        for (int i = 0; i < 4; ++i){
            int row = i * 64 + srow;
            int dstg = sg ^ (row & 7);
            const float* src = &W[(size_t)row * K + kb + sg * 8];
            float4 f0 = *(const float4*)src;
            float4 f1 = *(const float4*)(src + 4);
            ushort8 v;
            v[0] = f2bf(f0.x); v[1] = f2bf(f0.y); v[2] = f2bf(f0.z); v[3] = f2bf(f0.w);
            v[4] = f2bf(f1.x); v[5] = f2bf(f1.y); v[6] = f2bf(f1.z); v[7] = f2bf(f1.w);
            *(ushort8*)&Wt[row * 64 + dstg * 8] = v;
        }
        __syncthreads();
        #pragma unroll
        for (int kh = 0; kh < 2; ++kh){
            bf16x8 af[8], bfr[4];
            #pragma unroll
            for (int fi = 0; fi < 8; ++fi){
                int row = wr + fi * 16 + (l & 15);
                int g = (kh * 4 + (l >> 4)) ^ (row & 7);
                af[fi] = *(const bf16x8*)&Wt[row * 64 + g * 8];
            }
            #pragma unroll
            for (int fj = 0; fj < 4; ++fj){
                int row = wc + fj * 16 + (l & 15);
                int g = (kh * 4 + (l >> 4)) ^ (row & 7);
                bfr[fj] = *(const bf16x8*)&Wt[row * 64 + g * 8];
            }
            #pragma unroll
            for (int fi = 0; fi < 8; ++fi)
                #pragma unroll
                for (int fj = 0; fj < 4; ++fj)
                    acc[fi][fj] = __builtin_amdgcn_mfma_f32_16x16x32_bf16(af[fi], bfr[fj], acc[fi][fj], 0, 0, 0);
        }
    }
    float* Gm = G + (size_t)m * 65536;
    #pragma unroll
    for (int fi = 0; fi < 8; ++fi){
        #pragma unroll
        for (int r = 0; r < 4; ++r){
            int n = wr + fi * 16 + (l >> 4) * 4 + r;
            float* grow = Gm + (size_t)n * 256 + wc + (l & 15);
            #pragma unroll
            for (int fj = 0; fj < 4; ++fj) grow[fj * 16] = acc[fi][fj][r];
        }
    }
}

// ---------------- power iteration on G (bf16 in LDS) + Rayleigh vs fp32 W
__global__ __launch_bounds__(256) void kP(const float* __restrict__ w1, const float* __restrict__ w2,
                                          const float* __restrict__ G, float* __restrict__ inv_s){
    extern __shared__ char smem[];
    unsigned short* Gl = (unsigned short*)smem;            // 65536 ushorts = 131072 B
    float* yred = (float*)(smem + 131072);                 // 1024 floats
    float* xv   = yred + 1024;                             // 256 floats
    float* red  = xv + 256;                                // 16 floats
    int m = blockIdx.x, t = threadIdx.x;
    const float* Gm = G + (size_t)m * 65536;
    for (int i = t; i < 65536; i += 256) Gl[i] = f2bf(Gm[i]);
    {
        unsigned int h = (unsigned int)t * 2654435761u ^ 0x9e3779b9u;
        h ^= h >> 13; h *= 0x85ebca6bu; h ^= h >> 16;
        xv[t] = 0.5f + (float)(h & 0xffffu) * (1.0f / 65536.0f);
    }
    __syncthreads();
    int rid = t & 63, jq = t >> 6;
    int base_j = jq * 64;
    for (int it = 0; it < 128; ++it){
        float a0 = 0.f, a1 = 0.f, a2 = 0.f, a3 = 0.f;
        for (int j = base_j; j < base_j + 64; ++j){
            float xb = xv[j];
            uint2 g = *(const uint2*)&Gl[(size_t)j * 256 + 4 * rid];
            a0 += bf2f((unsigned short)(g.x & 0xffffu)) * xb;
            a1 += bf2f((unsigned short)(g.x >> 16)) * xb;
            a2 += bf2f((unsigned short)(g.y & 0xffffu)) * xb;
            a3 += bf2f((unsigned short)(g.y >> 16)) * xb;
        }
        *(float4*)&yred[jq * 256 + 4 * rid] = make_float4(a0, a1, a2, a3);
        __syncthreads();
        float yv = yred[t] + yred[256 + t] + yred[512 + t] + yred[768 + t];
        float ss = yv * yv;
        #pragma unroll
        for (int off = 32; off; off >>= 1) ss += __shfl_xor(ss, off);
        if ((t & 63) == 0) red[t >> 6] = ss;
        __syncthreads();
        ss = red[0] + red[1] + red[2] + red[3];
        float rs = rsqrtf(ss);
        __syncthreads();
        xv[t] = yv * rs;
        __syncthreads();
    }
    const float* W; int K;
    if (m < NFR){ W = w1 + (size_t)m * IND * IND; K = IND; }
    else        { W = w2 + (size_t)(m - NFR) * IND * ONODES; K = ONODES; }
    float zsq = 0.f;
    for (int o = t; o < K; o += 256){
        float z = 0.f;
        for (int d = 0; d < 256; ++d) z += W[(size_t)d * K + o] * xv[d];
        zsq += z * z;
    }
    #pragma unroll
    for (int off = 32; off; off >>= 1) zsq += __shfl_xor(zsq, off);
    if ((t & 63) == 0) red[4 + (t >> 6)] = zsq;
    __syncthreads();
    if (t == 0){
        float rho = red[4] + red[5] + red[6] + red[7];
        float sg = sqrtf(fmaxf(rho, 0.f));
        inv_s[m] = 1.0f / fmaxf(sg, 1e-6f);
    }
}

// ---------------- per-frame MLP, writes node_features transposed [b][node][frame]
__global__ __launch_bounds__(256) void kMLP(const float* __restrict__ inp, const float* __restrict__ w1,
                                            const float* __restrict__ b1, const float* __restrict__ w2,
                                            const float* __restrict__ b2, const float* __restrict__ inv_s,
                                            float* __restrict__ nf){
    int n = blockIdx.x, t = threadIdx.x;
    __shared__ float xl[16][IND];
    __shared__ float hl[16][IND];
    float i1 = inv_s[n], i2 = inv_s[NFR + n];
    for (int i = t; i < 16 * IND; i += 256){
        int b = i >> 8, d = i & 255;
        xl[b][d] = inp[(size_t)b * (NFR * IND) + (size_t)n * IND + d];
    }
    __syncthreads();
    const float* W1 = w1 + (size_t)n * IND * IND;
    float acc[16] = {};
    for (int d = 0; d < IND; ++d){
        float w = W1[(size_t)d * IND + t];
        #pragma unroll
        for (int b = 0; b < 16; ++b) acc[b] += xl[b][d] * w;
    }
    float bb = b1[(size_t)n * IND + t];
    #pragma unroll
    for (int b = 0; b < 16; ++b){
        float h = acc[b] * i1 + bb;
        h = 0.5f * h * (1.0f + erff(h * 0.70710678118654752f));
        hl[b][t] = h;
    }
    __syncthreads();
    const float* W2 = w2 + (size_t)n * IND * ONODES;
    float o0[16] = {}, o1[16] = {};
    for (int d = 0; d < IND; ++d){
        float wa = W2[(size_t)d * ONODES + t];
        float wb = W2[(size_t)d * ONODES + t + 256];
        #pragma unroll
        for (int b = 0; b < 16; ++b){ float h = hl[b][d]; o0[b] += h * wa; o1[b] += h * wb; }
    }
    float bb0 = b2[(size_t)n * ONODES + t], bb1 = b2[(size_t)n * ONODES + t + 256];
    #pragma unroll
    for (int b = 0; b < 16; ++b){
        nf[(size_t)b * (ONODES * NFR) + (size_t)t * NFR + n]         = o0[b] * i2 + bb0;
        nf[(size_t)b * (ONODES * NFR) + (size_t)(t + 256) * NFR + n] = o1[b] * i2 + bb1;
    }
}

// ---------------- qk projection: q/k [b][c][node][f]
__global__ __launch_bounds__(256) void kQK(const float* __restrict__ nf, const float* __restrict__ wqk,
                                           float* __restrict__ qb, float* __restrict__ kb){
    int b = blockIdx.x, nb = blockIdx.y, t = threadIdx.x;
    __shared__ float xs[32][132];
    __shared__ float wl[128][68];
    for (int i = t; i < 32 * 128; i += 256){
        int r = i >> 7, f = i & 127;
        xs[r][f] = nf[(size_t)b * 65536 + (size_t)(nb * 32 + r) * 128 + f];
    }
    int r = t >> 3, g = t & 7;
    for (int jt = 0; jt < 32; ++jt){
        __syncthreads();
        for (int i = t; i < 64 * 128; i += 256){
            int f = i >> 6, jl = i & 63;
            wl[f][jl] = wqk[(size_t)f * 2048 + jt * 64 + jl];
        }
        __syncthreads();
        float acc[8] = {};
        for (int f = 0; f < 128; ++f){
            float xvv = xs[r][f];
            float4 w0 = *(const float4*)&wl[f][g * 8];
            float4 w1v = *(const float4*)&wl[f][g * 8 + 4];
            acc[0] += xvv * w0.x; acc[1] += xvv * w0.y; acc[2] += xvv * w0.z; acc[3] += xvv * w0.w;
            acc[4] += xvv * w1v.x; acc[5] += xvv * w1v.y; acc[6] += xvv * w1v.z; acc[7] += xvv * w1v.w;
        }
        int j0 = jt * 64 + g * 8;
        int s = j0 >> 10, c = (j0 >> 7) & 7, fc = j0 & 127;
        float* dst = (s ? kb : qb) + ((size_t)(b * 8 + c) * 512 + nb * 32 + r) * 128 + fc;
        *(float4*)dst = make_float4(acc[0], acc[1], acc[2], acc[3]);
        *(float4*)(dst + 4) = make_float4(acc[4], acc[5], acc[6], acc[7]);
    }
}

// ---------------- scores + softmax -> attn [b][c][n][m]
__global__ __launch_bounds__(256) void kS(const float* __restrict__ qb, const float* __restrict__ kb,
                                          float* __restrict__ attn){
    int b = blockIdx.x, c = blockIdx.y, nb = blockIdx.z, t = threadIdx.x;
    __shared__ float ql[32][132];
    __shared__ float kl[128][68]; // kl[f][mr]
    size_t bc = (size_t)(b * 8 + c) * 512;
    for (int i = t; i < 32 * 128; i += 256){
        int r = i >> 7, f = i & 127;
        ql[r][f] = qb[(bc + nb * 32 + r) * 128 + f];
    }
    int r = t >> 3, g = t & 7;
    float sreg[8][8];
    #pragma unroll
    for (int mt = 0; mt < 8; ++mt){
        __syncthreads();
        for (int i = t; i < 64 * 128; i += 256){
            int mr = i >> 7, f = i & 127;
            kl[f][mr] = kb[(bc + mt * 64 + mr) * 128 + f];
        }
        __syncthreads();
        float acc[8] = {};
        for (int f = 0; f < 128; ++f){
            float qv = ql[r][f];
            float4 k0 = *(const float4*)&kl[f][g * 8];
            float4 k1 = *(const float4*)&kl[f][g * 8 + 4];
            acc[0] += qv * k0.x; acc[1] += qv * k0.y; acc[2] += qv * k0.z; acc[3] += qv * k0.w;
            acc[4] += qv * k1.x; acc[5] += qv * k1.y; acc[6] += qv * k1.z; acc[7] += qv * k1.w;
        }
        #pragma unroll
        for (int q = 0; q < 8; ++q) sreg[mt][q] = acc[q];
    }
    float mx = -1e30f;
    #pragma unroll
    for (int mt = 0; mt < 8; ++mt)
        #pragma unroll
        for (int q = 0; q < 8; ++q) mx = fmaxf(mx, sreg[mt][q]);
    mx = fmaxf(mx, __shfl_xor(mx, 1));
    mx = fmaxf(mx, __shfl_xor(mx, 2));
    mx = fmaxf(mx, __shfl_xor(mx, 4));
    float em = mx * SM_SCALE;
    float sum = 0.f;
    #pragma unroll
    for (int mt = 0; mt < 8; ++mt)
        #pragma unroll
        for (int q = 0; q < 8; ++q){
            float p = __expf(sreg[mt][q] * SM_SCALE - em);
            sreg[mt][q] = p;
            sum += p;
        }
    sum += __shfl_xor(sum, 1);
    sum += __shfl_xor(sum, 2);
    sum += __shfl_xor(sum, 4);
    float inv = 1.0f / sum;
    size_t rowb = (bc + nb * 32 + r) * 512;
    #pragma unroll
    for (int mt = 0; mt < 8; ++mt){
        *(float4*)&attn[rowb + mt * 64 + g * 8] =
            make_float4(sreg[mt][0] * inv, sreg[mt][1] * inv, sreg[mt][2] * inv, sreg[mt][3] * inv);
        *(float4*)&attn[rowb + mt * 64 + g * 8 + 4] =
            make_float4(sreg[mt][4] * inv, sreg[mt][5] * inv, sreg[mt][6] * inv, sreg[mt][7] * inv);
    }
}

// ---------------- top-32 (of channel-sum) per (b,n) row -> bitmask, + diagonal
__global__ __launch_bounds__(256) void kT(const float* __restrict__ attn, unsigned long long* __restrict__ mask){
    int wid = threadIdx.x >> 6, lane = threadIdx.x & 63;
    int row = blockIdx.x * 4 + wid;
    int b = row >> 9, n = row & 511;
    float v[8];
    #pragma unroll
    for (int j = 0; j < 8; ++j){
        float s = 0.f;
        #pragma unroll
        for (int c = 0; c < 8; ++c)
            s += attn[((size_t)(b * 8 + c) * 512 + n) * 512 + j * 64 + lane];
        v[j] = s;
    }
    unsigned int chosen = 0;
    for (int iter = 0; iter < 32; ++iter){
        float bv = -1e30f; int bm = 0x7fffffff;
        #pragma unroll
        for (int j = 0; j < 8; ++j){
            int mm = j * 64 + lane;
            if (v[j] > bv){ bv = v[j]; bm = mm; }
        }
        #pragma unroll
        for (int off = 1; off < 64; off <<= 1){
            float ov = __shfl_xor(bv, off);
            int om = __shfl_xor(bm, off);
            if (ov > bv || (ov == bv && om < bm)){ bv = ov; bm = om; }
        }
        if (lane == (bm & 63)){
            int jj = bm >> 6;
            #pragma unroll
            for (int j = 0; j < 8; ++j) if (j == jj) v[j] = -1e30f;
            chosen |= 1u << jj;
        }
    }
    #pragma unroll
    for (int j = 0; j < 8; ++j){
        unsigned long long bm64 = __ballot((chosen >> j) & 1u);
        if (lane == j){
            if ((n >> 6) == j) bm64 |= 1ull << (n & 63);
            mask[((size_t)b * 512 + n) * 8 + j] = bm64;
        }
    }
}

// ---------------- row-normalize masked attn -> bf16 NR
__global__ __launch_bounds__(256) void kN(const float* __restrict__ attn, const unsigned long long* __restrict__ mask,
                                          unsigned short* __restrict__ nrb){
    int wid = threadIdx.x >> 6, lane = threadIdx.x & 63;
    int row = blockIdx.x * 4 + wid; // 0..65535
    int b = row >> 12, c = (row >> 9) & 7, n = row & 511;
    size_t base = ((size_t)(b * 8 + c) * 512 + n) * 512;
    const unsigned long long* mrow = mask + ((size_t)b * 512 + n) * 8;
    float e[8]; float rs = 0.f;
    #pragma unroll
    for (int j = 0; j < 8; ++j){
        float a = attn[base + j * 64 + lane];
        bool keep = (mrow[j] >> lane) & 1ull;
        e[j] = keep ? a : 0.0f;
        rs += e[j];
    }
    #pragma unroll
    for (int off = 1; off < 64; off <<= 1) rs += __shfl_xor(rs, off);
    float inv = 1.0f / (rs + 1e-6f);
    #pragma unroll
    for (int j = 0; j < 8; ++j) nrb[base + j * 64 + lane] = f2bf(e[j] * inv);
}

// ---------------- column sums of NR (bf16 in, fp32 out)
__global__ __launch_bounds__(1024) void kC(const unsigned short* __restrict__ nrb, float* __restrict__ cs){
    int b = blockIdx.x, c = blockIdx.y, t = threadIdx.x;
    int mm = t & 511, nh = t >> 9;
    const unsigned short* Mp = nrb + (size_t)(b * 8 + c) * 262144;
    float s = 0.f;
    for (int n = nh * 256; n < nh * 256 + 256; ++n) s += bf2f(Mp[(size_t)n * 512 + mm]);
    __shared__ float red[1024];
    red[t] = s;
    __syncthreads();
    if (t < 512) cs[(size_t)(b * 8 + c) * 512 + t] = red[t] + red[t + 512];
}

// ---------------- in-place S = NR * rsqrt(colsum + 1e-6) (per column), bf16
__global__ __launch_bounds__(256) void kD(unsigned short* __restrict__ nrb, const float* __restrict__ cs){
    size_t idx = (size_t)blockIdx.x * 256 + threadIdx.x; // 16B chunk index
    size_t base = idx * 8;
    int bc = (int)(base >> 18);
    int mg = (int)(base & 511);
    const float* cp = cs + (size_t)bc * 512 + mg;
    ushort8 v = *(ushort8*)&nrb[base];
    float4 c0 = *(const float4*)cp;
    float4 c1 = *(const float4*)(cp + 4);
    float cv[8] = {c0.x, c0.y, c0.z, c0.w, c1.x, c1.y, c1.z, c1.w};
    #pragma unroll
    for (int j = 0; j < 8; ++j){
        float s = bf2f(v[j]) * rsqrtf(cv[j] + 1e-6f);
        v[j] = f2bf(s);
    }
    *(ushort8*)&nrb[base] = v;
}

// ---------------- out = S * S^T per (b,c), bf16 MFMA, 128x128 tiles, swizzled LDS
__global__ __launch_bounds__(256) void kF(const unsigned short* __restrict__ S, float* __restrict__ oe){
    int b = blockIdx.x, c = blockIdx.y, tz = blockIdx.z;
    int nb = (tz >> 2) * 128, mb = (tz & 3) * 128;
    size_t bc = (size_t)(b * 8 + c) * 512;
    const unsigned short* M = S + bc * 512;
    __shared__ unsigned short At[128 * 64];
    __shared__ unsigned short Bt[128 * 64];
    int t = threadIdx.x;
    int w = t >> 6, l = t & 63;
    int wr = (w >> 1) * 64, wc = (w & 1) * 64;
    f32x4 acc[4][4] = {};
    int srow = t >> 3, sg = t & 7;
    for (int kb = 0; kb < 512; kb += 64){
        __syncthreads();
        #pragma unroll
        for (int i = 0; i < 4; ++i){
            int row = i * 32 + srow;
            int dstg = sg ^ (row & 7);
            ushort8 va = *(const ushort8*)&M[(size_t)(nb + row) * 512 + kb + sg * 8];
            *(ushort8*)&At[row * 64 + dstg * 8] = va;
            ushort8 vb = *(const ushort8*)&M[(size_t)(mb + row) * 512 + kb + sg * 8];
            *(ushort8*)&Bt[row * 64 + dstg * 8] = vb;
        }
        __syncthreads();
        #pragma unroll
        for (int kh = 0; kh < 2; ++kh){
            bf16x8 af[4], bfr[4];
            #pragma unroll
            for (int fi = 0; fi < 4; ++fi){
                int row = wr + fi * 16 + (l & 15);
                int g = (kh * 4 + (l >> 4)) ^ (row & 7);
                af[fi] = *(const bf16x8*)&At[row * 64 + g * 8];
            }
            #pragma unroll
            for (int fj = 0; fj < 4; ++fj){
                int row = wc + fj * 16 + (l & 15);
                int g = (kh * 4 + (l >> 4)) ^ (row & 7);
                bfr[fj] = *(const bf16x8*)&Bt[row * 64 + g * 8];
            }
            #pragma unroll
            for (int fi = 0; fi < 4; ++fi)
                #pragma unroll
                for (int fj = 0; fj < 4; ++fj)
                    acc[fi][fj] = __builtin_amdgcn_mfma_f32_16x16x32_bf16(af[fi], bfr[fj], acc[fi][fj], 0, 0, 0);
        }
    }
    #pragma unroll
    for (int fi = 0; fi < 4; ++fi){
        #pragma unroll
        for (int r = 0; r < 4; ++r){
            int n = nb + wr + fi * 16 + (l >> 4) * 4 + r;
            float* orow = oe + (bc + n) * 512 + mb + wc + (l & 15);
            #pragma unroll
            for (int fj = 0; fj < 4; ++fj) orow[fj * 16] = acc[fi][fj][r];
        }
    }
}

extern "C" void kernel_launch(void* const* d_in, const int* in_sizes, int n_in,
                              void* d_out, int out_size, void* d_ws, size_t ws_size,
                              hipStream_t stream) {
    const float* inp = (const float*)d_in[0];
    const float* w1  = (const float*)d_in[1];
    const float* b1  = (const float*)d_in[2];
    const float* w2  = (const float*)d_in[3];
    const float* b2  = (const float*)d_in[4];
    const float* wqk = (const float*)d_in[5];

    float* out_nf   = (float*)d_out;                       // [16][512][128]
    float* out_edge = out_nf + (size_t)16 * 512 * 128;     // [16][8][512][512]

    char* ws = (char*)d_ws;
    float* inv_s = (float*)ws;                             // 256 floats
    float* q_buf = (float*)(ws + 4096);                    // [16][8][512][128] f32 (dead after kS)
    float* k_buf = q_buf + (size_t)16 * 8 * 512 * 128;
    float* attn  = k_buf + (size_t)16 * 8 * 512 * 128;     // [16][8][512][512] f32
    float* Gbuf  = attn;                                   // alias: G used before attn written
    float* csum  = attn + (size_t)16 * 8 * 512 * 512;      // [16][8][512]
    unsigned long long* mask = (unsigned long long*)(csum + (size_t)16 * 8 * 512); // [16][512][8]
    unsigned short* nrb = (unsigned short*)q_buf;          // [16][8][512][512] bf16 = 67MB (q+k region)

    kG  <<<256, 512, 0, stream>>>(w1, w2, Gbuf);
    kP  <<<256, 256, 136256, stream>>>(w1, w2, Gbuf, inv_s);
    kMLP<<<128, 256, 0, stream>>>(inp, w1, b1, w2, b2, inv_s, out_nf);
    kQK <<<dim3(16, 16), 256, 0, stream>>>(out_nf, wqk, q_buf, k_buf);
    kS  <<<dim3(16, 8, 16), 256, 0, stream>>>(q_buf, k_buf, attn);
    kT  <<<2048, 256, 0, stream>>>(attn, mask);
    kN  <<<16384, 256, 0, stream>>>(attn, mask, nrb);
    kC  <<<dim3(16, 8), 1024, 0, stream>>>(nrb, csum);
    kD  <<<16384, 256, 0, stream>>>(nrb, csum);
    kF  <<<dim3(16, 8, 16), 256, 0, stream>>>(nrb, out_edge);
}

// Round 3
// 847.800 us; speedup vs baseline: 2.0315x; 1.4298x over previous
//
#include <hip/hip_runtime.h>
#include <hip/hip_bf16.h>
#include <math.h>

#define NFR 128
#define IND 256
#define ONODES 512

static constexpr float SM_SCALE = 0.08838834764831845f; // 128^-0.5

typedef __attribute__((ext_vector_type(8))) short bf16x8;
typedef __attribute__((ext_vector_type(4))) float f32x4;
typedef __attribute__((ext_vector_type(8))) unsigned short ushort8;

__device__ __forceinline__ unsigned short f2bf(float f){
    unsigned int b = __float_as_uint(f);
    b = (b + 0x7fffu + ((b >> 16) & 1u)) >> 16;
    return (unsigned short)b;
}
__device__ __forceinline__ float bf2f(unsigned short u){
    return __uint_as_float(((unsigned int)u) << 16);
}

// ---------------- G[m] = W_m * W_m^T (256x256) via bf16 MFMA; bf16 output.
__global__ __launch_bounds__(512) void kG(const float* __restrict__ w1, const float* __restrict__ w2,
                                          unsigned short* __restrict__ Gb){
    int m = blockIdx.x;
    const float* W; int K;
    if (m < NFR){ W = w1 + (size_t)m * IND * IND; K = IND; }
    else        { W = w2 + (size_t)(m - NFR) * IND * ONODES; K = ONODES; }
    __shared__ unsigned short Wt[256 * 64]; // rows x 64 k, bf16, granule-swizzled
    int t = threadIdx.x;
    int w = t >> 6, l = t & 63;
    int wr = (w >> 2) * 128, wc = (w & 3) * 64;
    f32x4 acc[8][4] = {};
    int srow = t >> 3, sg = t & 7;
    for (int kb = 0; kb < K; kb += 64){
        __syncthreads();
        #pragma unroll
        for (int i = 0; i < 4; ++i){
            int row = i * 64 + srow;
            int dstg = sg ^ (row & 7);
            const float* src = &W[(size_t)row * K + kb + sg * 8];
            float4 f0 = *(const float4*)src;
            float4 f1 = *(const float4*)(src + 4);
            ushort8 v;
            v[0] = f2bf(f0.x); v[1] = f2bf(f0.y); v[2] = f2bf(f0.z); v[3] = f2bf(f0.w);
            v[4] = f2bf(f1.x); v[5] = f2bf(f1.y); v[6] = f2bf(f1.z); v[7] = f2bf(f1.w);
            *(ushort8*)&Wt[row * 64 + dstg * 8] = v;
        }
        __syncthreads();
        #pragma unroll
        for (int kh = 0; kh < 2; ++kh){
            bf16x8 af[8], bfr[4];
            #pragma unroll
            for (int fi = 0; fi < 8; ++fi){
                int row = wr + fi * 16 + (l & 15);
                int g = (kh * 4 + (l >> 4)) ^ (row & 7);
                af[fi] = *(const bf16x8*)&Wt[row * 64 + g * 8];
            }
            #pragma unroll
            for (int fj = 0; fj < 4; ++fj){
                int row = wc + fj * 16 + (l & 15);
                int g = (kh * 4 + (l >> 4)) ^ (row & 7);
                bfr[fj] = *(const bf16x8*)&Wt[row * 64 + g * 8];
            }
            #pragma unroll
            for (int fi = 0; fi < 8; ++fi)
                #pragma unroll
                for (int fj = 0; fj < 4; ++fj)
                    acc[fi][fj] = __builtin_amdgcn_mfma_f32_16x16x32_bf16(af[fi], bfr[fj], acc[fi][fj], 0, 0, 0);
        }
    }
    unsigned short* Gm = Gb + (size_t)m * 65536;
    #pragma unroll
    for (int fi = 0; fi < 8; ++fi){
        #pragma unroll
        for (int r = 0; r < 4; ++r){
            int n = wr + fi * 16 + (l >> 4) * 4 + r;
            unsigned short* grow = Gm + (size_t)n * 256 + wc + (l & 15);
            #pragma unroll
            for (int fj = 0; fj < 4; ++fj) grow[fj * 16] = f2bf(acc[fi][fj][r]);
        }
    }
}

// ---------------- G2[m] = G[m] * G[m] (bf16 in/out, symmetric so == G*G^T)
__global__ __launch_bounds__(512) void kG2(const unsigned short* __restrict__ Gb,
                                           unsigned short* __restrict__ G2b){
    int m = blockIdx.x;
    const unsigned short* Gm = Gb + (size_t)m * 65536;
    __shared__ unsigned short Wt[256 * 64];
    int t = threadIdx.x;
    int w = t >> 6, l = t & 63;
    int wr = (w >> 2) * 128, wc = (w & 3) * 64;
    f32x4 acc[8][4] = {};
    int srow = t >> 3, sg = t & 7;
    for (int kb = 0; kb < 256; kb += 64){
        __syncthreads();
        #pragma unroll
        for (int i = 0; i < 4; ++i){
            int row = i * 64 + srow;
            int dstg = sg ^ (row & 7);
            ushort8 v = *(const ushort8*)&Gm[(size_t)row * 256 + kb + sg * 8];
            *(ushort8*)&Wt[row * 64 + dstg * 8] = v;
        }
        __syncthreads();
        #pragma unroll
        for (int kh = 0; kh < 2; ++kh){
            bf16x8 af[8], bfr[4];
            #pragma unroll
            for (int fi = 0; fi < 8; ++fi){
                int row = wr + fi * 16 + (l & 15);
                int g = (kh * 4 + (l >> 4)) ^ (row & 7);
                af[fi] = *(const bf16x8*)&Wt[row * 64 + g * 8];
            }
            #pragma unroll
            for (int fj = 0; fj < 4; ++fj){
                int row = wc + fj * 16 + (l & 15);
                int g = (kh * 4 + (l >> 4)) ^ (row & 7);
                bfr[fj] = *(const bf16x8*)&Wt[row * 64 + g * 8];
            }
            #pragma unroll
            for (int fi = 0; fi < 8; ++fi)
                #pragma unroll
                for (int fj = 0; fj < 4; ++fj)
                    acc[fi][fj] = __builtin_amdgcn_mfma_f32_16x16x32_bf16(af[fi], bfr[fj], acc[fi][fj], 0, 0, 0);
        }
    }
    unsigned short* Om = G2b + (size_t)m * 65536;
    #pragma unroll
    for (int fi = 0; fi < 8; ++fi){
        #pragma unroll
        for (int r = 0; r < 4; ++r){
            int n = wr + fi * 16 + (l >> 4) * 4 + r;
            unsigned short* grow = Om + (size_t)n * 256 + wc + (l & 15);
            #pragma unroll
            for (int fj = 0; fj < 4; ++fj) grow[fj * 16] = f2bf(acc[fi][fj][r]);
        }
    }
}

// ---------------- power iteration on G2 (bf16 LDS, 16 waves) + Rayleigh vs fp32 W
__global__ __launch_bounds__(1024) void kP2(const float* __restrict__ w1, const float* __restrict__ w2,
                                            const unsigned short* __restrict__ G2b, float* __restrict__ inv_s){
    extern __shared__ char smem[];
    unsigned short* Gl = (unsigned short*)smem;            // 65536 ushorts = 131072 B
    float* yred = (float*)(smem + 131072);                 // 4096 floats = 16384 B
    float* xv   = (float*)(smem + 147456);                 // 256 floats
    float* red  = (float*)(smem + 148480);                 // 32 floats
    int m = blockIdx.x, t = threadIdx.x;
    {
        const ushort8* src = (const ushort8*)(G2b + (size_t)m * 65536);
        ushort8* dst = (ushort8*)Gl;
        #pragma unroll
        for (int i = 0; i < 8; ++i) dst[t + i * 1024] = src[t + i * 1024];
    }
    if (t < 256){
        unsigned int h = (unsigned int)t * 2654435761u ^ 0x9e3779b9u;
        h ^= h >> 13; h *= 0x85ebca6bu; h ^= h >> 16;
        xv[t] = 0.5f + (float)(h & 0xffffu) * (1.0f / 65536.0f);
    }
    __syncthreads();
    int rid = t & 63, seg = t >> 6;   // seg 0..15, rows 4rid..4rid+3, j in [16seg,16seg+16)
    int lane = t & 63;
    for (int it = 0; it < 64; ++it){
        float a0 = 0.f, a1 = 0.f, a2 = 0.f, a3 = 0.f;
        #pragma unroll
        for (int jj = 0; jj < 16; ++jj){
            int j = seg * 16 + jj;
            float xb = xv[j];
            uint2 g = *(const uint2*)&Gl[(size_t)j * 256 + 4 * rid];
            a0 += bf2f((unsigned short)(g.x & 0xffffu)) * xb;
            a1 += bf2f((unsigned short)(g.x >> 16)) * xb;
            a2 += bf2f((unsigned short)(g.y & 0xffffu)) * xb;
            a3 += bf2f((unsigned short)(g.y >> 16)) * xb;
        }
        *(float4*)&yred[seg * 256 + 4 * rid] = make_float4(a0, a1, a2, a3);
        __syncthreads();
        float yv = 0.f;
        if (t < 256){
            #pragma unroll
            for (int s = 0; s < 16; ++s) yv += yred[s * 256 + t];
            float ss = yv * yv;
            #pragma unroll
            for (int off = 32; off; off >>= 1) ss += __shfl_xor(ss, off);
            if (lane == 0) red[t >> 6] = ss;
        }
        __syncthreads();
        if (t < 256){
            float ss = red[0] + red[1] + red[2] + red[3];
            xv[t] = yv * rsqrtf(ss);
        }
        __syncthreads();
    }
    const float* W; int K;
    if (m < NFR){ W = w1 + (size_t)m * IND * IND; K = IND; }
    else        { W = w2 + (size_t)(m - NFR) * IND * ONODES; K = ONODES; }
    float zsq = 0.f;
    for (int o = t; o < K; o += 1024){
        float z = 0.f;
        for (int d = 0; d < 256; ++d) z += W[(size_t)d * K + o] * xv[d];
        zsq += z * z;
    }
    #pragma unroll
    for (int off = 32; off; off >>= 1) zsq += __shfl_xor(zsq, off);
    if (lane == 0) red[16 + (t >> 6)] = zsq;
    __syncthreads();
    if (t == 0){
        float rho = 0.f;
        #pragma unroll
        for (int i = 0; i < 16; ++i) rho += red[16 + i];
        float sg = sqrtf(fmaxf(rho, 0.f));
        inv_s[m] = 1.0f / fmaxf(sg, 1e-6f);
    }
}

// ---------------- per-frame MLP, writes node_features transposed [b][node][frame]
__global__ __launch_bounds__(256) void kMLP(const float* __restrict__ inp, const float* __restrict__ w1,
                                            const float* __restrict__ b1, const float* __restrict__ w2,
                                            const float* __restrict__ b2, const float* __restrict__ inv_s,
                                            float* __restrict__ nf){
    int n = blockIdx.x, t = threadIdx.x;
    __shared__ float xl[16][IND];
    __shared__ float hl[16][IND];
    float i1 = inv_s[n], i2 = inv_s[NFR + n];
    for (int i = t; i < 16 * IND; i += 256){
        int b = i >> 8, d = i & 255;
        xl[b][d] = inp[(size_t)b * (NFR * IND) + (size_t)n * IND + d];
    }
    __syncthreads();
    const float* W1 = w1 + (size_t)n * IND * IND;
    float acc[16] = {};
    for (int d = 0; d < IND; ++d){
        float w = W1[(size_t)d * IND + t];
        #pragma unroll
        for (int b = 0; b < 16; ++b) acc[b] += xl[b][d] * w;
    }
    float bb = b1[(size_t)n * IND + t];
    #pragma unroll
    for (int b = 0; b < 16; ++b){
        float h = acc[b] * i1 + bb;
        h = 0.5f * h * (1.0f + erff(h * 0.70710678118654752f));
        hl[b][t] = h;
    }
    __syncthreads();
    const float* W2 = w2 + (size_t)n * IND * ONODES;
    float o0[16] = {}, o1[16] = {};
    for (int d = 0; d < IND; ++d){
        float wa = W2[(size_t)d * ONODES + t];
        float wb = W2[(size_t)d * ONODES + t + 256];
        #pragma unroll
        for (int b = 0; b < 16; ++b){ float h = hl[b][d]; o0[b] += h * wa; o1[b] += h * wb; }
    }
    float bb0 = b2[(size_t)n * ONODES + t], bb1 = b2[(size_t)n * ONODES + t + 256];
    #pragma unroll
    for (int b = 0; b < 16; ++b){
        nf[(size_t)b * (ONODES * NFR) + (size_t)t * NFR + n]         = o0[b] * i2 + bb0;
        nf[(size_t)b * (ONODES * NFR) + (size_t)(t + 256) * NFR + n] = o1[b] * i2 + bb1;
    }
}

// ---------------- qk projection: q/k [b][c][node][f]
__global__ __launch_bounds__(256) void kQK(const float* __restrict__ nf, const float* __restrict__ wqk,
                                           float* __restrict__ qb, float* __restrict__ kb){
    int b = blockIdx.x, nb = blockIdx.y, t = threadIdx.x;
    __shared__ float xs[32][132];
    __shared__ float wl[128][68];
    for (int i = t; i < 32 * 128; i += 256){
        int r = i >> 7, f = i & 127;
        xs[r][f] = nf[(size_t)b * 65536 + (size_t)(nb * 32 + r) * 128 + f];
    }
    int r = t >> 3, g = t & 7;
    for (int jt = 0; jt < 32; ++jt){
        __syncthreads();
        for (int i = t; i < 64 * 128; i += 256){
            int f = i >> 6, jl = i & 63;
            wl[f][jl] = wqk[(size_t)f * 2048 + jt * 64 + jl];
        }
        __syncthreads();
        float acc[8] = {};
        for (int f = 0; f < 128; ++f){
            float xvv = xs[r][f];
            float4 w0 = *(const float4*)&wl[f][g * 8];
            float4 w1v = *(const float4*)&wl[f][g * 8 + 4];
            acc[0] += xvv * w0.x; acc[1] += xvv * w0.y; acc[2] += xvv * w0.z; acc[3] += xvv * w0.w;
            acc[4] += xvv * w1v.x; acc[5] += xvv * w1v.y; acc[6] += xvv * w1v.z; acc[7] += xvv * w1v.w;
        }
        int j0 = jt * 64 + g * 8;
        int s = j0 >> 10, c = (j0 >> 7) & 7, fc = j0 & 127;
        float* dst = (s ? kb : qb) + ((size_t)(b * 8 + c) * 512 + nb * 32 + r) * 128 + fc;
        *(float4*)dst = make_float4(acc[0], acc[1], acc[2], acc[3]);
        *(float4*)(dst + 4) = make_float4(acc[4], acc[5], acc[6], acc[7]);
    }
}

// ---------------- scores + softmax -> attn [b][c][n][m]
__global__ __launch_bounds__(256) void kS(const float* __restrict__ qb, const float* __restrict__ kb,
                                          float* __restrict__ attn){
    int b = blockIdx.x, c = blockIdx.y, nb = blockIdx.z, t = threadIdx.x;
    __shared__ float ql[32][132];
    __shared__ float kl[128][68]; // kl[f][mr]
    size_t bc = (size_t)(b * 8 + c) * 512;
    for (int i = t; i < 32 * 128; i += 256){
        int r = i >> 7, f = i & 127;
        ql[r][f] = qb[(bc + nb * 32 + r) * 128 + f];
    }
    int r = t >> 3, g = t & 7;
    float sreg[8][8];
    #pragma unroll
    for (int mt = 0; mt < 8; ++mt){
        __syncthreads();
        for (int i = t; i < 64 * 128; i += 256){
            int mr = i >> 7, f = i & 127;
            kl[f][mr] = kb[(bc + mt * 64 + mr) * 128 + f];
        }
        __syncthreads();
        float acc[8] = {};
        for (int f = 0; f < 128; ++f){
            float qv = ql[r][f];
            float4 k0 = *(const float4*)&kl[f][g * 8];
            float4 k1 = *(const float4*)&kl[f][g * 8 + 4];
            acc[0] += qv * k0.x; acc[1] += qv * k0.y; acc[2] += qv * k0.z; acc[3] += qv * k0.w;
            acc[4] += qv * k1.x; acc[5] += qv * k1.y; acc[6] += qv * k1.z; acc[7] += qv * k1.w;
        }
        #pragma unroll
        for (int q = 0; q < 8; ++q) sreg[mt][q] = acc[q];
    }
    float mx = -1e30f;
    #pragma unroll
    for (int mt = 0; mt < 8; ++mt)
        #pragma unroll
        for (int q = 0; q < 8; ++q) mx = fmaxf(mx, sreg[mt][q]);
    mx = fmaxf(mx, __shfl_xor(mx, 1));
    mx = fmaxf(mx, __shfl_xor(mx, 2));
    mx = fmaxf(mx, __shfl_xor(mx, 4));
    float em = mx * SM_SCALE;
    float sum = 0.f;
    #pragma unroll
    for (int mt = 0; mt < 8; ++mt)
        #pragma unroll
        for (int q = 0; q < 8; ++q){
            float p = __expf(sreg[mt][q] * SM_SCALE - em);
            sreg[mt][q] = p;
            sum += p;
        }
    sum += __shfl_xor(sum, 1);
    sum += __shfl_xor(sum, 2);
    sum += __shfl_xor(sum, 4);
    float inv = 1.0f / sum;
    size_t rowb = (bc + nb * 32 + r) * 512;
    #pragma unroll
    for (int mt = 0; mt < 8; ++mt){
        *(float4*)&attn[rowb + mt * 64 + g * 8] =
            make_float4(sreg[mt][0] * inv, sreg[mt][1] * inv, sreg[mt][2] * inv, sreg[mt][3] * inv);
        *(float4*)&attn[rowb + mt * 64 + g * 8 + 4] =
            make_float4(sreg[mt][4] * inv, sreg[mt][5] * inv, sreg[mt][6] * inv, sreg[mt][7] * inv);
    }
}

// ---------------- top-32 (of channel-sum) per (b,n) row -> bitmask, + diagonal
__global__ __launch_bounds__(256) void kT(const float* __restrict__ attn, unsigned long long* __restrict__ mask){
    int wid = threadIdx.x >> 6, lane = threadIdx.x & 63;
    int row = blockIdx.x * 4 + wid;
    int b = row >> 9, n = row & 511;
    float v[8];
    #pragma unroll
    for (int j = 0; j < 8; ++j){
        float s = 0.f;
        #pragma unroll
        for (int c = 0; c < 8; ++c)
            s += attn[((size_t)(b * 8 + c) * 512 + n) * 512 + j * 64 + lane];
        v[j] = s;
    }
    unsigned int chosen = 0;
    for (int iter = 0; iter < 32; ++iter){
        float bv = -1e30f; int bm = 0x7fffffff;
        #pragma unroll
        for (int j = 0; j < 8; ++j){
            int mm = j * 64 + lane;
            if (v[j] > bv){ bv = v[j]; bm = mm; }
        }
        #pragma unroll
        for (int off = 1; off < 64; off <<= 1){
            float ov = __shfl_xor(bv, off);
            int om = __shfl_xor(bm, off);
            if (ov > bv || (ov == bv && om < bm)){ bv = ov; bm = om; }
        }
        if (lane == (bm & 63)){
            int jj = bm >> 6;
            #pragma unroll
            for (int j = 0; j < 8; ++j) if (j == jj) v[j] = -1e30f;
            chosen |= 1u << jj;
        }
    }
    #pragma unroll
    for (int j = 0; j < 8; ++j){
        unsigned long long bm64 = __ballot((chosen >> j) & 1u);
        if (lane == j){
            if ((n >> 6) == j) bm64 |= 1ull << (n & 63);
            mask[((size_t)b * 512 + n) * 8 + j] = bm64;
        }
    }
}

// ---------------- row-normalize masked attn -> bf16 NR
__global__ __launch_bounds__(256) void kN(const float* __restrict__ attn, const unsigned long long* __restrict__ mask,
                                          unsigned short* __restrict__ nrb){
    int wid = threadIdx.x >> 6, lane = threadIdx.x & 63;
    int row = blockIdx.x * 4 + wid; // 0..65535
    int b = row >> 12, c = (row >> 9) & 7, n = row & 511;
    size_t base = ((size_t)(b * 8 + c) * 512 + n) * 512;
    const unsigned long long* mrow = mask + ((size_t)b * 512 + n) * 8;
    float e[8]; float rs = 0.f;
    #pragma unroll
    for (int j = 0; j < 8; ++j){
        float a = attn[base + j * 64 + lane];
        bool keep = (mrow[j] >> lane) & 1ull;
        e[j] = keep ? a : 0.0f;
        rs += e[j];
    }
    #pragma unroll
    for (int off = 1; off < 64; off <<= 1) rs += __shfl_xor(rs, off);
    float inv = 1.0f / (rs + 1e-6f);
    #pragma unroll
    for (int j = 0; j < 8; ++j) nrb[base + j * 64 + lane] = f2bf(e[j] * inv);
}

// ---------------- column sums of NR (bf16 in, fp32 out)
__global__ __launch_bounds__(1024) void kC(const unsigned short* __restrict__ nrb, float* __restrict__ cs){
    int b = blockIdx.x, c = blockIdx.y, t = threadIdx.x;
    int mm = t & 511, nh = t >> 9;
    const unsigned short* Mp = nrb + (size_t)(b * 8 + c) * 262144;
    float s = 0.f;
    for (int n = nh * 256; n < nh * 256 + 256; ++n) s += bf2f(Mp[(size_t)n * 512 + mm]);
    __shared__ float red[1024];
    red[t] = s;
    __syncthreads();
    if (t < 512) cs[(size_t)(b * 8 + c) * 512 + t] = red[t] + red[t + 512];
}

// ---------------- in-place S = NR * rsqrt(colsum + 1e-6) (per column), bf16
__global__ __launch_bounds__(256) void kD(unsigned short* __restrict__ nrb, const float* __restrict__ cs){
    size_t idx = (size_t)blockIdx.x * 256 + threadIdx.x; // 16B chunk index
    size_t base = idx * 8;
    int bc = (int)(base >> 18);
    int mg = (int)(base & 511);
    const float* cp = cs + (size_t)bc * 512 + mg;
    ushort8 v = *(ushort8*)&nrb[base];
    float4 c0 = *(const float4*)cp;
    float4 c1 = *(const float4*)(cp + 4);
    float cv[8] = {c0.x, c0.y, c0.z, c0.w, c1.x, c1.y, c1.z, c1.w};
    #pragma unroll
    for (int j = 0; j < 8; ++j){
        float s = bf2f(v[j]) * rsqrtf(cv[j] + 1e-6f);
        v[j] = f2bf(s);
    }
    *(ushort8*)&nrb[base] = v;
}

// ---------------- out = S * S^T per (b,c), bf16 MFMA, 128x128 tiles, swizzled LDS
__global__ __launch_bounds__(256) void kF(const unsigned short* __restrict__ S, float* __restrict__ oe){
    int b = blockIdx.x, c = blockIdx.y, tz = blockIdx.z;
    int nb = (tz >> 2) * 128, mb = (tz & 3) * 128;
    size_t bc = (size_t)(b * 8 + c) * 512;
    const unsigned short* M = S + bc * 512;
    __shared__ unsigned short At[128 * 64];
    __shared__ unsigned short Bt[128 * 64];
    int t = threadIdx.x;
    int w = t >> 6, l = t & 63;
    int wr = (w >> 1) * 64, wc = (w & 1) * 64;
    f32x4 acc[4][4] = {};
    int srow = t >> 3, sg = t & 7;
    for (int kb = 0; kb < 512; kb += 64){
        __syncthreads();
        #pragma unroll
        for (int i = 0; i < 4; ++i){
            int row = i * 32 + srow;
            int dstg = sg ^ (row & 7);
            ushort8 va = *(const ushort8*)&M[(size_t)(nb + row) * 512 + kb + sg * 8];
            *(ushort8*)&At[row * 64 + dstg * 8] = va;
            ushort8 vb = *(const ushort8*)&M[(size_t)(mb + row) * 512 + kb + sg * 8];
            *(ushort8*)&Bt[row * 64 + dstg * 8] = vb;
        }
        __syncthreads();
        #pragma unroll
        for (int kh = 0; kh < 2; ++kh){
            bf16x8 af[4], bfr[4];
            #pragma unroll
            for (int fi = 0; fi < 4; ++fi){
                int row = wr + fi * 16 + (l & 15);
                int g = (kh * 4 + (l >> 4)) ^ (row & 7);
                af[fi] = *(const bf16x8*)&At[row * 64 + g * 8];
            }
            #pragma unroll
            for (int fj = 0; fj < 4; ++fj){
                int row = wc + fj * 16 + (l & 15);
                int g = (kh * 4 + (l >> 4)) ^ (row & 7);
                bfr[fj] = *(const bf16x8*)&Bt[row * 64 + g * 8];
            }
            #pragma unroll
            for (int fi = 0; fi < 4; ++fi)
                #pragma unroll
                for (int fj = 0; fj < 4; ++fj)
                    acc[fi][fj] = __builtin_amdgcn_mfma_f32_16x16x32_bf16(af[fi], bfr[fj], acc[fi][fj], 0, 0, 0);
        }
    }
    #pragma unroll
    for (int fi = 0; fi < 4; ++fi){
        #pragma unroll
        for (int r = 0; r < 4; ++r){
            int n = nb + wr + fi * 16 + (l >> 4) * 4 + r;
            float* orow = oe + (bc + n) * 512 + mb + wc + (l & 15);
            #pragma unroll
            for (int fj = 0; fj < 4; ++fj) orow[fj * 16] = acc[fi][fj][r];
        }
    }
}

extern "C" void kernel_launch(void* const* d_in, const int* in_sizes, int n_in,
                              void* d_out, int out_size, void* d_ws, size_t ws_size,
                              hipStream_t stream) {
    const float* inp = (const float*)d_in[0];
    const float* w1  = (const float*)d_in[1];
    const float* b1  = (const float*)d_in[2];
    const float* w2  = (const float*)d_in[3];
    const float* b2  = (const float*)d_in[4];
    const float* wqk = (const float*)d_in[5];

    float* out_nf   = (float*)d_out;                       // [16][512][128]
    float* out_edge = out_nf + (size_t)16 * 512 * 128;     // [16][8][512][512]

    char* ws = (char*)d_ws;
    float* inv_s = (float*)ws;                             // 256 floats
    float* q_buf = (float*)(ws + 4096);                    // [16][8][512][128] f32 (dead after kS)
    float* k_buf = q_buf + (size_t)16 * 8 * 512 * 128;
    float* attn  = k_buf + (size_t)16 * 8 * 512 * 128;     // [16][8][512][512] f32
    float* csum  = attn + (size_t)16 * 8 * 512 * 512;      // [16][8][512]
    unsigned long long* mask = (unsigned long long*)(csum + (size_t)16 * 8 * 512); // [16][512][8]
    unsigned short* nrb = (unsigned short*)q_buf;          // bf16 NR aliases q/k region (dead after kS)
    unsigned short* Gb  = (unsigned short*)attn;           // bf16 G  [256][256][256] (dead before attn)
    unsigned short* G2b = Gb + (size_t)256 * 65536;        // bf16 G2 [256][256][256]

    kG  <<<256, 512, 0, stream>>>(w1, w2, Gb);
    kG2 <<<256, 512, 0, stream>>>(Gb, G2b);
    kP2 <<<256, 1024, 148608, stream>>>(w1, w2, G2b, inv_s);
    kMLP<<<128, 256, 0, stream>>>(inp, w1, b1, w2, b2, inv_s, out_nf);
    kQK <<<dim3(16, 16), 256, 0, stream>>>(out_nf, wqk, q_buf, k_buf);
    kS  <<<dim3(16, 8, 16), 256, 0, stream>>>(q_buf, k_buf, attn);
    kT  <<<2048, 256, 0, stream>>>(attn, mask);
    kN  <<<16384, 256, 0, stream>>>(attn, mask, nrb);
    kC  <<<dim3(16, 8), 1024, 0, stream>>>(nrb, csum);
    kD  <<<16384, 256, 0, stream>>>(nrb, csum);
    kF  <<<dim3(16, 8, 16), 256, 0, stream>>>(nrb, out_edge);
}

// Round 4
// 801.550 us; speedup vs baseline: 2.1487x; 1.0577x over previous
//
#include <hip/hip_runtime.h>
#include <hip/hip_bf16.h>
#include <math.h>

#define NFR 128
#define IND 256
#define ONODES 512

static constexpr float SM_SCALE = 0.08838834764831845f; // 128^-0.5

typedef __attribute__((ext_vector_type(8))) short bf16x8;
typedef __attribute__((ext_vector_type(4))) float f32x4;
typedef __attribute__((ext_vector_type(8))) unsigned short ushort8;

__device__ __forceinline__ unsigned short f2bf(float f){
    unsigned int b = __float_as_uint(f);
    b = (b + 0x7fffu + ((b >> 16) & 1u)) >> 16;
    return (unsigned short)b;
}
__device__ __forceinline__ float bf2f(unsigned short u){
    return __uint_as_float(((unsigned int)u) << 16);
}

// ---------------- G[m] = W_m * W_m^T (256x256) via bf16 MFMA; bf16 output.
__global__ __launch_bounds__(512) void kG(const float* __restrict__ w1, const float* __restrict__ w2,
                                          unsigned short* __restrict__ Gb){
    int m = blockIdx.x;
    const float* W; int K;
    if (m < NFR){ W = w1 + (size_t)m * IND * IND; K = IND; }
    else        { W = w2 + (size_t)(m - NFR) * IND * ONODES; K = ONODES; }
    __shared__ unsigned short Wt[256 * 64]; // rows x 64 k, bf16, granule-swizzled
    int t = threadIdx.x;
    int w = t >> 6, l = t & 63;
    int wr = (w >> 2) * 128, wc = (w & 3) * 64;
    f32x4 acc[8][4] = {};
    int srow = t >> 3, sg = t & 7;
    for (int kb = 0; kb < K; kb += 64){
        __syncthreads();
        #pragma unroll
        for (int i = 0; i < 4; ++i){
            int row = i * 64 + srow;
            int dstg = sg ^ (row & 7);
            const float* src = &W[(size_t)row * K + kb + sg * 8];
            float4 f0 = *(const float4*)src;
            float4 f1 = *(const float4*)(src + 4);
            ushort8 v;
            v[0] = f2bf(f0.x); v[1] = f2bf(f0.y); v[2] = f2bf(f0.z); v[3] = f2bf(f0.w);
            v[4] = f2bf(f1.x); v[5] = f2bf(f1.y); v[6] = f2bf(f1.z); v[7] = f2bf(f1.w);
            *(ushort8*)&Wt[row * 64 + dstg * 8] = v;
        }
        __syncthreads();
        #pragma unroll
        for (int kh = 0; kh < 2; ++kh){
            bf16x8 af[8], bfr[4];
            #pragma unroll
            for (int fi = 0; fi < 8; ++fi){
                int row = wr + fi * 16 + (l & 15);
                int g = (kh * 4 + (l >> 4)) ^ (row & 7);
                af[fi] = *(const bf16x8*)&Wt[row * 64 + g * 8];
            }
            #pragma unroll
            for (int fj = 0; fj < 4; ++fj){
                int row = wc + fj * 16 + (l & 15);
                int g = (kh * 4 + (l >> 4)) ^ (row & 7);
                bfr[fj] = *(const bf16x8*)&Wt[row * 64 + g * 8];
            }
            #pragma unroll
            for (int fi = 0; fi < 8; ++fi)
                #pragma unroll
                for (int fj = 0; fj < 4; ++fj)
                    acc[fi][fj] = __builtin_amdgcn_mfma_f32_16x16x32_bf16(af[fi], bfr[fj], acc[fi][fj], 0, 0, 0);
        }
    }
    unsigned short* Gm = Gb + (size_t)m * 65536;
    #pragma unroll
    for (int fi = 0; fi < 8; ++fi){
        #pragma unroll
        for (int r = 0; r < 4; ++r){
            int n = wr + fi * 16 + (l >> 4) * 4 + r;
            unsigned short* grow = Gm + (size_t)n * 256 + wc + (l & 15);
            #pragma unroll
            for (int fj = 0; fj < 4; ++fj) grow[fj * 16] = f2bf(acc[fi][fj][r]);
        }
    }
}

// ---------------- G2[m] = G[m] * G[m] (bf16 in/out, symmetric so == G*G^T)
__global__ __launch_bounds__(512) void kG2(const unsigned short* __restrict__ Gb,
                                           unsigned short* __restrict__ G2b){
    int m = blockIdx.x;
    const unsigned short* Gm = Gb + (size_t)m * 65536;
    __shared__ unsigned short Wt[256 * 64];
    int t = threadIdx.x;
    int w = t >> 6, l = t & 63;
    int wr = (w >> 2) * 128, wc = (w & 3) * 64;
    f32x4 acc[8][4] = {};
    int srow = t >> 3, sg = t & 7;
    for (int kb = 0; kb < 256; kb += 64){
        __syncthreads();
        #pragma unroll
        for (int i = 0; i < 4; ++i){
            int row = i * 64 + srow;
            int dstg = sg ^ (row & 7);
            ushort8 v = *(const ushort8*)&Gm[(size_t)row * 256 + kb + sg * 8];
            *(ushort8*)&Wt[row * 64 + dstg * 8] = v;
        }
        __syncthreads();
        #pragma unroll
        for (int kh = 0; kh < 2; ++kh){
            bf16x8 af[8], bfr[4];
            #pragma unroll
            for (int fi = 0; fi < 8; ++fi){
                int row = wr + fi * 16 + (l & 15);
                int g = (kh * 4 + (l >> 4)) ^ (row & 7);
                af[fi] = *(const bf16x8*)&Wt[row * 64 + g * 8];
            }
            #pragma unroll
            for (int fj = 0; fj < 4; ++fj){
                int row = wc + fj * 16 + (l & 15);
                int g = (kh * 4 + (l >> 4)) ^ (row & 7);
                bfr[fj] = *(const bf16x8*)&Wt[row * 64 + g * 8];
            }
            #pragma unroll
            for (int fi = 0; fi < 8; ++fi)
                #pragma unroll
                for (int fj = 0; fj < 4; ++fj)
                    acc[fi][fj] = __builtin_amdgcn_mfma_f32_16x16x32_bf16(af[fi], bfr[fj], acc[fi][fj], 0, 0, 0);
        }
    }
    unsigned short* Om = G2b + (size_t)m * 65536;
    #pragma unroll
    for (int fi = 0; fi < 8; ++fi){
        #pragma unroll
        for (int r = 0; r < 4; ++r){
            int n = wr + fi * 16 + (l >> 4) * 4 + r;
            unsigned short* grow = Om + (size_t)n * 256 + wc + (l & 15);
            #pragma unroll
            for (int fj = 0; fj < 4; ++fj) grow[fj * 16] = f2bf(acc[fi][fj][r]);
        }
    }
}

// ---------------- power iteration on G2 (bf16 LDS, 16 waves) + Rayleigh vs fp32 W
__global__ __launch_bounds__(1024) void kP2(const float* __restrict__ w1, const float* __restrict__ w2,
                                            const unsigned short* __restrict__ G2b, float* __restrict__ inv_s){
    extern __shared__ char smem[];
    unsigned short* Gl = (unsigned short*)smem;            // 65536 ushorts = 131072 B
    float* yred = (float*)(smem + 131072);                 // 4096 floats = 16384 B
    float* xv   = (float*)(smem + 147456);                 // 256 floats
    float* red  = (float*)(smem + 148480);                 // 32 floats
    int m = blockIdx.x, t = threadIdx.x;
    {
        const ushort8* src = (const ushort8*)(G2b + (size_t)m * 65536);
        ushort8* dst = (ushort8*)Gl;
        #pragma unroll
        for (int i = 0; i < 8; ++i) dst[t + i * 1024] = src[t + i * 1024];
    }
    if (t < 256){
        unsigned int h = (unsigned int)t * 2654435761u ^ 0x9e3779b9u;
        h ^= h >> 13; h *= 0x85ebca6bu; h ^= h >> 16;
        xv[t] = 0.5f + (float)(h & 0xffffu) * (1.0f / 65536.0f);
    }
    __syncthreads();
    int rid = t & 63, seg = t >> 6;   // seg 0..15, rows 4rid..4rid+3, j in [16seg,16seg+16)
    int lane = t & 63;
    for (int it = 0; it < 64; ++it){
        float a0 = 0.f, a1 = 0.f, a2 = 0.f, a3 = 0.f;
        #pragma unroll
        for (int jj = 0; jj < 16; ++jj){
            int j = seg * 16 + jj;
            float xb = xv[j];
            uint2 g = *(const uint2*)&Gl[(size_t)j * 256 + 4 * rid];
            a0 += bf2f((unsigned short)(g.x & 0xffffu)) * xb;
            a1 += bf2f((unsigned short)(g.x >> 16)) * xb;
            a2 += bf2f((unsigned short)(g.y & 0xffffu)) * xb;
            a3 += bf2f((unsigned short)(g.y >> 16)) * xb;
        }
        *(float4*)&yred[seg * 256 + 4 * rid] = make_float4(a0, a1, a2, a3);
        __syncthreads();
        float yv = 0.f;
        if (t < 256){
            #pragma unroll
            for (int s = 0; s < 16; ++s) yv += yred[s * 256 + t];
            float ss = yv * yv;
            #pragma unroll
            for (int off = 32; off; off >>= 1) ss += __shfl_xor(ss, off);
            if (lane == 0) red[t >> 6] = ss;
        }
        __syncthreads();
        if (t < 256){
            float ss = red[0] + red[1] + red[2] + red[3];
            xv[t] = yv * rsqrtf(ss);
        }
        __syncthreads();
    }
    const float* W; int K;
    if (m < NFR){ W = w1 + (size_t)m * IND * IND; K = IND; }
    else        { W = w2 + (size_t)(m - NFR) * IND * ONODES; K = ONODES; }
    float zsq = 0.f;
    for (int o = t; o < K; o += 1024){
        float z = 0.f;
        for (int d = 0; d < 256; ++d) z += W[(size_t)d * K + o] * xv[d];
        zsq += z * z;
    }
    #pragma unroll
    for (int off = 32; off; off >>= 1) zsq += __shfl_xor(zsq, off);
    if (lane == 0) red[16 + (t >> 6)] = zsq;
    __syncthreads();
    if (t == 0){
        float rho = 0.f;
        #pragma unroll
        for (int i = 0; i < 16; ++i) rho += red[16 + i];
        float sg = sqrtf(fmaxf(rho, 0.f));
        inv_s[m] = 1.0f / fmaxf(sg, 1e-6f);
    }
}

// ---------------- per-frame MLP, writes node_features transposed [b][node][frame]
__global__ __launch_bounds__(256) void kMLP(const float* __restrict__ inp, const float* __restrict__ w1,
                                            const float* __restrict__ b1, const float* __restrict__ w2,
                                            const float* __restrict__ b2, const float* __restrict__ inv_s,
                                            float* __restrict__ nf){
    int n = blockIdx.x, t = threadIdx.x;
    __shared__ float xl[16][IND];
    __shared__ float hl[16][IND];
    float i1 = inv_s[n], i2 = inv_s[NFR + n];
    for (int i = t; i < 16 * IND; i += 256){
        int b = i >> 8, d = i & 255;
        xl[b][d] = inp[(size_t)b * (NFR * IND) + (size_t)n * IND + d];
    }
    __syncthreads();
    const float* W1 = w1 + (size_t)n * IND * IND;
    float acc[16] = {};
    for (int d = 0; d < IND; ++d){
        float w = W1[(size_t)d * IND + t];
        #pragma unroll
        for (int b = 0; b < 16; ++b) acc[b] += xl[b][d] * w;
    }
    float bb = b1[(size_t)n * IND + t];
    #pragma unroll
    for (int b = 0; b < 16; ++b){
        float h = acc[b] * i1 + bb;
        h = 0.5f * h * (1.0f + erff(h * 0.70710678118654752f));
        hl[b][t] = h;
    }
    __syncthreads();
    const float* W2 = w2 + (size_t)n * IND * ONODES;
    float o0[16] = {}, o1[16] = {};
    for (int d = 0; d < IND; ++d){
        float wa = W2[(size_t)d * ONODES + t];
        float wb = W2[(size_t)d * ONODES + t + 256];
        #pragma unroll
        for (int b = 0; b < 16; ++b){ float h = hl[b][d]; o0[b] += h * wa; o1[b] += h * wb; }
    }
    float bb0 = b2[(size_t)n * ONODES + t], bb1 = b2[(size_t)n * ONODES + t + 256];
    #pragma unroll
    for (int b = 0; b < 16; ++b){
        nf[(size_t)b * (ONODES * NFR) + (size_t)t * NFR + n]         = o0[b] * i2 + bb0;
        nf[(size_t)b * (ONODES * NFR) + (size_t)(t + 256) * NFR + n] = o1[b] * i2 + bb1;
    }
}

// ---------------- qk projection: q/k [b][c][node][f] in bf16
__global__ __launch_bounds__(256) void kQK(const float* __restrict__ nf, const float* __restrict__ wqk,
                                           unsigned short* __restrict__ qb, unsigned short* __restrict__ kb){
    int b = blockIdx.x, nb = blockIdx.y, t = threadIdx.x;
    __shared__ float xs[32][132];
    __shared__ float wl[128][68];
    for (int i = t; i < 32 * 128; i += 256){
        int r = i >> 7, f = i & 127;
        xs[r][f] = nf[(size_t)b * 65536 + (size_t)(nb * 32 + r) * 128 + f];
    }
    int r = t >> 3, g = t & 7;
    for (int jt = 0; jt < 32; ++jt){
        __syncthreads();
        for (int i = t; i < 64 * 128; i += 256){
            int f = i >> 6, jl = i & 63;
            wl[f][jl] = wqk[(size_t)f * 2048 + jt * 64 + jl];
        }
        __syncthreads();
        float acc[8] = {};
        for (int f = 0; f < 128; ++f){
            float xvv = xs[r][f];
            float4 w0 = *(const float4*)&wl[f][g * 8];
            float4 w1v = *(const float4*)&wl[f][g * 8 + 4];
            acc[0] += xvv * w0.x; acc[1] += xvv * w0.y; acc[2] += xvv * w0.z; acc[3] += xvv * w0.w;
            acc[4] += xvv * w1v.x; acc[5] += xvv * w1v.y; acc[6] += xvv * w1v.z; acc[7] += xvv * w1v.w;
        }
        int j0 = jt * 64 + g * 8;
        int s = j0 >> 10, c = (j0 >> 7) & 7, fc = j0 & 127;
        unsigned short* dst = (s ? kb : qb) + ((size_t)(b * 8 + c) * 512 + nb * 32 + r) * 128 + fc;
        ushort8 v;
        #pragma unroll
        for (int j = 0; j < 8; ++j) v[j] = f2bf(acc[j]);
        *(ushort8*)dst = v;
    }
}

// ---------------- scores (bf16 MFMA, direct-global fragments) + softmax -> attn fp32
// block: 64 rows x 512 cols per (b,c); wave w owns cols [w*128, w*128+128)
__global__ __launch_bounds__(256) void kS2(const unsigned short* __restrict__ qb,
                                           const unsigned short* __restrict__ kb,
                                           float* __restrict__ attn){
    int b = blockIdx.x, c = blockIdx.y, rb = blockIdx.z;
    int t = threadIdx.x, w = t >> 6, l = t & 63;
    int mrow = l & 15, kq = l >> 4;
    size_t bc = (size_t)(b * 8 + c) * 512;
    const unsigned short* Q  = qb + (bc + rb * 64) * 128;
    const unsigned short* Kp = kb + (bc + w * 128) * 128;
    __shared__ float rmax[4][64];
    __shared__ float rsum[4][64];
    f32x4 acc[4][8];
    #pragma unroll
    for (int fi = 0; fi < 4; ++fi)
        #pragma unroll
        for (int fj = 0; fj < 8; ++fj) acc[fi][fj] = (f32x4){0.f, 0.f, 0.f, 0.f};
    #pragma unroll
    for (int kh = 0; kh < 4; ++kh){
        bf16x8 bfr[8];
        #pragma unroll
        for (int fj = 0; fj < 8; ++fj)
            bfr[fj] = *(const bf16x8*)&Kp[(size_t)(fj * 16 + mrow) * 128 + kh * 32 + kq * 8];
        #pragma unroll
        for (int fi = 0; fi < 4; ++fi){
            bf16x8 af = *(const bf16x8*)&Q[(size_t)(fi * 16 + mrow) * 128 + kh * 32 + kq * 8];
            #pragma unroll
            for (int fj = 0; fj < 8; ++fj)
                acc[fi][fj] = __builtin_amdgcn_mfma_f32_16x16x32_bf16(af, bfr[fj], acc[fi][fj], 0, 0, 0);
        }
    }
    // phase 1: per-row max over this wave's 128 cols
    #pragma unroll
    for (int fi = 0; fi < 4; ++fi){
        #pragma unroll
        for (int r = 0; r < 4; ++r){
            float mx = acc[fi][0][r];
            #pragma unroll
            for (int fj = 1; fj < 8; ++fj) mx = fmaxf(mx, acc[fi][fj][r]);
            mx = fmaxf(mx, __shfl_xor(mx, 1));
            mx = fmaxf(mx, __shfl_xor(mx, 2));
            mx = fmaxf(mx, __shfl_xor(mx, 4));
            mx = fmaxf(mx, __shfl_xor(mx, 8));
            if (mrow == 0) rmax[w][fi * 16 + kq * 4 + r] = mx;
        }
    }
    __syncthreads();
    // phase 2: exp + per-row partial sum
    #pragma unroll
    for (int fi = 0; fi < 4; ++fi){
        #pragma unroll
        for (int r = 0; r < 4; ++r){
            int rl = fi * 16 + kq * 4 + r;
            float gm = fmaxf(fmaxf(rmax[0][rl], rmax[1][rl]), fmaxf(rmax[2][rl], rmax[3][rl]));
            float s = 0.f;
            #pragma unroll
            for (int fj = 0; fj < 8; ++fj){
                float p = __expf((acc[fi][fj][r] - gm) * SM_SCALE);
                acc[fi][fj][r] = p;
                s += p;
            }
            s += __shfl_xor(s, 1);
            s += __shfl_xor(s, 2);
            s += __shfl_xor(s, 4);
            s += __shfl_xor(s, 8);
            if (mrow == 0) rsum[w][rl] = s;
        }
    }
    __syncthreads();
    // phase 3: normalize + write
    #pragma unroll
    for (int fi = 0; fi < 4; ++fi){
        #pragma unroll
        for (int r = 0; r < 4; ++r){
            int rl = fi * 16 + kq * 4 + r;
            float inv = 1.0f / (rsum[0][rl] + rsum[1][rl] + rsum[2][rl] + rsum[3][rl]);
            size_t rowb = (bc + rb * 64 + rl) * 512 + w * 128 + mrow;
            #pragma unroll
            for (int fj = 0; fj < 8; ++fj)
                attn[rowb + fj * 16] = acc[fi][fj][r] * inv;
        }
    }
}

// ---------------- fused: channel-sum top-32 + diag -> mask -> row-normalize -> bf16 NR
// one block per (b,n); 8 channel rows staged in LDS
__global__ __launch_bounds__(256) void kTN(const float* __restrict__ attn, unsigned short* __restrict__ nrb){
    int b = blockIdx.x >> 9, n = blockIdx.x & 511;
    int t = threadIdx.x, w = t >> 6, lane = t & 63;
    __shared__ float al[8][512];
    float4* alv = (float4*)&al[0][0];
    for (int i = t; i < 1024; i += 256){
        int c = i >> 7, q4 = i & 127;
        alv[i] = *(const float4*)&attn[((size_t)(b * 8 + c) * 512 + n) * 512 + q4 * 4];
    }
    __syncthreads();
    // channel sums, lane-major: v[j] = sum_c al[c][j*64+lane]
    float v[8];
    #pragma unroll
    for (int j = 0; j < 8; ++j){
        float s = 0.f;
        #pragma unroll
        for (int c = 0; c < 8; ++c) s += al[c][j * 64 + lane];
        v[j] = s;
    }
    // top-32 extraction (redundant per wave, deterministic), tie-break smaller index
    unsigned int chosen = 0;
    for (int iter = 0; iter < 32; ++iter){
        float bv = -1e30f; int bm = 0x7fffffff;
        #pragma unroll
        for (int j = 0; j < 8; ++j){
            int mm = j * 64 + lane;
            if (v[j] > bv){ bv = v[j]; bm = mm; }
        }
        #pragma unroll
        for (int off = 1; off < 64; off <<= 1){
            float ov = __shfl_xor(bv, off);
            int om = __shfl_xor(bm, off);
            if (ov > bv || (ov == bv && om < bm)){ bv = ov; bm = om; }
        }
        if (lane == (bm & 63)){
            int jj = bm >> 6;
            #pragma unroll
            for (int j = 0; j < 8; ++j) if (j == jj) v[j] = -1e30f;
            chosen |= 1u << jj;
        }
    }
    // per-wave channels: c = w*2, w*2+1; mask = chosen | diagonal
    #pragma unroll
    for (int cc = 0; cc < 2; ++cc){
        int c = w * 2 + cc;
        float e[8]; float rs = 0.f;
        #pragma unroll
        for (int j = 0; j < 8; ++j){
            float a = al[c][j * 64 + lane];
            bool keep = ((chosen >> j) & 1u) || (j * 64 + lane == n);
            e[j] = keep ? a : 0.0f;
            rs += e[j];
        }
        #pragma unroll
        for (int off = 1; off < 64; off <<= 1) rs += __shfl_xor(rs, off);
        float inv = 1.0f / (rs + 1e-6f);
        size_t base = ((size_t)(b * 8 + c) * 512 + n) * 512;
        #pragma unroll
        for (int j = 0; j < 8; ++j) nrb[base + j * 64 + lane] = f2bf(e[j] * inv);
    }
}

// ---------------- column sums of NR (bf16 in, fp32 out)
__global__ __launch_bounds__(1024) void kC(const unsigned short* __restrict__ nrb, float* __restrict__ cs){
    int b = blockIdx.x, c = blockIdx.y, t = threadIdx.x;
    int mm = t & 511, nh = t >> 9;
    const unsigned short* Mp = nrb + (size_t)(b * 8 + c) * 262144;
    float s = 0.f;
    for (int n = nh * 256; n < nh * 256 + 256; ++n) s += bf2f(Mp[(size_t)n * 512 + mm]);
    __shared__ float red[1024];
    red[t] = s;
    __syncthreads();
    if (t < 512) cs[(size_t)(b * 8 + c) * 512 + t] = red[t] + red[t + 512];
}

// ---------------- out = (NR*D^1/2) * (NR*D^1/2)^T per (b,c); D folded into staging
__global__ __launch_bounds__(256) void kF(const unsigned short* __restrict__ S, const float* __restrict__ cs,
                                          float* __restrict__ oe){
    int b = blockIdx.x, c = blockIdx.y, tz = blockIdx.z;
    int nb = (tz >> 2) * 128, mb = (tz & 3) * 128;
    size_t bc = (size_t)(b * 8 + c) * 512;
    const unsigned short* M = S + bc * 512;
    __shared__ unsigned short At[128 * 64];
    __shared__ unsigned short Bt[128 * 64];
    __shared__ float dl[512];
    int t = threadIdx.x;
    for (int i = t; i < 512; i += 256) dl[i] = rsqrtf(cs[bc + i] + 1e-6f);
    int w = t >> 6, l = t & 63;
    int wr = (w >> 1) * 64, wc = (w & 1) * 64;
    f32x4 acc[4][4] = {};
    int srow = t >> 3, sg = t & 7;
    __syncthreads();
    for (int kb = 0; kb < 512; kb += 64){
        __syncthreads();
        float4 d0 = *(const float4*)&dl[kb + sg * 8];
        float4 d1 = *(const float4*)&dl[kb + sg * 8 + 4];
        float dv[8] = {d0.x, d0.y, d0.z, d0.w, d1.x, d1.y, d1.z, d1.w};
        #pragma unroll
        for (int i = 0; i < 4; ++i){
            int row = i * 32 + srow;
            int dstg = sg ^ (row & 7);
            ushort8 va = *(const ushort8*)&M[(size_t)(nb + row) * 512 + kb + sg * 8];
            ushort8 vb = *(const ushort8*)&M[(size_t)(mb + row) * 512 + kb + sg * 8];
            ushort8 wa, wb;
            #pragma unroll
            for (int j = 0; j < 8; ++j){
                wa[j] = f2bf(bf2f(va[j]) * dv[j]);
                wb[j] = f2bf(bf2f(vb[j]) * dv[j]);
            }
            *(ushort8*)&At[row * 64 + dstg * 8] = wa;
            *(ushort8*)&Bt[row * 64 + dstg * 8] = wb;
        }
        __syncthreads();
        #pragma unroll
        for (int kh = 0; kh < 2; ++kh){
            bf16x8 af[4], bfr[4];
            #pragma unroll
            for (int fi = 0; fi < 4; ++fi){
                int row = wr + fi * 16 + (l & 15);
                int g = (kh * 4 + (l >> 4)) ^ (row & 7);
                af[fi] = *(const bf16x8*)&At[row * 64 + g * 8];
            }
            #pragma unroll
            for (int fj = 0; fj < 4; ++fj){
                int row = wc + fj * 16 + (l & 15);
                int g = (kh * 4 + (l >> 4)) ^ (row & 7);
                bfr[fj] = *(const bf16x8*)&Bt[row * 64 + g * 8];
            }
            #pragma unroll
            for (int fi = 0; fi < 4; ++fi)
                #pragma unroll
                for (int fj = 0; fj < 4; ++fj)
                    acc[fi][fj] = __builtin_amdgcn_mfma_f32_16x16x32_bf16(af[fi], bfr[fj], acc[fi][fj], 0, 0, 0);
        }
    }
    #pragma unroll
    for (int fi = 0; fi < 4; ++fi){
        #pragma unroll
        for (int r = 0; r < 4; ++r){
            int n = nb + wr + fi * 16 + (l >> 4) * 4 + r;
            float* orow = oe + (bc + n) * 512 + mb + wc + (l & 15);
            #pragma unroll
            for (int fj = 0; fj < 4; ++fj) orow[fj * 16] = acc[fi][fj][r];
        }
    }
}

extern "C" void kernel_launch(void* const* d_in, const int* in_sizes, int n_in,
                              void* d_out, int out_size, void* d_ws, size_t ws_size,
                              hipStream_t stream) {
    const float* inp = (const float*)d_in[0];
    const float* w1  = (const float*)d_in[1];
    const float* b1  = (const float*)d_in[2];
    const float* w2  = (const float*)d_in[3];
    const float* b2  = (const float*)d_in[4];
    const float* wqk = (const float*)d_in[5];

    float* out_nf   = (float*)d_out;                       // [16][512][128]
    float* out_edge = out_nf + (size_t)16 * 512 * 128;     // [16][8][512][512]

    char* ws = (char*)d_ws;
    float* inv_s = (float*)ws;                             // 256 floats
    // region A (134 MB): q/k bf16 during kQK/kS2, then reused as bf16 NR
    unsigned short* qb  = (unsigned short*)(ws + 4096);            // [16][8][512][128] bf16
    unsigned short* kbuf = qb + (size_t)16 * 8 * 512 * 128;        // [16][8][512][128] bf16
    unsigned short* nrb = qb;                                       // [16][8][512][512] bf16 (aliases q+k, dead)
    // region B (268 MB): attn fp32; G/G2 alias it (dead before attn written)
    float* attn = (float*)(ws + 4096 + (size_t)134 * 1024 * 1024);
    unsigned short* Gb  = (unsigned short*)attn;
    unsigned short* G2b = Gb + (size_t)256 * 65536;
    float* csum = attn + (size_t)16 * 8 * 512 * 512;       // [16][8][512]

    kG  <<<256, 512, 0, stream>>>(w1, w2, Gb);
    kG2 <<<256, 512, 0, stream>>>(Gb, G2b);
    kP2 <<<256, 1024, 148608, stream>>>(w1, w2, G2b, inv_s);
    kMLP<<<128, 256, 0, stream>>>(inp, w1, b1, w2, b2, inv_s, out_nf);
    kQK <<<dim3(16, 16), 256, 0, stream>>>(out_nf, wqk, qb, kbuf);
    kS2 <<<dim3(16, 8, 8), 256, 0, stream>>>(qb, kbuf, attn);
    kTN <<<8192, 256, 0, stream>>>(attn, nrb);
    kC  <<<dim3(16, 8), 1024, 0, stream>>>(nrb, csum);
    kF  <<<dim3(16, 8, 16), 256, 0, stream>>>(nrb, csum, out_edge);
}

// Round 5
// 682.896 us; speedup vs baseline: 2.5220x; 1.1738x over previous
//
#include <hip/hip_runtime.h>
#include <hip/hip_bf16.h>
#include <math.h>

#define NFR 128
#define IND 256
#define ONODES 512

static constexpr float SM_SCALE = 0.08838834764831845f; // 128^-0.5

typedef __attribute__((ext_vector_type(8))) short bf16x8;
typedef __attribute__((ext_vector_type(4))) float f32x4;
typedef __attribute__((ext_vector_type(8))) unsigned short ushort8;

__device__ __forceinline__ unsigned short f2bf(float f){
    unsigned int b = __float_as_uint(f);
    b = (b + 0x7fffu + ((b >> 16) & 1u)) >> 16;
    return (unsigned short)b;
}
__device__ __forceinline__ float bf2f(unsigned short u){
    return __uint_as_float(((unsigned int)u) << 16);
}

// ---------------- G[m] = W_m * W_m^T (256x256) via bf16 MFMA; bf16 output.
__global__ __launch_bounds__(512) void kG(const float* __restrict__ w1, const float* __restrict__ w2,
                                          unsigned short* __restrict__ Gb){
    int m = blockIdx.x;
    const float* W; int K;
    if (m < NFR){ W = w1 + (size_t)m * IND * IND; K = IND; }
    else        { W = w2 + (size_t)(m - NFR) * IND * ONODES; K = ONODES; }
    __shared__ unsigned short Wt[256 * 64]; // rows x 64 k, bf16, granule-swizzled
    int t = threadIdx.x;
    int w = t >> 6, l = t & 63;
    int wr = (w >> 2) * 128, wc = (w & 3) * 64;
    f32x4 acc[8][4] = {};
    int srow = t >> 3, sg = t & 7;
    for (int kb = 0; kb < K; kb += 64){
        __syncthreads();
        #pragma unroll
        for (int i = 0; i < 4; ++i){
            int row = i * 64 + srow;
            int dstg = sg ^ (row & 7);
            const float* src = &W[(size_t)row * K + kb + sg * 8];
            float4 f0 = *(const float4*)src;
            float4 f1 = *(const float4*)(src + 4);
            ushort8 v;
            v[0] = f2bf(f0.x); v[1] = f2bf(f0.y); v[2] = f2bf(f0.z); v[3] = f2bf(f0.w);
            v[4] = f2bf(f1.x); v[5] = f2bf(f1.y); v[6] = f2bf(f1.z); v[7] = f2bf(f1.w);
            *(ushort8*)&Wt[row * 64 + dstg * 8] = v;
        }
        __syncthreads();
        #pragma unroll
        for (int kh = 0; kh < 2; ++kh){
            bf16x8 af[8], bfr[4];
            #pragma unroll
            for (int fi = 0; fi < 8; ++fi){
                int row = wr + fi * 16 + (l & 15);
                int g = (kh * 4 + (l >> 4)) ^ (row & 7);
                af[fi] = *(const bf16x8*)&Wt[row * 64 + g * 8];
            }
            #pragma unroll
            for (int fj = 0; fj < 4; ++fj){
                int row = wc + fj * 16 + (l & 15);
                int g = (kh * 4 + (l >> 4)) ^ (row & 7);
                bfr[fj] = *(const bf16x8*)&Wt[row * 64 + g * 8];
            }
            #pragma unroll
            for (int fi = 0; fi < 8; ++fi)
                #pragma unroll
                for (int fj = 0; fj < 4; ++fj)
                    acc[fi][fj] = __builtin_amdgcn_mfma_f32_16x16x32_bf16(af[fi], bfr[fj], acc[fi][fj], 0, 0, 0);
        }
    }
    unsigned short* Gm = Gb + (size_t)m * 65536;
    #pragma unroll
    for (int fi = 0; fi < 8; ++fi){
        #pragma unroll
        for (int r = 0; r < 4; ++r){
            int n = wr + fi * 16 + (l >> 4) * 4 + r;
            unsigned short* grow = Gm + (size_t)n * 256 + wc + (l & 15);
            #pragma unroll
            for (int fj = 0; fj < 4; ++fj) grow[fj * 16] = f2bf(acc[fi][fj][r]);
        }
    }
}

// ---------------- G2[m] = G[m] * G[m] (bf16 in/out, symmetric so == G*G^T)
__global__ __launch_bounds__(512) void kG2(const unsigned short* __restrict__ Gb,
                                           unsigned short* __restrict__ G2b){
    int m = blockIdx.x;
    const unsigned short* Gm = Gb + (size_t)m * 65536;
    __shared__ unsigned short Wt[256 * 64];
    int t = threadIdx.x;
    int w = t >> 6, l = t & 63;
    int wr = (w >> 2) * 128, wc = (w & 3) * 64;
    f32x4 acc[8][4] = {};
    int srow = t >> 3, sg = t & 7;
    for (int kb = 0; kb < 256; kb += 64){
        __syncthreads();
        #pragma unroll
        for (int i = 0; i < 4; ++i){
            int row = i * 64 + srow;
            int dstg = sg ^ (row & 7);
            ushort8 v = *(const ushort8*)&Gm[(size_t)row * 256 + kb + sg * 8];
            *(ushort8*)&Wt[row * 64 + dstg * 8] = v;
        }
        __syncthreads();
        #pragma unroll
        for (int kh = 0; kh < 2; ++kh){
            bf16x8 af[8], bfr[4];
            #pragma unroll
            for (int fi = 0; fi < 8; ++fi){
                int row = wr + fi * 16 + (l & 15);
                int g = (kh * 4 + (l >> 4)) ^ (row & 7);
                af[fi] = *(const bf16x8*)&Wt[row * 64 + g * 8];
            }
            #pragma unroll
            for (int fj = 0; fj < 4; ++fj){
                int row = wc + fj * 16 + (l & 15);
                int g = (kh * 4 + (l >> 4)) ^ (row & 7);
                bfr[fj] = *(const bf16x8*)&Wt[row * 64 + g * 8];
            }
            #pragma unroll
            for (int fi = 0; fi < 8; ++fi)
                #pragma unroll
                for (int fj = 0; fj < 4; ++fj)
                    acc[fi][fj] = __builtin_amdgcn_mfma_f32_16x16x32_bf16(af[fi], bfr[fj], acc[fi][fj], 0, 0, 0);
        }
    }
    unsigned short* Om = G2b + (size_t)m * 65536;
    #pragma unroll
    for (int fi = 0; fi < 8; ++fi){
        #pragma unroll
        for (int r = 0; r < 4; ++r){
            int n = wr + fi * 16 + (l >> 4) * 4 + r;
            unsigned short* grow = Om + (size_t)n * 256 + wc + (l & 15);
            #pragma unroll
            for (int fj = 0; fj < 4; ++fj) grow[fj * 16] = f2bf(acc[fi][fj][r]);
        }
    }
}

// ---------------- power iteration on G2 (bf16 LDS, 16 waves) + Rayleigh vs fp32 W
__global__ __launch_bounds__(1024) void kP2(const float* __restrict__ w1, const float* __restrict__ w2,
                                            const unsigned short* __restrict__ G2b, float* __restrict__ inv_s){
    extern __shared__ char smem[];
    unsigned short* Gl = (unsigned short*)smem;            // 65536 ushorts = 131072 B
    float* yred = (float*)(smem + 131072);                 // 4096 floats = 16384 B
    float* xv   = (float*)(smem + 147456);                 // 256 floats
    float* red  = (float*)(smem + 148480);                 // 32 floats
    int m = blockIdx.x, t = threadIdx.x;
    {
        const ushort8* src = (const ushort8*)(G2b + (size_t)m * 65536);
        ushort8* dst = (ushort8*)Gl;
        #pragma unroll
        for (int i = 0; i < 8; ++i) dst[t + i * 1024] = src[t + i * 1024];
    }
    if (t < 256){
        unsigned int h = (unsigned int)t * 2654435761u ^ 0x9e3779b9u;
        h ^= h >> 13; h *= 0x85ebca6bu; h ^= h >> 16;
        xv[t] = 0.5f + (float)(h & 0xffffu) * (1.0f / 65536.0f);
    }
    __syncthreads();
    int rid = t & 63, seg = t >> 6;   // seg 0..15, rows 4rid..4rid+3, j in [16seg,16seg+16)
    int lane = t & 63;
    for (int it = 0; it < 64; ++it){
        float a0 = 0.f, a1 = 0.f, a2 = 0.f, a3 = 0.f;
        #pragma unroll
        for (int jj = 0; jj < 16; ++jj){
            int j = seg * 16 + jj;
            float xb = xv[j];
            uint2 g = *(const uint2*)&Gl[(size_t)j * 256 + 4 * rid];
            a0 += bf2f((unsigned short)(g.x & 0xffffu)) * xb;
            a1 += bf2f((unsigned short)(g.x >> 16)) * xb;
            a2 += bf2f((unsigned short)(g.y & 0xffffu)) * xb;
            a3 += bf2f((unsigned short)(g.y >> 16)) * xb;
        }
        *(float4*)&yred[seg * 256 + 4 * rid] = make_float4(a0, a1, a2, a3);
        __syncthreads();
        float yv = 0.f;
        if (t < 256){
            #pragma unroll
            for (int s = 0; s < 16; ++s) yv += yred[s * 256 + t];
            float ss = yv * yv;
            #pragma unroll
            for (int off = 32; off; off >>= 1) ss += __shfl_xor(ss, off);
            if (lane == 0) red[t >> 6] = ss;
        }
        __syncthreads();
        if (t < 256){
            float ss = red[0] + red[1] + red[2] + red[3];
            xv[t] = yv * rsqrtf(ss);
        }
        __syncthreads();
    }
    const float* W; int K;
    if (m < NFR){ W = w1 + (size_t)m * IND * IND; K = IND; }
    else        { W = w2 + (size_t)(m - NFR) * IND * ONODES; K = ONODES; }
    float zsq = 0.f;
    for (int o = t; o < K; o += 1024){
        float z = 0.f;
        for (int d = 0; d < 256; ++d) z += W[(size_t)d * K + o] * xv[d];
        zsq += z * z;
    }
    #pragma unroll
    for (int off = 32; off; off >>= 1) zsq += __shfl_xor(zsq, off);
    if (lane == 0) red[16 + (t >> 6)] = zsq;
    __syncthreads();
    if (t == 0){
        float rho = 0.f;
        #pragma unroll
        for (int i = 0; i < 16; ++i) rho += red[16 + i];
        float sg = sqrtf(fmaxf(rho, 0.f));
        inv_s[m] = 1.0f / fmaxf(sg, 1e-6f);
    }
}

// ---------------- per-frame MLP, writes node_features transposed [b][node][frame]
__global__ __launch_bounds__(256) void kMLP(const float* __restrict__ inp, const float* __restrict__ w1,
                                            const float* __restrict__ b1, const float* __restrict__ w2,
                                            const float* __restrict__ b2, const float* __restrict__ inv_s,
                                            float* __restrict__ nf){
    int n = blockIdx.x, t = threadIdx.x;
    __shared__ float xl[16][IND];
    __shared__ float hl[16][IND];
    float i1 = inv_s[n], i2 = inv_s[NFR + n];
    for (int i = t; i < 16 * IND; i += 256){
        int b = i >> 8, d = i & 255;
        xl[b][d] = inp[(size_t)b * (NFR * IND) + (size_t)n * IND + d];
    }
    __syncthreads();
    const float* W1 = w1 + (size_t)n * IND * IND;
    float acc[16] = {};
    for (int d = 0; d < IND; ++d){
        float w = W1[(size_t)d * IND + t];
        #pragma unroll
        for (int b = 0; b < 16; ++b) acc[b] += xl[b][d] * w;
    }
    float bb = b1[(size_t)n * IND + t];
    #pragma unroll
    for (int b = 0; b < 16; ++b){
        float h = acc[b] * i1 + bb;
        h = 0.5f * h * (1.0f + erff(h * 0.70710678118654752f));
        hl[b][t] = h;
    }
    __syncthreads();
    const float* W2 = w2 + (size_t)n * IND * ONODES;
    float o0[16] = {}, o1[16] = {};
    for (int d = 0; d < IND; ++d){
        float wa = W2[(size_t)d * ONODES + t];
        float wb = W2[(size_t)d * ONODES + t + 256];
        #pragma unroll
        for (int b = 0; b < 16; ++b){ float h = hl[b][d]; o0[b] += h * wa; o1[b] += h * wb; }
    }
    float bb0 = b2[(size_t)n * ONODES + t], bb1 = b2[(size_t)n * ONODES + t + 256];
    #pragma unroll
    for (int b = 0; b < 16; ++b){
        nf[(size_t)b * (ONODES * NFR) + (size_t)t * NFR + n]         = o0[b] * i2 + bb0;
        nf[(size_t)b * (ONODES * NFR) + (size_t)(t + 256) * NFR + n] = o1[b] * i2 + bb1;
    }
}

// ---------------- qk projection: q/k [b][c][node][f] in bf16
__global__ __launch_bounds__(256) void kQK(const float* __restrict__ nf, const float* __restrict__ wqk,
                                           unsigned short* __restrict__ qb, unsigned short* __restrict__ kb){
    int b = blockIdx.x, nb = blockIdx.y, t = threadIdx.x;
    __shared__ float xs[32][132];
    __shared__ float wl[128][68];
    for (int i = t; i < 32 * 128; i += 256){
        int r = i >> 7, f = i & 127;
        xs[r][f] = nf[(size_t)b * 65536 + (size_t)(nb * 32 + r) * 128 + f];
    }
    int r = t >> 3, g = t & 7;
    for (int jt = 0; jt < 32; ++jt){
        __syncthreads();
        for (int i = t; i < 64 * 128; i += 256){
            int f = i >> 6, jl = i & 63;
            wl[f][jl] = wqk[(size_t)f * 2048 + jt * 64 + jl];
        }
        __syncthreads();
        float acc[8] = {};
        for (int f = 0; f < 128; ++f){
            float xvv = xs[r][f];
            float4 w0 = *(const float4*)&wl[f][g * 8];
            float4 w1v = *(const float4*)&wl[f][g * 8 + 4];
            acc[0] += xvv * w0.x; acc[1] += xvv * w0.y; acc[2] += xvv * w0.z; acc[3] += xvv * w0.w;
            acc[4] += xvv * w1v.x; acc[5] += xvv * w1v.y; acc[6] += xvv * w1v.z; acc[7] += xvv * w1v.w;
        }
        int j0 = jt * 64 + g * 8;
        int s = j0 >> 10, c = (j0 >> 7) & 7, fc = j0 & 127;
        unsigned short* dst = (s ? kb : qb) + ((size_t)(b * 8 + c) * 512 + nb * 32 + r) * 128 + fc;
        ushort8 v;
        #pragma unroll
        for (int j = 0; j < 8; ++j) v[j] = f2bf(acc[j]);
        *(ushort8*)dst = v;
    }
}

// ---------------- scores (bf16 MFMA, direct-global fragments) + softmax -> attn fp32
// block: 64 rows x 512 cols per (b,c); wave w owns cols [w*128, w*128+128)
__global__ __launch_bounds__(256) void kS2(const unsigned short* __restrict__ qb,
                                           const unsigned short* __restrict__ kb,
                                           float* __restrict__ attn){
    int b = blockIdx.x, c = blockIdx.y, rb = blockIdx.z;
    int t = threadIdx.x, w = t >> 6, l = t & 63;
    int mrow = l & 15, kq = l >> 4;
    size_t bc = (size_t)(b * 8 + c) * 512;
    const unsigned short* Q  = qb + (bc + rb * 64) * 128;
    const unsigned short* Kp = kb + (bc + w * 128) * 128;
    __shared__ float rmax[4][64];
    __shared__ float rsum[4][64];
    f32x4 acc[4][8];
    #pragma unroll
    for (int fi = 0; fi < 4; ++fi)
        #pragma unroll
        for (int fj = 0; fj < 8; ++fj) acc[fi][fj] = (f32x4){0.f, 0.f, 0.f, 0.f};
    #pragma unroll
    for (int kh = 0; kh < 4; ++kh){
        bf16x8 bfr[8];
        #pragma unroll
        for (int fj = 0; fj < 8; ++fj)
            bfr[fj] = *(const bf16x8*)&Kp[(size_t)(fj * 16 + mrow) * 128 + kh * 32 + kq * 8];
        #pragma unroll
        for (int fi = 0; fi < 4; ++fi){
            bf16x8 af = *(const bf16x8*)&Q[(size_t)(fi * 16 + mrow) * 128 + kh * 32 + kq * 8];
            #pragma unroll
            for (int fj = 0; fj < 8; ++fj)
                acc[fi][fj] = __builtin_amdgcn_mfma_f32_16x16x32_bf16(af, bfr[fj], acc[fi][fj], 0, 0, 0);
        }
    }
    // phase 1: per-row max over this wave's 128 cols
    #pragma unroll
    for (int fi = 0; fi < 4; ++fi){
        #pragma unroll
        for (int r = 0; r < 4; ++r){
            float mx = acc[fi][0][r];
            #pragma unroll
            for (int fj = 1; fj < 8; ++fj) mx = fmaxf(mx, acc[fi][fj][r]);
            mx = fmaxf(mx, __shfl_xor(mx, 1));
            mx = fmaxf(mx, __shfl_xor(mx, 2));
            mx = fmaxf(mx, __shfl_xor(mx, 4));
            mx = fmaxf(mx, __shfl_xor(mx, 8));
            if (mrow == 0) rmax[w][fi * 16 + kq * 4 + r] = mx;
        }
    }
    __syncthreads();
    // phase 2: exp + per-row partial sum
    #pragma unroll
    for (int fi = 0; fi < 4; ++fi){
        #pragma unroll
        for (int r = 0; r < 4; ++r){
            int rl = fi * 16 + kq * 4 + r;
            float gm = fmaxf(fmaxf(rmax[0][rl], rmax[1][rl]), fmaxf(rmax[2][rl], rmax[3][rl]));
            float s = 0.f;
            #pragma unroll
            for (int fj = 0; fj < 8; ++fj){
                float p = __expf((acc[fi][fj][r] - gm) * SM_SCALE);
                acc[fi][fj][r] = p;
                s += p;
            }
            s += __shfl_xor(s, 1);
            s += __shfl_xor(s, 2);
            s += __shfl_xor(s, 4);
            s += __shfl_xor(s, 8);
            if (mrow == 0) rsum[w][rl] = s;
        }
    }
    __syncthreads();
    // phase 3: normalize + write
    #pragma unroll
    for (int fi = 0; fi < 4; ++fi){
        #pragma unroll
        for (int r = 0; r < 4; ++r){
            int rl = fi * 16 + kq * 4 + r;
            float inv = 1.0f / (rsum[0][rl] + rsum[1][rl] + rsum[2][rl] + rsum[3][rl]);
            size_t rowb = (bc + rb * 64 + rl) * 512 + w * 128 + mrow;
            #pragma unroll
            for (int fj = 0; fj < 8; ++fj)
                attn[rowb + fj * 16] = acc[fi][fj][r] * inv;
        }
    }
}

// ---------------- fused: channel-sum radix-select top-32 + diag -> mask -> row-normalize -> bf16 NR
// one block per (b,n); 8 channel rows staged in LDS; wave 0 does the select
__global__ __launch_bounds__(256) void kTN(const float* __restrict__ attn, unsigned short* __restrict__ nrb){
    int b = blockIdx.x >> 9, n = blockIdx.x & 511;
    int t = threadIdx.x, w = t >> 6, lane = t & 63;
    __shared__ float al[8][512];
    __shared__ unsigned long long keepm[8];
    float4* alv = (float4*)&al[0][0];
    for (int i = t; i < 1024; i += 256){
        int c = i >> 7, q4 = i & 127;
        alv[i] = *(const float4*)&attn[((size_t)(b * 8 + c) * 512 + n) * 512 + q4 * 4];
    }
    __syncthreads();
    if (w == 0){
        // channel sums: v[j] = sum_c al[c][j*64+lane]; all positive -> uint order == float order
        unsigned int vb[8];
        #pragma unroll
        for (int j = 0; j < 8; ++j){
            float s = 0.f;
            #pragma unroll
            for (int c = 0; c < 8; ++c) s += al[c][j * 64 + lane];
            vb[j] = __float_as_uint(s);
        }
        // radix binary search for the 32nd-largest bit pattern T
        unsigned int T = 0u;
        for (int bit = 31; bit >= 0; --bit){
            unsigned int cand = T | (1u << bit);
            int cnt = 0;
            #pragma unroll
            for (int j = 0; j < 8; ++j) cnt += __popcll(__ballot(vb[j] >= cand));
            if (cnt >= 32) T = cand;
        }
        // keep: all > T, plus smallest-index ties == T up to 32 total
        int cntgt = 0;
        #pragma unroll
        for (int j = 0; j < 8; ++j) cntgt += __popcll(__ballot(vb[j] > T));
        int need = 32 - cntgt;
        unsigned long long lmask = (1ull << lane) - 1ull;
        int run = 0;
        #pragma unroll
        for (int j = 0; j < 8; ++j){
            bool eq = (vb[j] == T);
            unsigned long long eqm = __ballot(eq);
            int rank = run + __popcll(eqm & lmask);
            bool kv = (vb[j] > T) || (eq && rank < need);
            unsigned long long km = __ballot(kv);
            if (lane == 0) keepm[j] = km;
            run += __popcll(eqm);
        }
    }
    __syncthreads();
    // per-wave channels: c = w*2, w*2+1; mask = keepm | diagonal
    #pragma unroll
    for (int cc = 0; cc < 2; ++cc){
        int c = w * 2 + cc;
        float e[8]; float rs = 0.f;
        #pragma unroll
        for (int j = 0; j < 8; ++j){
            float a = al[c][j * 64 + lane];
            bool keep = ((keepm[j] >> lane) & 1ull) || (j * 64 + lane == n);
            e[j] = keep ? a : 0.0f;
            rs += e[j];
        }
        #pragma unroll
        for (int off = 1; off < 64; off <<= 1) rs += __shfl_xor(rs, off);
        float inv = 1.0f / (rs + 1e-6f);
        size_t base = ((size_t)(b * 8 + c) * 512 + n) * 512;
        #pragma unroll
        for (int j = 0; j < 8; ++j) nrb[base + j * 64 + lane] = f2bf(e[j] * inv);
    }
}

// ---------------- column sums of NR (bf16 in, fp32 out)
__global__ __launch_bounds__(1024) void kC(const unsigned short* __restrict__ nrb, float* __restrict__ cs){
    int b = blockIdx.x, c = blockIdx.y, t = threadIdx.x;
    int mm = t & 511, nh = t >> 9;
    const unsigned short* Mp = nrb + (size_t)(b * 8 + c) * 262144;
    float s = 0.f;
    for (int n = nh * 256; n < nh * 256 + 256; ++n) s += bf2f(Mp[(size_t)n * 512 + mm]);
    __shared__ float red[1024];
    red[t] = s;
    __syncthreads();
    if (t < 512) cs[(size_t)(b * 8 + c) * 512 + t] = red[t] + red[t + 512];
}

// ---------------- out = (NR*D^1/2) * (NR*D^1/2)^T per (b,c); D folded into staging
__global__ __launch_bounds__(256) void kF(const unsigned short* __restrict__ S, const float* __restrict__ cs,
                                          float* __restrict__ oe){
    int b = blockIdx.x, c = blockIdx.y, tz = blockIdx.z;
    int nb = (tz >> 2) * 128, mb = (tz & 3) * 128;
    size_t bc = (size_t)(b * 8 + c) * 512;
    const unsigned short* M = S + bc * 512;
    __shared__ unsigned short At[128 * 64];
    __shared__ unsigned short Bt[128 * 64];
    __shared__ float dl[512];
    int t = threadIdx.x;
    for (int i = t; i < 512; i += 256) dl[i] = rsqrtf(cs[bc + i] + 1e-6f);
    int w = t >> 6, l = t & 63;
    int wr = (w >> 1) * 64, wc = (w & 1) * 64;
    f32x4 acc[4][4] = {};
    int srow = t >> 3, sg = t & 7;
    __syncthreads();
    for (int kb = 0; kb < 512; kb += 64){
        __syncthreads();
        float4 d0 = *(const float4*)&dl[kb + sg * 8];
        float4 d1 = *(const float4*)&dl[kb + sg * 8 + 4];
        float dv[8] = {d0.x, d0.y, d0.z, d0.w, d1.x, d1.y, d1.z, d1.w};
        #pragma unroll
        for (int i = 0; i < 4; ++i){
            int row = i * 32 + srow;
            int dstg = sg ^ (row & 7);
            ushort8 va = *(const ushort8*)&M[(size_t)(nb + row) * 512 + kb + sg * 8];
            ushort8 vb = *(const ushort8*)&M[(size_t)(mb + row) * 512 + kb + sg * 8];
            ushort8 wa, wb;
            #pragma unroll
            for (int j = 0; j < 8; ++j){
                wa[j] = f2bf(bf2f(va[j]) * dv[j]);
                wb[j] = f2bf(bf2f(vb[j]) * dv[j]);
            }
            *(ushort8*)&At[row * 64 + dstg * 8] = wa;
            *(ushort8*)&Bt[row * 64 + dstg * 8] = wb;
        }
        __syncthreads();
        #pragma unroll
        for (int kh = 0; kh < 2; ++kh){
            bf16x8 af[4], bfr[4];
            #pragma unroll
            for (int fi = 0; fi < 4; ++fi){
                int row = wr + fi * 16 + (l & 15);
                int g = (kh * 4 + (l >> 4)) ^ (row & 7);
                af[fi] = *(const bf16x8*)&At[row * 64 + g * 8];
            }
            #pragma unroll
            for (int fj = 0; fj < 4; ++fj){
                int row = wc + fj * 16 + (l & 15);
                int g = (kh * 4 + (l >> 4)) ^ (row & 7);
                bfr[fj] = *(const bf16x8*)&Bt[row * 64 + g * 8];
            }
            #pragma unroll
            for (int fi = 0; fi < 4; ++fi)
                #pragma unroll
                for (int fj = 0; fj < 4; ++fj)
                    acc[fi][fj] = __builtin_amdgcn_mfma_f32_16x16x32_bf16(af[fi], bfr[fj], acc[fi][fj], 0, 0, 0);
        }
    }
    #pragma unroll
    for (int fi = 0; fi < 4; ++fi){
        #pragma unroll
        for (int r = 0; r < 4; ++r){
            int n = nb + wr + fi * 16 + (l >> 4) * 4 + r;
            float* orow = oe + (bc + n) * 512 + mb + wc + (l & 15);
            #pragma unroll
            for (int fj = 0; fj < 4; ++fj) orow[fj * 16] = acc[fi][fj][r];
        }
    }
}

extern "C" void kernel_launch(void* const* d_in, const int* in_sizes, int n_in,
                              void* d_out, int out_size, void* d_ws, size_t ws_size,
                              hipStream_t stream) {
    const float* inp = (const float*)d_in[0];
    const float* w1  = (const float*)d_in[1];
    const float* b1  = (const float*)d_in[2];
    const float* w2  = (const float*)d_in[3];
    const float* b2  = (const float*)d_in[4];
    const float* wqk = (const float*)d_in[5];

    float* out_nf   = (float*)d_out;                       // [16][512][128]
    float* out_edge = out_nf + (size_t)16 * 512 * 128;     // [16][8][512][512]

    char* ws = (char*)d_ws;
    float* inv_s = (float*)ws;                             // 256 floats
    // region A (134 MB): q/k bf16 during kQK/kS2, then reused as bf16 NR
    unsigned short* qb  = (unsigned short*)(ws + 4096);            // [16][8][512][128] bf16
    unsigned short* kbuf = qb + (size_t)16 * 8 * 512 * 128;        // [16][8][512][128] bf16
    unsigned short* nrb = qb;                                       // [16][8][512][512] bf16 (aliases q+k, dead)
    // region B (268 MB): attn fp32; G/G2 alias it (dead before attn written)
    float* attn = (float*)(ws + 4096 + (size_t)134 * 1024 * 1024);
    unsigned short* Gb  = (unsigned short*)attn;
    unsigned short* G2b = Gb + (size_t)256 * 65536;
    float* csum = attn + (size_t)16 * 8 * 512 * 512;       // [16][8][512]

    kG  <<<256, 512, 0, stream>>>(w1, w2, Gb);
    kG2 <<<256, 512, 0, stream>>>(Gb, G2b);
    kP2 <<<256, 1024, 148608, stream>>>(w1, w2, G2b, inv_s);
    kMLP<<<128, 256, 0, stream>>>(inp, w1, b1, w2, b2, inv_s, out_nf);
    kQK <<<dim3(16, 16), 256, 0, stream>>>(out_nf, wqk, qb, kbuf);
    kS2 <<<dim3(16, 8, 8), 256, 0, stream>>>(qb, kbuf, attn);
    kTN <<<8192, 256, 0, stream>>>(attn, nrb);
    kC  <<<dim3(16, 8), 1024, 0, stream>>>(nrb, csum);
    kF  <<<dim3(16, 8, 16), 256, 0, stream>>>(nrb, csum, out_edge);
}

// Round 6
// 562.088 us; speedup vs baseline: 3.0641x; 1.2149x over previous
//
#include <hip/hip_runtime.h>
#include <hip/hip_bf16.h>
#include <math.h>

#define NFR 128
#define IND 256
#define ONODES 512

static constexpr float SM_SCALE = 0.08838834764831845f; // 128^-0.5

typedef __attribute__((ext_vector_type(8))) short bf16x8;
typedef __attribute__((ext_vector_type(4))) float f32x4;
typedef __attribute__((ext_vector_type(8))) unsigned short ushort8;

__device__ __forceinline__ unsigned short f2bf(float f){
    unsigned int b = __float_as_uint(f);
    b = (b + 0x7fffu + ((b >> 16) & 1u)) >> 16;
    return (unsigned short)b;
}
__device__ __forceinline__ float bf2f(unsigned short u){
    return __uint_as_float(((unsigned int)u) << 16);
}

// ---------------- G[m] = W_m * W_m^T (256x256) via bf16 MFMA; bf16 output.
__global__ __launch_bounds__(512) void kG(const float* __restrict__ w1, const float* __restrict__ w2,
                                          unsigned short* __restrict__ Gb){
    int m = blockIdx.x;
    const float* W; int K;
    if (m < NFR){ W = w1 + (size_t)m * IND * IND; K = IND; }
    else        { W = w2 + (size_t)(m - NFR) * IND * ONODES; K = ONODES; }
    __shared__ unsigned short Wt[256 * 64]; // rows x 64 k, bf16, granule-swizzled
    int t = threadIdx.x;
    int w = t >> 6, l = t & 63;
    int wr = (w >> 2) * 128, wc = (w & 3) * 64;
    f32x4 acc[8][4] = {};
    int srow = t >> 3, sg = t & 7;
    for (int kb = 0; kb < K; kb += 64){
        __syncthreads();
        #pragma unroll
        for (int i = 0; i < 4; ++i){
            int row = i * 64 + srow;
            int dstg = sg ^ (row & 7);
            const float* src = &W[(size_t)row * K + kb + sg * 8];
            float4 f0 = *(const float4*)src;
            float4 f1 = *(const float4*)(src + 4);
            ushort8 v;
            v[0] = f2bf(f0.x); v[1] = f2bf(f0.y); v[2] = f2bf(f0.z); v[3] = f2bf(f0.w);
            v[4] = f2bf(f1.x); v[5] = f2bf(f1.y); v[6] = f2bf(f1.z); v[7] = f2bf(f1.w);
            *(ushort8*)&Wt[row * 64 + dstg * 8] = v;
        }
        __syncthreads();
        #pragma unroll
        for (int kh = 0; kh < 2; ++kh){
            bf16x8 af[8], bfr[4];
            #pragma unroll
            for (int fi = 0; fi < 8; ++fi){
                int row = wr + fi * 16 + (l & 15);
                int g = (kh * 4 + (l >> 4)) ^ (row & 7);
                af[fi] = *(const bf16x8*)&Wt[row * 64 + g * 8];
            }
            #pragma unroll
            for (int fj = 0; fj < 4; ++fj){
                int row = wc + fj * 16 + (l & 15);
                int g = (kh * 4 + (l >> 4)) ^ (row & 7);
                bfr[fj] = *(const bf16x8*)&Wt[row * 64 + g * 8];
            }
            #pragma unroll
            for (int fi = 0; fi < 8; ++fi)
                #pragma unroll
                for (int fj = 0; fj < 4; ++fj)
                    acc[fi][fj] = __builtin_amdgcn_mfma_f32_16x16x32_bf16(af[fi], bfr[fj], acc[fi][fj], 0, 0, 0);
        }
    }
    unsigned short* Gm = Gb + (size_t)m * 65536;
    #pragma unroll
    for (int fi = 0; fi < 8; ++fi){
        #pragma unroll
        for (int r = 0; r < 4; ++r){
            int n = wr + fi * 16 + (l >> 4) * 4 + r;
            unsigned short* grow = Gm + (size_t)n * 256 + wc + (l & 15);
            #pragma unroll
            for (int fj = 0; fj < 4; ++fj) grow[fj * 16] = f2bf(acc[fi][fj][r]);
        }
    }
}

// ---------------- G2[m] = G[m] * G[m] (bf16 in/out, symmetric so == G*G^T)
__global__ __launch_bounds__(512) void kG2(const unsigned short* __restrict__ Gb,
                                           unsigned short* __restrict__ G2b){
    int m = blockIdx.x;
    const unsigned short* Gm = Gb + (size_t)m * 65536;
    __shared__ unsigned short Wt[256 * 64];
    int t = threadIdx.x;
    int w = t >> 6, l = t & 63;
    int wr = (w >> 2) * 128, wc = (w & 3) * 64;
    f32x4 acc[8][4] = {};
    int srow = t >> 3, sg = t & 7;
    for (int kb = 0; kb < 256; kb += 64){
        __syncthreads();
        #pragma unroll
        for (int i = 0; i < 4; ++i){
            int row = i * 64 + srow;
            int dstg = sg ^ (row & 7);
            ushort8 v = *(const ushort8*)&Gm[(size_t)row * 256 + kb + sg * 8];
            *(ushort8*)&Wt[row * 64 + dstg * 8] = v;
        }
        __syncthreads();
        #pragma unroll
        for (int kh = 0; kh < 2; ++kh){
            bf16x8 af[8], bfr[4];
            #pragma unroll
            for (int fi = 0; fi < 8; ++fi){
                int row = wr + fi * 16 + (l & 15);
                int g = (kh * 4 + (l >> 4)) ^ (row & 7);
                af[fi] = *(const bf16x8*)&Wt[row * 64 + g * 8];
            }
            #pragma unroll
            for (int fj = 0; fj < 4; ++fj){
                int row = wc + fj * 16 + (l & 15);
                int g = (kh * 4 + (l >> 4)) ^ (row & 7);
                bfr[fj] = *(const bf16x8*)&Wt[row * 64 + g * 8];
            }
            #pragma unroll
            for (int fi = 0; fi < 8; ++fi)
                #pragma unroll
                for (int fj = 0; fj < 4; ++fj)
                    acc[fi][fj] = __builtin_amdgcn_mfma_f32_16x16x32_bf16(af[fi], bfr[fj], acc[fi][fj], 0, 0, 0);
        }
    }
    unsigned short* Om = G2b + (size_t)m * 65536;
    #pragma unroll
    for (int fi = 0; fi < 8; ++fi){
        #pragma unroll
        for (int r = 0; r < 4; ++r){
            int n = wr + fi * 16 + (l >> 4) * 4 + r;
            unsigned short* grow = Om + (size_t)n * 256 + wc + (l & 15);
            #pragma unroll
            for (int fj = 0; fj < 4; ++fj) grow[fj * 16] = f2bf(acc[fi][fj][r]);
        }
    }
}

// ---------------- power iteration on G2 (bf16 LDS, 16 waves) + Rayleigh vs fp32 W
__global__ __launch_bounds__(1024) void kP2(const float* __restrict__ w1, const float* __restrict__ w2,
                                            const unsigned short* __restrict__ G2b, float* __restrict__ inv_s){
    extern __shared__ char smem[];
    unsigned short* Gl = (unsigned short*)smem;            // 65536 ushorts = 131072 B
    float* yred = (float*)(smem + 131072);                 // 4096 floats = 16384 B
    float* xv   = (float*)(smem + 147456);                 // 256 floats
    float* red  = (float*)(smem + 148480);                 // 32 floats
    int m = blockIdx.x, t = threadIdx.x;
    {
        const ushort8* src = (const ushort8*)(G2b + (size_t)m * 65536);
        ushort8* dst = (ushort8*)Gl;
        #pragma unroll
        for (int i = 0; i < 8; ++i) dst[t + i * 1024] = src[t + i * 1024];
    }
    if (t < 256){
        unsigned int h = (unsigned int)t * 2654435761u ^ 0x9e3779b9u;
        h ^= h >> 13; h *= 0x85ebca6bu; h ^= h >> 16;
        xv[t] = 0.5f + (float)(h & 0xffffu) * (1.0f / 65536.0f);
    }
    __syncthreads();
    int rid = t & 63, seg = t >> 6;   // seg 0..15, rows 4rid..4rid+3, j in [16seg,16seg+16)
    int lane = t & 63;
    for (int it = 0; it < 64; ++it){
        float a0 = 0.f, a1 = 0.f, a2 = 0.f, a3 = 0.f;
        #pragma unroll
        for (int jj = 0; jj < 16; ++jj){
            int j = seg * 16 + jj;
            float xb = xv[j];
            uint2 g = *(const uint2*)&Gl[(size_t)j * 256 + 4 * rid];
            a0 += bf2f((unsigned short)(g.x & 0xffffu)) * xb;
            a1 += bf2f((unsigned short)(g.x >> 16)) * xb;
            a2 += bf2f((unsigned short)(g.y & 0xffffu)) * xb;
            a3 += bf2f((unsigned short)(g.y >> 16)) * xb;
        }
        *(float4*)&yred[seg * 256 + 4 * rid] = make_float4(a0, a1, a2, a3);
        __syncthreads();
        float yv = 0.f;
        if (t < 256){
            #pragma unroll
            for (int s = 0; s < 16; ++s) yv += yred[s * 256 + t];
            float ss = yv * yv;
            #pragma unroll
            for (int off = 32; off; off >>= 1) ss += __shfl_xor(ss, off);
            if (lane == 0) red[t >> 6] = ss;
        }
        __syncthreads();
        if (t < 256){
            float ss = red[0] + red[1] + red[2] + red[3];
            xv[t] = yv * rsqrtf(ss);
        }
        __syncthreads();
    }
    const float* W; int K;
    if (m < NFR){ W = w1 + (size_t)m * IND * IND; K = IND; }
    else        { W = w2 + (size_t)(m - NFR) * IND * ONODES; K = ONODES; }
    float zsq = 0.f;
    for (int o = t; o < K; o += 1024){
        float z = 0.f;
        for (int d = 0; d < 256; ++d) z += W[(size_t)d * K + o] * xv[d];
        zsq += z * z;
    }
    #pragma unroll
    for (int off = 32; off; off >>= 1) zsq += __shfl_xor(zsq, off);
    if (lane == 0) red[16 + (t >> 6)] = zsq;
    __syncthreads();
    if (t == 0){
        float rho = 0.f;
        #pragma unroll
        for (int i = 0; i < 16; ++i) rho += red[16 + i];
        float sg = sqrtf(fmaxf(rho, 0.f));
        inv_s[m] = 1.0f / fmaxf(sg, 1e-6f);
    }
}

// ---------------- per-frame MLP, writes node_features transposed [b][node][frame] fp32 + bf16
__global__ __launch_bounds__(256) void kMLP(const float* __restrict__ inp, const float* __restrict__ w1,
                                            const float* __restrict__ b1, const float* __restrict__ w2,
                                            const float* __restrict__ b2, const float* __restrict__ inv_s,
                                            float* __restrict__ nf, unsigned short* __restrict__ nfb){
    int n = blockIdx.x, t = threadIdx.x;
    __shared__ float xl[16][IND];
    __shared__ float hl[16][IND];
    float i1 = inv_s[n], i2 = inv_s[NFR + n];
    for (int i = t; i < 16 * IND; i += 256){
        int b = i >> 8, d = i & 255;
        xl[b][d] = inp[(size_t)b * (NFR * IND) + (size_t)n * IND + d];
    }
    __syncthreads();
    const float* W1 = w1 + (size_t)n * IND * IND;
    float acc[16] = {};
    for (int d = 0; d < IND; ++d){
        float w = W1[(size_t)d * IND + t];
        #pragma unroll
        for (int b = 0; b < 16; ++b) acc[b] += xl[b][d] * w;
    }
    float bb = b1[(size_t)n * IND + t];
    #pragma unroll
    for (int b = 0; b < 16; ++b){
        float h = acc[b] * i1 + bb;
        h = 0.5f * h * (1.0f + erff(h * 0.70710678118654752f));
        hl[b][t] = h;
    }
    __syncthreads();
    const float* W2 = w2 + (size_t)n * IND * ONODES;
    float o0[16] = {}, o1[16] = {};
    for (int d = 0; d < IND; ++d){
        float wa = W2[(size_t)d * ONODES + t];
        float wb = W2[(size_t)d * ONODES + t + 256];
        #pragma unroll
        for (int b = 0; b < 16; ++b){ float h = hl[b][d]; o0[b] += h * wa; o1[b] += h * wb; }
    }
    float bb0 = b2[(size_t)n * ONODES + t], bb1 = b2[(size_t)n * ONODES + t + 256];
    #pragma unroll
    for (int b = 0; b < 16; ++b){
        float r0 = o0[b] * i2 + bb0;
        float r1 = o1[b] * i2 + bb1;
        nf[(size_t)b * (ONODES * NFR) + (size_t)t * NFR + n]         = r0;
        nf[(size_t)b * (ONODES * NFR) + (size_t)(t + 256) * NFR + n] = r1;
        nfb[(size_t)b * (ONODES * NFR) + (size_t)t * NFR + n]         = f2bf(r0);
        nfb[(size_t)b * (ONODES * NFR) + (size_t)(t + 256) * NFR + n] = f2bf(r1);
    }
}

// ---------------- transpose wqk [128][2048] fp32 -> wqkT [2048][128] bf16
__global__ __launch_bounds__(256) void kWT(const float* __restrict__ wqk, unsigned short* __restrict__ wqkT){
    int j = blockIdx.x * 256 + threadIdx.x; // 0..2047
    unsigned short* dst = wqkT + (size_t)j * 128;
    #pragma unroll
    for (int fb = 0; fb < 16; ++fb){
        ushort8 v;
        #pragma unroll
        for (int u = 0; u < 8; ++u) v[u] = f2bf(wqk[(size_t)(fb * 8 + u) * 2048 + j]);
        *(ushort8*)&dst[fb * 8] = v;
    }
}

// ---------------- qk projection via bf16 MFMA, direct-global fragments
// grid: b x 8 rowtiles(64 nodes) x 4 coltiles(512 j); wave w owns cols [jt*512+w*128, +128)
__global__ __launch_bounds__(256) void kQK2(const unsigned short* __restrict__ nfb,
                                            const unsigned short* __restrict__ wqkT,
                                            unsigned short* __restrict__ qb, unsigned short* __restrict__ kb){
    int b = blockIdx.x, rb = blockIdx.y, jt = blockIdx.z;
    int t = threadIdx.x, w = t >> 6, l = t & 63;
    int mrow = l & 15, kq = l >> 4;
    const unsigned short* A = nfb + ((size_t)b * 512 + rb * 64) * 128;
    const unsigned short* B = wqkT + (size_t)(jt * 512 + w * 128) * 128;
    f32x4 acc[4][8];
    #pragma unroll
    for (int fi = 0; fi < 4; ++fi)
        #pragma unroll
        for (int fj = 0; fj < 8; ++fj) acc[fi][fj] = (f32x4){0.f, 0.f, 0.f, 0.f};
    #pragma unroll
    for (int kh = 0; kh < 4; ++kh){
        bf16x8 bfr[8];
        #pragma unroll
        for (int fj = 0; fj < 8; ++fj)
            bfr[fj] = *(const bf16x8*)&B[(size_t)(fj * 16 + mrow) * 128 + kh * 32 + kq * 8];
        #pragma unroll
        for (int fi = 0; fi < 4; ++fi){
            bf16x8 af = *(const bf16x8*)&A[(size_t)(fi * 16 + mrow) * 128 + kh * 32 + kq * 8];
            #pragma unroll
            for (int fj = 0; fj < 8; ++fj)
                acc[fi][fj] = __builtin_amdgcn_mfma_f32_16x16x32_bf16(af, bfr[fj], acc[fi][fj], 0, 0, 0);
        }
    }
    #pragma unroll
    for (int fi = 0; fi < 4; ++fi){
        #pragma unroll
        for (int r = 0; r < 4; ++r){
            int node = rb * 64 + fi * 16 + kq * 4 + r;
            #pragma unroll
            for (int fj = 0; fj < 8; ++fj){
                int j = jt * 512 + w * 128 + fj * 16 + mrow;
                int s = j >> 10, c = (j >> 7) & 7, fc = j & 127;
                unsigned short* dst = (s ? kb : qb) + ((size_t)(b * 8 + c) * 512 + node) * 128 + fc;
                *dst = f2bf(acc[fi][fj][r]);
            }
        }
    }
}

// ---------------- scores (bf16 MFMA, direct-global fragments) + softmax -> attn fp32
// block: 64 rows x 512 cols per (b,c); wave w owns cols [w*128, w*128+128)
__global__ __launch_bounds__(256) void kS2(const unsigned short* __restrict__ qb,
                                           const unsigned short* __restrict__ kb,
                                           float* __restrict__ attn){
    int b = blockIdx.x, c = blockIdx.y, rb = blockIdx.z;
    int t = threadIdx.x, w = t >> 6, l = t & 63;
    int mrow = l & 15, kq = l >> 4;
    size_t bc = (size_t)(b * 8 + c) * 512;
    const unsigned short* Q  = qb + (bc + rb * 64) * 128;
    const unsigned short* Kp = kb + (bc + w * 128) * 128;
    __shared__ float rmax[4][64];
    __shared__ float rsum[4][64];
    f32x4 acc[4][8];
    #pragma unroll
    for (int fi = 0; fi < 4; ++fi)
        #pragma unroll
        for (int fj = 0; fj < 8; ++fj) acc[fi][fj] = (f32x4){0.f, 0.f, 0.f, 0.f};
    #pragma unroll
    for (int kh = 0; kh < 4; ++kh){
        bf16x8 bfr[8];
        #pragma unroll
        for (int fj = 0; fj < 8; ++fj)
            bfr[fj] = *(const bf16x8*)&Kp[(size_t)(fj * 16 + mrow) * 128 + kh * 32 + kq * 8];
        #pragma unroll
        for (int fi = 0; fi < 4; ++fi){
            bf16x8 af = *(const bf16x8*)&Q[(size_t)(fi * 16 + mrow) * 128 + kh * 32 + kq * 8];
            #pragma unroll
            for (int fj = 0; fj < 8; ++fj)
                acc[fi][fj] = __builtin_amdgcn_mfma_f32_16x16x32_bf16(af, bfr[fj], acc[fi][fj], 0, 0, 0);
        }
    }
    // phase 1: per-row max over this wave's 128 cols
    #pragma unroll
    for (int fi = 0; fi < 4; ++fi){
        #pragma unroll
        for (int r = 0; r < 4; ++r){
            float mx = acc[fi][0][r];
            #pragma unroll
            for (int fj = 1; fj < 8; ++fj) mx = fmaxf(mx, acc[fi][fj][r]);
            mx = fmaxf(mx, __shfl_xor(mx, 1));
            mx = fmaxf(mx, __shfl_xor(mx, 2));
            mx = fmaxf(mx, __shfl_xor(mx, 4));
            mx = fmaxf(mx, __shfl_xor(mx, 8));
            if (mrow == 0) rmax[w][fi * 16 + kq * 4 + r] = mx;
        }
    }
    __syncthreads();
    // phase 2: exp + per-row partial sum
    #pragma unroll
    for (int fi = 0; fi < 4; ++fi){
        #pragma unroll
        for (int r = 0; r < 4; ++r){
            int rl = fi * 16 + kq * 4 + r;
            float gm = fmaxf(fmaxf(rmax[0][rl], rmax[1][rl]), fmaxf(rmax[2][rl], rmax[3][rl]));
            float s = 0.f;
            #pragma unroll
            for (int fj = 0; fj < 8; ++fj){
                float p = __expf((acc[fi][fj][r] - gm) * SM_SCALE);
                acc[fi][fj][r] = p;
                s += p;
            }
            s += __shfl_xor(s, 1);
            s += __shfl_xor(s, 2);
            s += __shfl_xor(s, 4);
            s += __shfl_xor(s, 8);
            if (mrow == 0) rsum[w][rl] = s;
        }
    }
    __syncthreads();
    // phase 3: normalize + write
    #pragma unroll
    for (int fi = 0; fi < 4; ++fi){
        #pragma unroll
        for (int r = 0; r < 4; ++r){
            int rl = fi * 16 + kq * 4 + r;
            float inv = 1.0f / (rsum[0][rl] + rsum[1][rl] + rsum[2][rl] + rsum[3][rl]);
            size_t rowb = (bc + rb * 64 + rl) * 512 + w * 128 + mrow;
            #pragma unroll
            for (int fj = 0; fj < 8; ++fj)
                attn[rowb + fj * 16] = acc[fi][fj][r] * inv;
        }
    }
}

// ---------------- fused: channel-sum radix-select top-32 + diag -> mask -> row-normalize -> bf16 NR
// one block per (b,n); 8 channel rows staged in LDS; wave 0 does the select
__global__ __launch_bounds__(256) void kTN(const float* __restrict__ attn, unsigned short* __restrict__ nrb){
    int b = blockIdx.x >> 9, n = blockIdx.x & 511;
    int t = threadIdx.x, w = t >> 6, lane = t & 63;
    __shared__ float al[8][512];
    __shared__ unsigned long long keepm[8];
    float4* alv = (float4*)&al[0][0];
    for (int i = t; i < 1024; i += 256){
        int c = i >> 7, q4 = i & 127;
        alv[i] = *(const float4*)&attn[((size_t)(b * 8 + c) * 512 + n) * 512 + q4 * 4];
    }
    __syncthreads();
    if (w == 0){
        // channel sums: v[j] = sum_c al[c][j*64+lane]; all positive -> uint order == float order
        unsigned int vb[8];
        #pragma unroll
        for (int j = 0; j < 8; ++j){
            float s = 0.f;
            #pragma unroll
            for (int c = 0; c < 8; ++c) s += al[c][j * 64 + lane];
            vb[j] = __float_as_uint(s);
        }
        // radix binary search for the 32nd-largest bit pattern T
        unsigned int T = 0u;
        for (int bit = 31; bit >= 0; --bit){
            unsigned int cand = T | (1u << bit);
            int cnt = 0;
            #pragma unroll
            for (int j = 0; j < 8; ++j) cnt += __popcll(__ballot(vb[j] >= cand));
            if (cnt >= 32) T = cand;
        }
        // keep: all > T, plus smallest-index ties == T up to 32 total
        int cntgt = 0;
        #pragma unroll
        for (int j = 0; j < 8; ++j) cntgt += __popcll(__ballot(vb[j] > T));
        int need = 32 - cntgt;
        unsigned long long lmask = (1ull << lane) - 1ull;
        int run = 0;
        #pragma unroll
        for (int j = 0; j < 8; ++j){
            bool eq = (vb[j] == T);
            unsigned long long eqm = __ballot(eq);
            int rank = run + __popcll(eqm & lmask);
            bool kv = (vb[j] > T) || (eq && rank < need);
            unsigned long long km = __ballot(kv);
            if (lane == 0) keepm[j] = km;
            run += __popcll(eqm);
        }
    }
    __syncthreads();
    // per-wave channels: c = w*2, w*2+1; mask = keepm | diagonal
    #pragma unroll
    for (int cc = 0; cc < 2; ++cc){
        int c = w * 2 + cc;
        float e[8]; float rs = 0.f;
        #pragma unroll
        for (int j = 0; j < 8; ++j){
            float a = al[c][j * 64 + lane];
            bool keep = ((keepm[j] >> lane) & 1ull) || (j * 64 + lane == n);
            e[j] = keep ? a : 0.0f;
            rs += e[j];
        }
        #pragma unroll
        for (int off = 1; off < 64; off <<= 1) rs += __shfl_xor(rs, off);
        float inv = 1.0f / (rs + 1e-6f);
        size_t base = ((size_t)(b * 8 + c) * 512 + n) * 512;
        #pragma unroll
        for (int j = 0; j < 8; ++j) nrb[base + j * 64 + lane] = f2bf(e[j] * inv);
    }
}

// ---------------- column sums of NR (bf16 in, fp32 out)
__global__ __launch_bounds__(1024) void kC(const unsigned short* __restrict__ nrb, float* __restrict__ cs){
    int b = blockIdx.x, c = blockIdx.y, t = threadIdx.x;
    int mm = t & 511, nh = t >> 9;
    const unsigned short* Mp = nrb + (size_t)(b * 8 + c) * 262144;
    float s = 0.f;
    for (int n = nh * 256; n < nh * 256 + 256; ++n) s += bf2f(Mp[(size_t)n * 512 + mm]);
    __shared__ float red[1024];
    red[t] = s;
    __syncthreads();
    if (t < 512) cs[(size_t)(b * 8 + c) * 512 + t] = red[t] + red[t + 512];
}

// ---------------- out = (NR*D^1/2) * (NR*D^1/2)^T per (b,c); D folded into staging
__global__ __launch_bounds__(256) void kF(const unsigned short* __restrict__ S, const float* __restrict__ cs,
                                          float* __restrict__ oe){
    int b = blockIdx.x, c = blockIdx.y, tz = blockIdx.z;
    int nb = (tz >> 2) * 128, mb = (tz & 3) * 128;
    size_t bc = (size_t)(b * 8 + c) * 512;
    const unsigned short* M = S + bc * 512;
    __shared__ unsigned short At[128 * 64];
    __shared__ unsigned short Bt[128 * 64];
    __shared__ float dl[512];
    int t = threadIdx.x;
    for (int i = t; i < 512; i += 256) dl[i] = rsqrtf(cs[bc + i] + 1e-6f);
    int w = t >> 6, l = t & 63;
    int wr = (w >> 1) * 64, wc = (w & 1) * 64;
    f32x4 acc[4][4] = {};
    int srow = t >> 3, sg = t & 7;
    __syncthreads();
    for (int kb = 0; kb < 512; kb += 64){
        __syncthreads();
        float4 d0 = *(const float4*)&dl[kb + sg * 8];
        float4 d1 = *(const float4*)&dl[kb + sg * 8 + 4];
        float dv[8] = {d0.x, d0.y, d0.z, d0.w, d1.x, d1.y, d1.z, d1.w};
        #pragma unroll
        for (int i = 0; i < 4; ++i){
            int row = i * 32 + srow;
            int dstg = sg ^ (row & 7);
            ushort8 va = *(const ushort8*)&M[(size_t)(nb + row) * 512 + kb + sg * 8];
            ushort8 vb = *(const ushort8*)&M[(size_t)(mb + row) * 512 + kb + sg * 8];
            ushort8 wa, wb;
            #pragma unroll
            for (int j = 0; j < 8; ++j){
                wa[j] = f2bf(bf2f(va[j]) * dv[j]);
                wb[j] = f2bf(bf2f(vb[j]) * dv[j]);
            }
            *(ushort8*)&At[row * 64 + dstg * 8] = wa;
            *(ushort8*)&Bt[row * 64 + dstg * 8] = wb;
        }
        __syncthreads();
        #pragma unroll
        for (int kh = 0; kh < 2; ++kh){
            bf16x8 af[4], bfr[4];
            #pragma unroll
            for (int fi = 0; fi < 4; ++fi){
                int row = wr + fi * 16 + (l & 15);
                int g = (kh * 4 + (l >> 4)) ^ (row & 7);
                af[fi] = *(const bf16x8*)&At[row * 64 + g * 8];
            }
            #pragma unroll
            for (int fj = 0; fj < 4; ++fj){
                int row = wc + fj * 16 + (l & 15);
                int g = (kh * 4 + (l >> 4)) ^ (row & 7);
                bfr[fj] = *(const bf16x8*)&Bt[row * 64 + g * 8];
            }
            #pragma unroll
            for (int fi = 0; fi < 4; ++fi)
                #pragma unroll
                for (int fj = 0; fj < 4; ++fj)
                    acc[fi][fj] = __builtin_amdgcn_mfma_f32_16x16x32_bf16(af[fi], bfr[fj], acc[fi][fj], 0, 0, 0);
        }
    }
    #pragma unroll
    for (int fi = 0; fi < 4; ++fi){
        #pragma unroll
        for (int r = 0; r < 4; ++r){
            int n = nb + wr + fi * 16 + (l >> 4) * 4 + r;
            float* orow = oe + (bc + n) * 512 + mb + wc + (l & 15);
            #pragma unroll
            for (int fj = 0; fj < 4; ++fj) orow[fj * 16] = acc[fi][fj][r];
        }
    }
}

extern "C" void kernel_launch(void* const* d_in, const int* in_sizes, int n_in,
                              void* d_out, int out_size, void* d_ws, size_t ws_size,
                              hipStream_t stream) {
    const float* inp = (const float*)d_in[0];
    const float* w1  = (const float*)d_in[1];
    const float* b1  = (const float*)d_in[2];
    const float* w2  = (const float*)d_in[3];
    const float* b2  = (const float*)d_in[4];
    const float* wqk = (const float*)d_in[5];

    float* out_nf   = (float*)d_out;                       // [16][512][128]
    float* out_edge = out_nf + (size_t)16 * 512 * 128;     // [16][8][512][512]

    char* ws = (char*)d_ws;
    float* inv_s = (float*)ws;                             // 256 floats
    // region A (134 MB): q/k bf16 during kQK2/kS2, then reused as bf16 NR
    unsigned short* qb  = (unsigned short*)(ws + 4096);            // [16][8][512][128] bf16
    unsigned short* kbuf = qb + (size_t)16 * 8 * 512 * 128;        // [16][8][512][128] bf16
    unsigned short* nrb = qb;                                       // [16][8][512][512] bf16 (aliases q+k, dead)
    // region B (268 MB): attn fp32; G/G2 alias it (dead before attn written)
    float* attn = (float*)(ws + 4096 + (size_t)134 * 1024 * 1024);
    unsigned short* Gb  = (unsigned short*)attn;
    unsigned short* G2b = Gb + (size_t)256 * 65536;
    float* csum = attn + (size_t)16 * 8 * 512 * 512;       // [16][8][512]
    unsigned short* nfb  = (unsigned short*)(csum + (size_t)16 * 8 * 512);  // [16][512][128] bf16 (2 MB)
    unsigned short* wqkT = nfb + (size_t)16 * 512 * 128;                    // [2048][128] bf16 (0.5 MB)

    kG  <<<256, 512, 0, stream>>>(w1, w2, Gb);
    kG2 <<<256, 512, 0, stream>>>(Gb, G2b);
    kP2 <<<256, 1024, 148608, stream>>>(w1, w2, G2b, inv_s);
    kMLP<<<128, 256, 0, stream>>>(inp, w1, b1, w2, b2, inv_s, out_nf, nfb);
    kWT <<<8, 256, 0, stream>>>(wqk, wqkT);
    kQK2<<<dim3(16, 8, 4), 256, 0, stream>>>(nfb, wqkT, qb, kbuf);
    kS2 <<<dim3(16, 8, 8), 256, 0, stream>>>(qb, kbuf, attn);
    kTN <<<8192, 256, 0, stream>>>(attn, nrb);
    kC  <<<dim3(16, 8), 1024, 0, stream>>>(nrb, csum);
    kF  <<<dim3(16, 8, 16), 256, 0, stream>>>(nrb, csum, out_edge);
}

// Round 7
// 557.820 us; speedup vs baseline: 3.0875x; 1.0077x over previous
//
#include <hip/hip_runtime.h>
#include <hip/hip_bf16.h>
#include <math.h>

#define NFR 128
#define IND 256
#define ONODES 512

static constexpr float SM_SCALE = 0.08838834764831845f; // 128^-0.5

typedef __attribute__((ext_vector_type(8))) short bf16x8;
typedef __attribute__((ext_vector_type(4))) float f32x4;
typedef __attribute__((ext_vector_type(8))) unsigned short ushort8;
typedef __attribute__((ext_vector_type(4))) unsigned short ushort4v;

__device__ __forceinline__ unsigned short f2bf(float f){
    unsigned int b = __float_as_uint(f);
    b = (b + 0x7fffu + ((b >> 16) & 1u)) >> 16;
    return (unsigned short)b;
}
__device__ __forceinline__ float bf2f(unsigned short u){
    return __uint_as_float(((unsigned int)u) << 16);
}

// ---------------- G[m] = W_m * W_m^T (256x256) via bf16 MFMA; bf16 output.
__global__ __launch_bounds__(512) void kG(const float* __restrict__ w1, const float* __restrict__ w2,
                                          unsigned short* __restrict__ Gb){
    int m = blockIdx.x;
    const float* W; int K;
    if (m < NFR){ W = w1 + (size_t)m * IND * IND; K = IND; }
    else        { W = w2 + (size_t)(m - NFR) * IND * ONODES; K = ONODES; }
    __shared__ unsigned short Wt[256 * 64]; // rows x 64 k, bf16, granule-swizzled
    int t = threadIdx.x;
    int w = t >> 6, l = t & 63;
    int wr = (w >> 2) * 128, wc = (w & 3) * 64;
    f32x4 acc[8][4] = {};
    int srow = t >> 3, sg = t & 7;
    for (int kb = 0; kb < K; kb += 64){
        __syncthreads();
        #pragma unroll
        for (int i = 0; i < 4; ++i){
            int row = i * 64 + srow;
            int dstg = sg ^ (row & 7);
            const float* src = &W[(size_t)row * K + kb + sg * 8];
            float4 f0 = *(const float4*)src;
            float4 f1 = *(const float4*)(src + 4);
            ushort8 v;
            v[0] = f2bf(f0.x); v[1] = f2bf(f0.y); v[2] = f2bf(f0.z); v[3] = f2bf(f0.w);
            v[4] = f2bf(f1.x); v[5] = f2bf(f1.y); v[6] = f2bf(f1.z); v[7] = f2bf(f1.w);
            *(ushort8*)&Wt[row * 64 + dstg * 8] = v;
        }
        __syncthreads();
        #pragma unroll
        for (int kh = 0; kh < 2; ++kh){
            bf16x8 af[8], bfr[4];
            #pragma unroll
            for (int fi = 0; fi < 8; ++fi){
                int row = wr + fi * 16 + (l & 15);
                int g = (kh * 4 + (l >> 4)) ^ (row & 7);
                af[fi] = *(const bf16x8*)&Wt[row * 64 + g * 8];
            }
            #pragma unroll
            for (int fj = 0; fj < 4; ++fj){
                int row = wc + fj * 16 + (l & 15);
                int g = (kh * 4 + (l >> 4)) ^ (row & 7);
                bfr[fj] = *(const bf16x8*)&Wt[row * 64 + g * 8];
            }
            #pragma unroll
            for (int fi = 0; fi < 8; ++fi)
                #pragma unroll
                for (int fj = 0; fj < 4; ++fj)
                    acc[fi][fj] = __builtin_amdgcn_mfma_f32_16x16x32_bf16(af[fi], bfr[fj], acc[fi][fj], 0, 0, 0);
        }
    }
    unsigned short* Gm = Gb + (size_t)m * 65536;
    #pragma unroll
    for (int fi = 0; fi < 8; ++fi){
        #pragma unroll
        for (int r = 0; r < 4; ++r){
            int n = wr + fi * 16 + (l >> 4) * 4 + r;
            unsigned short* grow = Gm + (size_t)n * 256 + wc + (l & 15);
            #pragma unroll
            for (int fj = 0; fj < 4; ++fj) grow[fj * 16] = f2bf(acc[fi][fj][r]);
        }
    }
}

// ---------------- power iteration on G via register-resident MFMA (128 iters) + fp32 Rayleigh
// One block (256 thr, 4 waves) per matrix; wave w owns rows [w*64, w*64+64).
// A-fragments (G rows) preloaded ONCE into 128 VGPRs; X (256x16, cols identical) lives in
// XOR-swizzled LDS XT[16][256] (bf16) consumed directly as B-fragments.
__global__ __launch_bounds__(256, 1) void kP3(const float* __restrict__ w1, const float* __restrict__ w2,
                                              const unsigned short* __restrict__ Gb, float* __restrict__ inv_s){
    __shared__ unsigned short XT[16 * 256];
    __shared__ float red[16];
    int m = blockIdx.x, t = threadIdx.x;
    int w = t >> 6, l = t & 63;
    int mrow = l & 15, kq = l >> 4;
    const unsigned short* Gm = Gb + (size_t)m * 65536;
    bf16x8 a[4][8];
    #pragma unroll
    for (int fi = 0; fi < 4; ++fi)
        #pragma unroll
        for (int ks = 0; ks < 8; ++ks)
            a[fi][ks] = *(const bf16x8*)&Gm[(size_t)(w * 64 + fi * 16 + mrow) * 256 + ks * 32 + kq * 8];
    // init X: same hash as prior rounds; all 16 cols identical
    {
        unsigned int h = (unsigned int)t * 2654435761u ^ 0x9e3779b9u;
        h ^= h >> 13; h *= 0x85ebca6bu; h ^= h >> 16;
        unsigned short xb = f2bf(0.5f + (float)(h & 0xffffu) * (1.0f / 65536.0f));
        #pragma unroll
        for (int c = 0; c < 16; ++c)
            XT[c * 256 + (t ^ ((c & 7) << 3))] = xb;
    }
    __syncthreads();
    for (int it = 0; it < 128; ++it){
        bf16x8 bq[8];
        #pragma unroll
        for (int ks = 0; ks < 8; ++ks)
            bq[ks] = *(const bf16x8*)&XT[mrow * 256 + ((ks * 32 + kq * 8) ^ ((mrow & 7) << 3))];
        f32x4 acc[4] = {};
        #pragma unroll
        for (int ks = 0; ks < 8; ++ks)
            #pragma unroll
            for (int fi = 0; fi < 4; ++fi)
                acc[fi] = __builtin_amdgcn_mfma_f32_16x16x32_bf16(a[fi][ks], bq[ks], acc[fi], 0, 0, 0);
        // col-0 norm (held by lanes with mrow==0)
        float ss = 0.f;
        if (mrow == 0){
            #pragma unroll
            for (int fi = 0; fi < 4; ++fi)
                #pragma unroll
                for (int r = 0; r < 4; ++r) ss += acc[fi][r] * acc[fi][r];
        }
        #pragma unroll
        for (int off = 1; off < 64; off <<= 1) ss += __shfl_xor(ss, off);
        if (l == 0) red[w] = ss;
        __syncthreads();               // all XT reads done + red ready
        float rs = rsqrtf(red[0] + red[1] + red[2] + red[3]);
        #pragma unroll
        for (int fi = 0; fi < 4; ++fi){
            int r0 = w * 64 + fi * 16 + kq * 4;
            ushort4v v;
            #pragma unroll
            for (int r = 0; r < 4; ++r) v[r] = f2bf(acc[fi][r] * rs);
            *(ushort4v*)&XT[mrow * 256 + (r0 ^ ((mrow & 7) << 3))] = v;
        }
        __syncthreads();               // new X ready
    }
    // Rayleigh: x = col 0 (unswizzled since (0&7)<<3 == 0); sigma^2 = |W^T x|^2 / |x|^2
    const float* W; int K;
    if (m < NFR){ W = w1 + (size_t)m * IND * IND; K = IND; }
    else        { W = w2 + (size_t)(m - NFR) * IND * ONODES; K = ONODES; }
    float zsq = 0.f;
    for (int o = t; o < K; o += 256){
        float z = 0.f;
        for (int d = 0; d < 256; ++d) z += W[(size_t)d * K + o] * bf2f(XT[d]);
        zsq += z * z;
    }
    #pragma unroll
    for (int off = 1; off < 64; off <<= 1) zsq += __shfl_xor(zsq, off);
    if (l == 0) red[4 + w] = zsq;
    float xd = bf2f(XT[t]);
    float xsq = xd * xd;
    #pragma unroll
    for (int off = 1; off < 64; off <<= 1) xsq += __shfl_xor(xsq, off);
    if (l == 0) red[8 + w] = xsq;
    __syncthreads();
    if (t == 0){
        float num = red[4] + red[5] + red[6] + red[7];
        float den = red[8] + red[9] + red[10] + red[11];
        float sg = sqrtf(fmaxf(num / fmaxf(den, 1e-20f), 0.f));
        inv_s[m] = 1.0f / fmaxf(sg, 1e-6f);
    }
}

// ---------------- per-frame MLP, writes node_features transposed [b][node][frame] fp32 + bf16
__global__ __launch_bounds__(256) void kMLP(const float* __restrict__ inp, const float* __restrict__ w1,
                                            const float* __restrict__ b1, const float* __restrict__ w2,
                                            const float* __restrict__ b2, const float* __restrict__ inv_s,
                                            float* __restrict__ nf, unsigned short* __restrict__ nfb){
    int n = blockIdx.x, t = threadIdx.x;
    __shared__ float xl[16][IND];
    __shared__ float hl[16][IND];
    float i1 = inv_s[n], i2 = inv_s[NFR + n];
    for (int i = t; i < 16 * IND; i += 256){
        int b = i >> 8, d = i & 255;
        xl[b][d] = inp[(size_t)b * (NFR * IND) + (size_t)n * IND + d];
    }
    __syncthreads();
    const float* W1 = w1 + (size_t)n * IND * IND;
    float acc[16] = {};
    for (int d = 0; d < IND; ++d){
        float w = W1[(size_t)d * IND + t];
        #pragma unroll
        for (int b = 0; b < 16; ++b) acc[b] += xl[b][d] * w;
    }
    float bb = b1[(size_t)n * IND + t];
    #pragma unroll
    for (int b = 0; b < 16; ++b){
        float h = acc[b] * i1 + bb;
        h = 0.5f * h * (1.0f + erff(h * 0.70710678118654752f));
        hl[b][t] = h;
    }
    __syncthreads();
    const float* W2 = w2 + (size_t)n * IND * ONODES;
    float o0[16] = {}, o1[16] = {};
    for (int d = 0; d < IND; ++d){
        float wa = W2[(size_t)d * ONODES + t];
        float wb = W2[(size_t)d * ONODES + t + 256];
        #pragma unroll
        for (int b = 0; b < 16; ++b){ float h = hl[b][d]; o0[b] += h * wa; o1[b] += h * wb; }
    }
    float bb0 = b2[(size_t)n * ONODES + t], bb1 = b2[(size_t)n * ONODES + t + 256];
    #pragma unroll
    for (int b = 0; b < 16; ++b){
        float r0 = o0[b] * i2 + bb0;
        float r1 = o1[b] * i2 + bb1;
        nf[(size_t)b * (ONODES * NFR) + (size_t)t * NFR + n]         = r0;
        nf[(size_t)b * (ONODES * NFR) + (size_t)(t + 256) * NFR + n] = r1;
        nfb[(size_t)b * (ONODES * NFR) + (size_t)t * NFR + n]         = f2bf(r0);
        nfb[(size_t)b * (ONODES * NFR) + (size_t)(t + 256) * NFR + n] = f2bf(r1);
    }
}

// ---------------- transpose wqk [128][2048] fp32 -> wqkT [2048][128] bf16
__global__ __launch_bounds__(256) void kWT(const float* __restrict__ wqk, unsigned short* __restrict__ wqkT){
    int j = blockIdx.x * 256 + threadIdx.x; // 0..2047
    unsigned short* dst = wqkT + (size_t)j * 128;
    #pragma unroll
    for (int fb = 0; fb < 16; ++fb){
        ushort8 v;
        #pragma unroll
        for (int u = 0; u < 8; ++u) v[u] = f2bf(wqk[(size_t)(fb * 8 + u) * 2048 + j]);
        *(ushort8*)&dst[fb * 8] = v;
    }
}

// ---------------- qk projection via bf16 MFMA, direct-global fragments
__global__ __launch_bounds__(256) void kQK2(const unsigned short* __restrict__ nfb,
                                            const unsigned short* __restrict__ wqkT,
                                            unsigned short* __restrict__ qb, unsigned short* __restrict__ kb){
    int b = blockIdx.x, rb = blockIdx.y, jt = blockIdx.z;
    int t = threadIdx.x, w = t >> 6, l = t & 63;
    int mrow = l & 15, kq = l >> 4;
    const unsigned short* A = nfb + ((size_t)b * 512 + rb * 64) * 128;
    const unsigned short* B = wqkT + (size_t)(jt * 512 + w * 128) * 128;
    f32x4 acc[4][8];
    #pragma unroll
    for (int fi = 0; fi < 4; ++fi)
        #pragma unroll
        for (int fj = 0; fj < 8; ++fj) acc[fi][fj] = (f32x4){0.f, 0.f, 0.f, 0.f};
    #pragma unroll
    for (int kh = 0; kh < 4; ++kh){
        bf16x8 bfr[8];
        #pragma unroll
        for (int fj = 0; fj < 8; ++fj)
            bfr[fj] = *(const bf16x8*)&B[(size_t)(fj * 16 + mrow) * 128 + kh * 32 + kq * 8];
        #pragma unroll
        for (int fi = 0; fi < 4; ++fi){
            bf16x8 af = *(const bf16x8*)&A[(size_t)(fi * 16 + mrow) * 128 + kh * 32 + kq * 8];
            #pragma unroll
            for (int fj = 0; fj < 8; ++fj)
                acc[fi][fj] = __builtin_amdgcn_mfma_f32_16x16x32_bf16(af, bfr[fj], acc[fi][fj], 0, 0, 0);
        }
    }
    #pragma unroll
    for (int fi = 0; fi < 4; ++fi){
        #pragma unroll
        for (int r = 0; r < 4; ++r){
            int node = rb * 64 + fi * 16 + kq * 4 + r;
            #pragma unroll
            for (int fj = 0; fj < 8; ++fj){
                int j = jt * 512 + w * 128 + fj * 16 + mrow;
                int s = j >> 10, c = (j >> 7) & 7, fc = j & 127;
                unsigned short* dst = (s ? kb : qb) + ((size_t)(b * 8 + c) * 512 + node) * 128 + fc;
                *dst = f2bf(acc[fi][fj][r]);
            }
        }
    }
}

// ---------------- scores (bf16 MFMA, direct-global fragments) + softmax -> attn bf16
__global__ __launch_bounds__(256) void kS2(const unsigned short* __restrict__ qb,
                                           const unsigned short* __restrict__ kb,
                                           unsigned short* __restrict__ attnb){
    int b = blockIdx.x, c = blockIdx.y, rb = blockIdx.z;
    int t = threadIdx.x, w = t >> 6, l = t & 63;
    int mrow = l & 15, kq = l >> 4;
    size_t bc = (size_t)(b * 8 + c) * 512;
    const unsigned short* Q  = qb + (bc + rb * 64) * 128;
    const unsigned short* Kp = kb + (bc + w * 128) * 128;
    __shared__ float rmax[4][64];
    __shared__ float rsum[4][64];
    f32x4 acc[4][8];
    #pragma unroll
    for (int fi = 0; fi < 4; ++fi)
        #pragma unroll
        for (int fj = 0; fj < 8; ++fj) acc[fi][fj] = (f32x4){0.f, 0.f, 0.f, 0.f};
    #pragma unroll
    for (int kh = 0; kh < 4; ++kh){
        bf16x8 bfr[8];
        #pragma unroll
        for (int fj = 0; fj < 8; ++fj)
            bfr[fj] = *(const bf16x8*)&Kp[(size_t)(fj * 16 + mrow) * 128 + kh * 32 + kq * 8];
        #pragma unroll
        for (int fi = 0; fi < 4; ++fi){
            bf16x8 af = *(const bf16x8*)&Q[(size_t)(fi * 16 + mrow) * 128 + kh * 32 + kq * 8];
            #pragma unroll
            for (int fj = 0; fj < 8; ++fj)
                acc[fi][fj] = __builtin_amdgcn_mfma_f32_16x16x32_bf16(af, bfr[fj], acc[fi][fj], 0, 0, 0);
        }
    }
    #pragma unroll
    for (int fi = 0; fi < 4; ++fi){
        #pragma unroll
        for (int r = 0; r < 4; ++r){
            float mx = acc[fi][0][r];
            #pragma unroll
            for (int fj = 1; fj < 8; ++fj) mx = fmaxf(mx, acc[fi][fj][r]);
            mx = fmaxf(mx, __shfl_xor(mx, 1));
            mx = fmaxf(mx, __shfl_xor(mx, 2));
            mx = fmaxf(mx, __shfl_xor(mx, 4));
            mx = fmaxf(mx, __shfl_xor(mx, 8));
            if (mrow == 0) rmax[w][fi * 16 + kq * 4 + r] = mx;
        }
    }
    __syncthreads();
    #pragma unroll
    for (int fi = 0; fi < 4; ++fi){
        #pragma unroll
        for (int r = 0; r < 4; ++r){
            int rl = fi * 16 + kq * 4 + r;
            float gm = fmaxf(fmaxf(rmax[0][rl], rmax[1][rl]), fmaxf(rmax[2][rl], rmax[3][rl]));
            float s = 0.f;
            #pragma unroll
            for (int fj = 0; fj < 8; ++fj){
                float p = __expf((acc[fi][fj][r] - gm) * SM_SCALE);
                acc[fi][fj][r] = p;
                s += p;
            }
            s += __shfl_xor(s, 1);
            s += __shfl_xor(s, 2);
            s += __shfl_xor(s, 4);
            s += __shfl_xor(s, 8);
            if (mrow == 0) rsum[w][rl] = s;
        }
    }
    __syncthreads();
    #pragma unroll
    for (int fi = 0; fi < 4; ++fi){
        #pragma unroll
        for (int r = 0; r < 4; ++r){
            int rl = fi * 16 + kq * 4 + r;
            float inv = 1.0f / (rsum[0][rl] + rsum[1][rl] + rsum[2][rl] + rsum[3][rl]);
            size_t rowb = (bc + rb * 64 + rl) * 512 + w * 128 + mrow;
            #pragma unroll
            for (int fj = 0; fj < 8; ++fj)
                attnb[rowb + fj * 16] = f2bf(acc[fi][fj][r] * inv);
        }
    }
}

// ---------------- fused: channel-sum radix-select top-32 + diag -> mask -> row-normalize -> bf16 NR
__global__ __launch_bounds__(256) void kTN(const unsigned short* __restrict__ attnb, unsigned short* __restrict__ nrb){
    int b = blockIdx.x >> 9, n = blockIdx.x & 511;
    int t = threadIdx.x, w = t >> 6, lane = t & 63;
    __shared__ unsigned short al[8][512];
    __shared__ unsigned long long keepm[8];
    ushort8* alv = (ushort8*)&al[0][0];
    for (int i = t; i < 512; i += 256){
        int c = i >> 6, o = i & 63;
        alv[i] = *(const ushort8*)&attnb[((size_t)(b * 8 + c) * 512 + n) * 512 + o * 8];
    }
    __syncthreads();
    if (w == 0){
        unsigned int vb[8];
        #pragma unroll
        for (int j = 0; j < 8; ++j){
            float s = 0.f;
            #pragma unroll
            for (int c = 0; c < 8; ++c) s += bf2f(al[c][j * 64 + lane]);
            vb[j] = __float_as_uint(s);
        }
        unsigned int T = 0u;
        for (int bit = 31; bit >= 0; --bit){
            unsigned int cand = T | (1u << bit);
            int cnt = 0;
            #pragma unroll
            for (int j = 0; j < 8; ++j) cnt += __popcll(__ballot(vb[j] >= cand));
            if (cnt >= 32) T = cand;
        }
        int cntgt = 0;
        #pragma unroll
        for (int j = 0; j < 8; ++j) cntgt += __popcll(__ballot(vb[j] > T));
        int need = 32 - cntgt;
        unsigned long long lmask = (1ull << lane) - 1ull;
        int run = 0;
        #pragma unroll
        for (int j = 0; j < 8; ++j){
            bool eq = (vb[j] == T);
            unsigned long long eqm = __ballot(eq);
            int rank = run + __popcll(eqm & lmask);
            bool kv = (vb[j] > T) || (eq && rank < need);
            unsigned long long km = __ballot(kv);
            if (lane == 0) keepm[j] = km;
            run += __popcll(eqm);
        }
    }
    __syncthreads();
    #pragma unroll
    for (int cc = 0; cc < 2; ++cc){
        int c = w * 2 + cc;
        float e[8]; float rs = 0.f;
        #pragma unroll
        for (int j = 0; j < 8; ++j){
            float a = bf2f(al[c][j * 64 + lane]);
            bool keep = ((keepm[j] >> lane) & 1ull) || (j * 64 + lane == n);
            e[j] = keep ? a : 0.0f;
            rs += e[j];
        }
        #pragma unroll
        for (int off = 1; off < 64; off <<= 1) rs += __shfl_xor(rs, off);
        float inv = 1.0f / (rs + 1e-6f);
        size_t base = ((size_t)(b * 8 + c) * 512 + n) * 512;
        #pragma unroll
        for (int j = 0; j < 8; ++j) nrb[base + j * 64 + lane] = f2bf(e[j] * inv);
    }
}

// ---------------- column sums of NR (bf16 in, fp32 out)
__global__ __launch_bounds__(1024) void kC(const unsigned short* __restrict__ nrb, float* __restrict__ cs){
    int b = blockIdx.x, c = blockIdx.y, t = threadIdx.x;
    int mm = t & 511, nh = t >> 9;
    const unsigned short* Mp = nrb + (size_t)(b * 8 + c) * 262144;
    float s = 0.f;
    for (int n = nh * 256; n < nh * 256 + 256; ++n) s += bf2f(Mp[(size_t)n * 512 + mm]);
    __shared__ float red[1024];
    red[t] = s;
    __syncthreads();
    if (t < 512) cs[(size_t)(b * 8 + c) * 512 + t] = red[t] + red[t + 512];
}

// ---------------- out = (NR*D^1/2) * (NR*D^1/2)^T per (b,c); D folded into staging
__global__ __launch_bounds__(256) void kF(const unsigned short* __restrict__ S, const float* __restrict__ cs,
                                          float* __restrict__ oe){
    int b = blockIdx.x, c = blockIdx.y, tz = blockIdx.z;
    int nb = (tz >> 2) * 128, mb = (tz & 3) * 128;
    size_t bc = (size_t)(b * 8 + c) * 512;
    const unsigned short* M = S + bc * 512;
    __shared__ unsigned short At[128 * 64];
    __shared__ unsigned short Bt[128 * 64];
    __shared__ float dl[512];
    int t = threadIdx.x;
    for (int i = t; i < 512; i += 256) dl[i] = rsqrtf(cs[bc + i] + 1e-6f);
    int w = t >> 6, l = t & 63;
    int wr = (w >> 1) * 64, wc = (w & 1) * 64;
    f32x4 acc[4][4] = {};
    int srow = t >> 3, sg = t & 7;
    __syncthreads();
    for (int kb = 0; kb < 512; kb += 64){
        __syncthreads();
        float4 d0 = *(const float4*)&dl[kb + sg * 8];
        float4 d1 = *(const float4*)&dl[kb + sg * 8 + 4];
        float dv[8] = {d0.x, d0.y, d0.z, d0.w, d1.x, d1.y, d1.z, d1.w};
        #pragma unroll
        for (int i = 0; i < 4; ++i){
            int row = i * 32 + srow;
            int dstg = sg ^ (row & 7);
            ushort8 va = *(const ushort8*)&M[(size_t)(nb + row) * 512 + kb + sg * 8];
            ushort8 vb = *(const ushort8*)&M[(size_t)(mb + row) * 512 + kb + sg * 8];
            ushort8 wa, wb;
            #pragma unroll
            for (int j = 0; j < 8; ++j){
                wa[j] = f2bf(bf2f(va[j]) * dv[j]);
                wb[j] = f2bf(bf2f(vb[j]) * dv[j]);
            }
            *(ushort8*)&At[row * 64 + dstg * 8] = wa;
            *(ushort8*)&Bt[row * 64 + dstg * 8] = wb;
        }
        __syncthreads();
        #pragma unroll
        for (int kh = 0; kh < 2; ++kh){
            bf16x8 af[4], bfr[4];
            #pragma unroll
            for (int fi = 0; fi < 4; ++fi){
                int row = wr + fi * 16 + (l & 15);
                int g = (kh * 4 + (l >> 4)) ^ (row & 7);
                af[fi] = *(const bf16x8*)&At[row * 64 + g * 8];
            }
            #pragma unroll
            for (int fj = 0; fj < 4; ++fj){
                int row = wc + fj * 16 + (l & 15);
                int g = (kh * 4 + (l >> 4)) ^ (row & 7);
                bfr[fj] = *(const bf16x8*)&Bt[row * 64 + g * 8];
            }
            #pragma unroll
            for (int fi = 0; fi < 4; ++fi)
                #pragma unroll
                for (int fj = 0; fj < 4; ++fj)
                    acc[fi][fj] = __builtin_amdgcn_mfma_f32_16x16x32_bf16(af[fi], bfr[fj], acc[fi][fj], 0, 0, 0);
        }
    }
    #pragma unroll
    for (int fi = 0; fi < 4; ++fi){
        #pragma unroll
        for (int r = 0; r < 4; ++r){
            int n = nb + wr + fi * 16 + (l >> 4) * 4 + r;
            float* orow = oe + (bc + n) * 512 + mb + wc + (l & 15);
            #pragma unroll
            for (int fj = 0; fj < 4; ++fj) orow[fj * 16] = acc[fi][fj][r];
        }
    }
}

extern "C" void kernel_launch(void* const* d_in, const int* in_sizes, int n_in,
                              void* d_out, int out_size, void* d_ws, size_t ws_size,
                              hipStream_t stream) {
    const float* inp = (const float*)d_in[0];
    const float* w1  = (const float*)d_in[1];
    const float* b1  = (const float*)d_in[2];
    const float* w2  = (const float*)d_in[3];
    const float* b2  = (const float*)d_in[4];
    const float* wqk = (const float*)d_in[5];

    float* out_nf   = (float*)d_out;                       // [16][512][128]
    float* out_edge = out_nf + (size_t)16 * 512 * 128;     // [16][8][512][512]

    char* ws = (char*)d_ws;
    float* inv_s = (float*)ws;                             // 256 floats
    // region A (134 MB): q/k bf16 during kQK2/kS2, then reused as bf16 NR
    unsigned short* qb  = (unsigned short*)(ws + 4096);            // [16][8][512][128] bf16
    unsigned short* kbuf = qb + (size_t)16 * 8 * 512 * 128;        // [16][8][512][128] bf16
    unsigned short* nrb = qb;                                       // [16][8][512][512] bf16 (aliases q+k)
    // region B (134 MB): attn bf16; G aliases it (dead before attn written)
    unsigned short* attnb = (unsigned short*)(ws + 4096 + (size_t)134 * 1024 * 1024);
    unsigned short* Gb  = attnb;                                    // [256][256][256] bf16 (33.5 MB)
    float* csum = (float*)(attnb + (size_t)16 * 8 * 512 * 512);    // [16][8][512]
    unsigned short* nfb  = (unsigned short*)(csum + (size_t)16 * 8 * 512);  // [16][512][128] bf16 (2 MB)
    unsigned short* wqkT = nfb + (size_t)16 * 512 * 128;                    // [2048][128] bf16 (0.5 MB)

    kG  <<<256, 512, 0, stream>>>(w1, w2, Gb);
    kP3 <<<256, 256, 0, stream>>>(w1, w2, Gb, inv_s);
    kMLP<<<128, 256, 0, stream>>>(inp, w1, b1, w2, b2, inv_s, out_nf, nfb);
    kWT <<<8, 256, 0, stream>>>(wqk, wqkT);
    kQK2<<<dim3(16, 8, 4), 256, 0, stream>>>(nfb, wqkT, qb, kbuf);
    kS2 <<<dim3(16, 8, 8), 256, 0, stream>>>(qb, kbuf, attnb);
    kTN <<<8192, 256, 0, stream>>>(attnb, nrb);
    kC  <<<dim3(16, 8), 1024, 0, stream>>>(nrb, csum);
    kF  <<<dim3(16, 8, 16), 256, 0, stream>>>(nrb, csum, out_edge);
}

// Round 8
// 538.309 us; speedup vs baseline: 3.1994x; 1.0362x over previous
//
#include <hip/hip_runtime.h>
#include <hip/hip_bf16.h>
#include <math.h>

#define NFR 128
#define IND 256
#define ONODES 512

static constexpr float SM_SCALE = 0.08838834764831845f; // 128^-0.5

typedef __attribute__((ext_vector_type(8))) short bf16x8;
typedef __attribute__((ext_vector_type(4))) float f32x4;
typedef __attribute__((ext_vector_type(8))) unsigned short ushort8;
typedef __attribute__((ext_vector_type(4))) unsigned short ushort4v;

__device__ __forceinline__ unsigned short f2bf(float f){
    unsigned int b = __float_as_uint(f);
    b = (b + 0x7fffu + ((b >> 16) & 1u)) >> 16;
    return (unsigned short)b;
}
__device__ __forceinline__ float bf2f(unsigned short u){
    return __uint_as_float(((unsigned int)u) << 16);
}

// ---------------- G[m] = W_m * W_m^T (256x256) via bf16 MFMA; bf16 output.
__global__ __launch_bounds__(512) void kG(const float* __restrict__ w1, const float* __restrict__ w2,
                                          unsigned short* __restrict__ Gb){
    int m = blockIdx.x;
    const float* W; int K;
    if (m < NFR){ W = w1 + (size_t)m * IND * IND; K = IND; }
    else        { W = w2 + (size_t)(m - NFR) * IND * ONODES; K = ONODES; }
    __shared__ unsigned short Wt[256 * 64]; // rows x 64 k, bf16, granule-swizzled
    int t = threadIdx.x;
    int w = t >> 6, l = t & 63;
    int wr = (w >> 2) * 128, wc = (w & 3) * 64;
    f32x4 acc[8][4] = {};
    int srow = t >> 3, sg = t & 7;
    for (int kb = 0; kb < K; kb += 64){
        __syncthreads();
        #pragma unroll
        for (int i = 0; i < 4; ++i){
            int row = i * 64 + srow;
            int dstg = sg ^ (row & 7);
            const float* src = &W[(size_t)row * K + kb + sg * 8];
            float4 f0 = *(const float4*)src;
            float4 f1 = *(const float4*)(src + 4);
            ushort8 v;
            v[0] = f2bf(f0.x); v[1] = f2bf(f0.y); v[2] = f2bf(f0.z); v[3] = f2bf(f0.w);
            v[4] = f2bf(f1.x); v[5] = f2bf(f1.y); v[6] = f2bf(f1.z); v[7] = f2bf(f1.w);
            *(ushort8*)&Wt[row * 64 + dstg * 8] = v;
        }
        __syncthreads();
        #pragma unroll
        for (int kh = 0; kh < 2; ++kh){
            bf16x8 af[8], bfr[4];
            #pragma unroll
            for (int fi = 0; fi < 8; ++fi){
                int row = wr + fi * 16 + (l & 15);
                int g = (kh * 4 + (l >> 4)) ^ (row & 7);
                af[fi] = *(const bf16x8*)&Wt[row * 64 + g * 8];
            }
            #pragma unroll
            for (int fj = 0; fj < 4; ++fj){
                int row = wc + fj * 16 + (l & 15);
                int g = (kh * 4 + (l >> 4)) ^ (row & 7);
                bfr[fj] = *(const bf16x8*)&Wt[row * 64 + g * 8];
            }
            #pragma unroll
            for (int fi = 0; fi < 8; ++fi)
                #pragma unroll
                for (int fj = 0; fj < 4; ++fj)
                    acc[fi][fj] = __builtin_amdgcn_mfma_f32_16x16x32_bf16(af[fi], bfr[fj], acc[fi][fj], 0, 0, 0);
        }
    }
    unsigned short* Gm = Gb + (size_t)m * 65536;
    #pragma unroll
    for (int fi = 0; fi < 8; ++fi){
        #pragma unroll
        for (int r = 0; r < 4; ++r){
            int n = wr + fi * 16 + (l >> 4) * 4 + r;
            unsigned short* grow = Gm + (size_t)n * 256 + wc + (l & 15);
            #pragma unroll
            for (int fj = 0; fj < 4; ++fj) grow[fj * 16] = f2bf(acc[fi][fj][r]);
        }
    }
}

// ---------------- power iteration on G via register-resident MFMA (128 iters) + fp32 Rayleigh
// One block (512 thr, 8 waves) per matrix; wave w owns rows [w*32, w*32+32).
// A-fragments: a[2][8] = 64 VGPRs per lane, loaded ONCE (fits -> no reload, the R7 failure).
// X (256x16, cols identical) lives in XOR-swizzled LDS XT[16][256] bf16 as B-fragments.
__global__ __launch_bounds__(512, 1) void kP3(const float* __restrict__ w1, const float* __restrict__ w2,
                                              const unsigned short* __restrict__ Gb, float* __restrict__ inv_s){
    __shared__ unsigned short XT[16 * 256];
    __shared__ float red[24];
    int m = blockIdx.x, t = threadIdx.x;
    int w = t >> 6, l = t & 63;
    int mrow = l & 15, kq = l >> 4;
    const unsigned short* Gm = Gb + (size_t)m * 65536;
    bf16x8 a0[8], a1[8];
    #pragma unroll
    for (int ks = 0; ks < 8; ++ks){
        a0[ks] = *(const bf16x8*)&Gm[(size_t)(w * 32 + mrow) * 256 + ks * 32 + kq * 8];
        a1[ks] = *(const bf16x8*)&Gm[(size_t)(w * 32 + 16 + mrow) * 256 + ks * 32 + kq * 8];
    }
    if (t < 256){
        unsigned int h = (unsigned int)t * 2654435761u ^ 0x9e3779b9u;
        h ^= h >> 13; h *= 0x85ebca6bu; h ^= h >> 16;
        unsigned short xb = f2bf(0.5f + (float)(h & 0xffffu) * (1.0f / 65536.0f));
        #pragma unroll
        for (int c = 0; c < 16; ++c)
            XT[c * 256 + (t ^ ((c & 7) << 3))] = xb;
    }
    __syncthreads();
    for (int it = 0; it < 128; ++it){
        bf16x8 bq[8];
        #pragma unroll
        for (int ks = 0; ks < 8; ++ks)
            bq[ks] = *(const bf16x8*)&XT[mrow * 256 + ((ks * 32 + kq * 8) ^ ((mrow & 7) << 3))];
        f32x4 acc0 = {}, acc1 = {};
        #pragma unroll
        for (int ks = 0; ks < 8; ++ks){
            acc0 = __builtin_amdgcn_mfma_f32_16x16x32_bf16(a0[ks], bq[ks], acc0, 0, 0, 0);
            acc1 = __builtin_amdgcn_mfma_f32_16x16x32_bf16(a1[ks], bq[ks], acc1, 0, 0, 0);
        }
        // col-0 norm contribution (held by lanes with mrow==0)
        float ss = 0.f;
        if (mrow == 0){
            #pragma unroll
            for (int r = 0; r < 4; ++r) ss += acc0[r] * acc0[r] + acc1[r] * acc1[r];
        }
        #pragma unroll
        for (int off = 1; off < 64; off <<= 1) ss += __shfl_xor(ss, off);
        if (l == 0) red[w] = ss;
        __syncthreads();               // all XT reads done + red ready
        float rs = rsqrtf(red[0] + red[1] + red[2] + red[3] + red[4] + red[5] + red[6] + red[7]);
        {
            int r0 = w * 32 + kq * 4;
            ushort4v v0, v1;
            #pragma unroll
            for (int r = 0; r < 4; ++r){ v0[r] = f2bf(acc0[r] * rs); v1[r] = f2bf(acc1[r] * rs); }
            *(ushort4v*)&XT[mrow * 256 + (r0 ^ ((mrow & 7) << 3))] = v0;
            *(ushort4v*)&XT[mrow * 256 + ((r0 + 16) ^ ((mrow & 7) << 3))] = v1;
        }
        __syncthreads();               // new X ready
    }
    // Rayleigh: x = col 0 (unswizzled since (0&7)<<3 == 0); sigma^2 = |W^T x|^2 / |x|^2
    const float* W; int K;
    if (m < NFR){ W = w1 + (size_t)m * IND * IND; K = IND; }
    else        { W = w2 + (size_t)(m - NFR) * IND * ONODES; K = ONODES; }
    float zsq = 0.f;
    for (int o = t; o < K; o += 512){
        float z = 0.f;
        for (int d = 0; d < 256; ++d) z += W[(size_t)d * K + o] * bf2f(XT[d]);
        zsq += z * z;
    }
    #pragma unroll
    for (int off = 1; off < 64; off <<= 1) zsq += __shfl_xor(zsq, off);
    if (l == 0) red[8 + w] = zsq;
    float xsq = 0.f;
    if (t < 256){
        float xd = bf2f(XT[t]);
        xsq = xd * xd;
    }
    #pragma unroll
    for (int off = 1; off < 64; off <<= 1) xsq += __shfl_xor(xsq, off);
    if (l == 0) red[16 + w] = xsq;
    __syncthreads();
    if (t == 0){
        float num = 0.f, den = 0.f;
        #pragma unroll
        for (int i = 0; i < 8; ++i){ num += red[8 + i]; den += red[16 + i]; }
        float sg = sqrtf(fmaxf(num / fmaxf(den, 1e-20f), 0.f));
        inv_s[m] = 1.0f / fmaxf(sg, 1e-6f);
    }
}

// ---------------- per-frame MLP, writes node_features transposed [b][node][frame] fp32 + bf16
__global__ __launch_bounds__(256) void kMLP(const float* __restrict__ inp, const float* __restrict__ w1,
                                            const float* __restrict__ b1, const float* __restrict__ w2,
                                            const float* __restrict__ b2, const float* __restrict__ inv_s,
                                            float* __restrict__ nf, unsigned short* __restrict__ nfb){
    int n = blockIdx.x, t = threadIdx.x;
    __shared__ float xl[16][IND];
    __shared__ float hl[16][IND];
    float i1 = inv_s[n], i2 = inv_s[NFR + n];
    for (int i = t; i < 16 * IND; i += 256){
        int b = i >> 8, d = i & 255;
        xl[b][d] = inp[(size_t)b * (NFR * IND) + (size_t)n * IND + d];
    }
    __syncthreads();
    const float* W1 = w1 + (size_t)n * IND * IND;
    float acc[16] = {};
    for (int d = 0; d < IND; ++d){
        float w = W1[(size_t)d * IND + t];
        #pragma unroll
        for (int b = 0; b < 16; ++b) acc[b] += xl[b][d] * w;
    }
    float bb = b1[(size_t)n * IND + t];
    #pragma unroll
    for (int b = 0; b < 16; ++b){
        float h = acc[b] * i1 + bb;
        h = 0.5f * h * (1.0f + erff(h * 0.70710678118654752f));
        hl[b][t] = h;
    }
    __syncthreads();
    const float* W2 = w2 + (size_t)n * IND * ONODES;
    float o0[16] = {}, o1[16] = {};
    for (int d = 0; d < IND; ++d){
        float wa = W2[(size_t)d * ONODES + t];
        float wb = W2[(size_t)d * ONODES + t + 256];
        #pragma unroll
        for (int b = 0; b < 16; ++b){ float h = hl[b][d]; o0[b] += h * wa; o1[b] += h * wb; }
    }
    float bb0 = b2[(size_t)n * ONODES + t], bb1 = b2[(size_t)n * ONODES + t + 256];
    #pragma unroll
    for (int b = 0; b < 16; ++b){
        float r0 = o0[b] * i2 + bb0;
        float r1 = o1[b] * i2 + bb1;
        nf[(size_t)b * (ONODES * NFR) + (size_t)t * NFR + n]         = r0;
        nf[(size_t)b * (ONODES * NFR) + (size_t)(t + 256) * NFR + n] = r1;
        nfb[(size_t)b * (ONODES * NFR) + (size_t)t * NFR + n]         = f2bf(r0);
        nfb[(size_t)b * (ONODES * NFR) + (size_t)(t + 256) * NFR + n] = f2bf(r1);
    }
}

// ---------------- transpose wqk [128][2048] fp32 -> wqkT [2048][128] bf16
__global__ __launch_bounds__(256) void kWT(const float* __restrict__ wqk, unsigned short* __restrict__ wqkT){
    int j = blockIdx.x * 256 + threadIdx.x; // 0..2047
    unsigned short* dst = wqkT + (size_t)j * 128;
    #pragma unroll
    for (int fb = 0; fb < 16; ++fb){
        ushort8 v;
        #pragma unroll
        for (int u = 0; u < 8; ++u) v[u] = f2bf(wqk[(size_t)(fb * 8 + u) * 2048 + j]);
        *(ushort8*)&dst[fb * 8] = v;
    }
}

// ---------------- qk projection via bf16 MFMA, direct-global fragments
__global__ __launch_bounds__(256) void kQK2(const unsigned short* __restrict__ nfb,
                                            const unsigned short* __restrict__ wqkT,
                                            unsigned short* __restrict__ qb, unsigned short* __restrict__ kb){
    int b = blockIdx.x, rb = blockIdx.y, jt = blockIdx.z;
    int t = threadIdx.x, w = t >> 6, l = t & 63;
    int mrow = l & 15, kq = l >> 4;
    const unsigned short* A = nfb + ((size_t)b * 512 + rb * 64) * 128;
    const unsigned short* B = wqkT + (size_t)(jt * 512 + w * 128) * 128;
    f32x4 acc[4][8];
    #pragma unroll
    for (int fi = 0; fi < 4; ++fi)
        #pragma unroll
        for (int fj = 0; fj < 8; ++fj) acc[fi][fj] = (f32x4){0.f, 0.f, 0.f, 0.f};
    #pragma unroll
    for (int kh = 0; kh < 4; ++kh){
        bf16x8 bfr[8];
        #pragma unroll
        for (int fj = 0; fj < 8; ++fj)
            bfr[fj] = *(const bf16x8*)&B[(size_t)(fj * 16 + mrow) * 128 + kh * 32 + kq * 8];
        #pragma unroll
        for (int fi = 0; fi < 4; ++fi){
            bf16x8 af = *(const bf16x8*)&A[(size_t)(fi * 16 + mrow) * 128 + kh * 32 + kq * 8];
            #pragma unroll
            for (int fj = 0; fj < 8; ++fj)
                acc[fi][fj] = __builtin_amdgcn_mfma_f32_16x16x32_bf16(af, bfr[fj], acc[fi][fj], 0, 0, 0);
        }
    }
    #pragma unroll
    for (int fi = 0; fi < 4; ++fi){
        #pragma unroll
        for (int r = 0; r < 4; ++r){
            int node = rb * 64 + fi * 16 + kq * 4 + r;
            #pragma unroll
            for (int fj = 0; fj < 8; ++fj){
                int j = jt * 512 + w * 128 + fj * 16 + mrow;
                int s = j >> 10, c = (j >> 7) & 7, fc = j & 127;
                unsigned short* dst = (s ? kb : qb) + ((size_t)(b * 8 + c) * 512 + node) * 128 + fc;
                *dst = f2bf(acc[fi][fj][r]);
            }
        }
    }
}

// ---------------- scores (bf16 MFMA, direct-global fragments) + softmax -> attn bf16
__global__ __launch_bounds__(256) void kS2(const unsigned short* __restrict__ qb,
                                           const unsigned short* __restrict__ kb,
                                           unsigned short* __restrict__ attnb){
    int b = blockIdx.x, c = blockIdx.y, rb = blockIdx.z;
    int t = threadIdx.x, w = t >> 6, l = t & 63;
    int mrow = l & 15, kq = l >> 4;
    size_t bc = (size_t)(b * 8 + c) * 512;
    const unsigned short* Q  = qb + (bc + rb * 64) * 128;
    const unsigned short* Kp = kb + (bc + w * 128) * 128;
    __shared__ float rmax[4][64];
    __shared__ float rsum[4][64];
    f32x4 acc[4][8];
    #pragma unroll
    for (int fi = 0; fi < 4; ++fi)
        #pragma unroll
        for (int fj = 0; fj < 8; ++fj) acc[fi][fj] = (f32x4){0.f, 0.f, 0.f, 0.f};
    #pragma unroll
    for (int kh = 0; kh < 4; ++kh){
        bf16x8 bfr[8];
        #pragma unroll
        for (int fj = 0; fj < 8; ++fj)
            bfr[fj] = *(const bf16x8*)&Kp[(size_t)(fj * 16 + mrow) * 128 + kh * 32 + kq * 8];
        #pragma unroll
        for (int fi = 0; fi < 4; ++fi){
            bf16x8 af = *(const bf16x8*)&Q[(size_t)(fi * 16 + mrow) * 128 + kh * 32 + kq * 8];
            #pragma unroll
            for (int fj = 0; fj < 8; ++fj)
                acc[fi][fj] = __builtin_amdgcn_mfma_f32_16x16x32_bf16(af, bfr[fj], acc[fi][fj], 0, 0, 0);
        }
    }
    #pragma unroll
    for (int fi = 0; fi < 4; ++fi){
        #pragma unroll
        for (int r = 0; r < 4; ++r){
            float mx = acc[fi][0][r];
            #pragma unroll
            for (int fj = 1; fj < 8; ++fj) mx = fmaxf(mx, acc[fi][fj][r]);
            mx = fmaxf(mx, __shfl_xor(mx, 1));
            mx = fmaxf(mx, __shfl_xor(mx, 2));
            mx = fmaxf(mx, __shfl_xor(mx, 4));
            mx = fmaxf(mx, __shfl_xor(mx, 8));
            if (mrow == 0) rmax[w][fi * 16 + kq * 4 + r] = mx;
        }
    }
    __syncthreads();
    #pragma unroll
    for (int fi = 0; fi < 4; ++fi){
        #pragma unroll
        for (int r = 0; r < 4; ++r){
            int rl = fi * 16 + kq * 4 + r;
            float gm = fmaxf(fmaxf(rmax[0][rl], rmax[1][rl]), fmaxf(rmax[2][rl], rmax[3][rl]));
            float s = 0.f;
            #pragma unroll
            for (int fj = 0; fj < 8; ++fj){
                float p = __expf((acc[fi][fj][r] - gm) * SM_SCALE);
                acc[fi][fj][r] = p;
                s += p;
            }
            s += __shfl_xor(s, 1);
            s += __shfl_xor(s, 2);
            s += __shfl_xor(s, 4);
            s += __shfl_xor(s, 8);
            if (mrow == 0) rsum[w][rl] = s;
        }
    }
    __syncthreads();
    #pragma unroll
    for (int fi = 0; fi < 4; ++fi){
        #pragma unroll
        for (int r = 0; r < 4; ++r){
            int rl = fi * 16 + kq * 4 + r;
            float inv = 1.0f / (rsum[0][rl] + rsum[1][rl] + rsum[2][rl] + rsum[3][rl]);
            size_t rowb = (bc + rb * 64 + rl) * 512 + w * 128 + mrow;
            #pragma unroll
            for (int fj = 0; fj < 8; ++fj)
                attnb[rowb + fj * 16] = f2bf(acc[fi][fj][r] * inv);
        }
    }
}

// ---------------- fused: channel-sum radix-select top-32 + diag -> mask -> row-normalize -> bf16 NR
__global__ __launch_bounds__(256) void kTN(const unsigned short* __restrict__ attnb, unsigned short* __restrict__ nrb){
    int b = blockIdx.x >> 9, n = blockIdx.x & 511;
    int t = threadIdx.x, w = t >> 6, lane = t & 63;
    __shared__ unsigned short al[8][512];
    __shared__ unsigned long long keepm[8];
    ushort8* alv = (ushort8*)&al[0][0];
    for (int i = t; i < 512; i += 256){
        int c = i >> 6, o = i & 63;
        alv[i] = *(const ushort8*)&attnb[((size_t)(b * 8 + c) * 512 + n) * 512 + o * 8];
    }
    __syncthreads();
    if (w == 0){
        unsigned int vb[8];
        #pragma unroll
        for (int j = 0; j < 8; ++j){
            float s = 0.f;
            #pragma unroll
            for (int c = 0; c < 8; ++c) s += bf2f(al[c][j * 64 + lane]);
            vb[j] = __float_as_uint(s);
        }
        unsigned int T = 0u;
        for (int bit = 31; bit >= 0; --bit){
            unsigned int cand = T | (1u << bit);
            int cnt = 0;
            #pragma unroll
            for (int j = 0; j < 8; ++j) cnt += __popcll(__ballot(vb[j] >= cand));
            if (cnt >= 32) T = cand;
        }
        int cntgt = 0;
        #pragma unroll
        for (int j = 0; j < 8; ++j) cntgt += __popcll(__ballot(vb[j] > T));
        int need = 32 - cntgt;
        unsigned long long lmask = (1ull << lane) - 1ull;
        int run = 0;
        #pragma unroll
        for (int j = 0; j < 8; ++j){
            bool eq = (vb[j] == T);
            unsigned long long eqm = __ballot(eq);
            int rank = run + __popcll(eqm & lmask);
            bool kv = (vb[j] > T) || (eq && rank < need);
            unsigned long long km = __ballot(kv);
            if (lane == 0) keepm[j] = km;
            run += __popcll(eqm);
        }
    }
    __syncthreads();
    #pragma unroll
    for (int cc = 0; cc < 2; ++cc){
        int c = w * 2 + cc;
        float e[8]; float rs = 0.f;
        #pragma unroll
        for (int j = 0; j < 8; ++j){
            float a = bf2f(al[c][j * 64 + lane]);
            bool keep = ((keepm[j] >> lane) & 1ull) || (j * 64 + lane == n);
            e[j] = keep ? a : 0.0f;
            rs += e[j];
        }
        #pragma unroll
        for (int off = 1; off < 64; off <<= 1) rs += __shfl_xor(rs, off);
        float inv = 1.0f / (rs + 1e-6f);
        size_t base = ((size_t)(b * 8 + c) * 512 + n) * 512;
        #pragma unroll
        for (int j = 0; j < 8; ++j) nrb[base + j * 64 + lane] = f2bf(e[j] * inv);
    }
}

// ---------------- column sums of NR (bf16 in, fp32 out)
__global__ __launch_bounds__(1024) void kC(const unsigned short* __restrict__ nrb, float* __restrict__ cs){
    int b = blockIdx.x, c = blockIdx.y, t = threadIdx.x;
    int mm = t & 511, nh = t >> 9;
    const unsigned short* Mp = nrb + (size_t)(b * 8 + c) * 262144;
    float s = 0.f;
    for (int n = nh * 256; n < nh * 256 + 256; ++n) s += bf2f(Mp[(size_t)n * 512 + mm]);
    __shared__ float red[1024];
    red[t] = s;
    __syncthreads();
    if (t < 512) cs[(size_t)(b * 8 + c) * 512 + t] = red[t] + red[t + 512];
}

// ---------------- out = (NR*D^1/2) * (NR*D^1/2)^T per (b,c); D folded into staging
__global__ __launch_bounds__(256) void kF(const unsigned short* __restrict__ S, const float* __restrict__ cs,
                                          float* __restrict__ oe){
    int b = blockIdx.x, c = blockIdx.y, tz = blockIdx.z;
    int nb = (tz >> 2) * 128, mb = (tz & 3) * 128;
    size_t bc = (size_t)(b * 8 + c) * 512;
    const unsigned short* M = S + bc * 512;
    __shared__ unsigned short At[128 * 64];
    __shared__ unsigned short Bt[128 * 64];
    __shared__ float dl[512];
    int t = threadIdx.x;
    for (int i = t; i < 512; i += 256) dl[i] = rsqrtf(cs[bc + i] + 1e-6f);
    int w = t >> 6, l = t & 63;
    int wr = (w >> 1) * 64, wc = (w & 1) * 64;
    f32x4 acc[4][4] = {};
    int srow = t >> 3, sg = t & 7;
    __syncthreads();
    for (int kb = 0; kb < 512; kb += 64){
        __syncthreads();
        float4 d0 = *(const float4*)&dl[kb + sg * 8];
        float4 d1 = *(const float4*)&dl[kb + sg * 8 + 4];
        float dv[8] = {d0.x, d0.y, d0.z, d0.w, d1.x, d1.y, d1.z, d1.w};
        #pragma unroll
        for (int i = 0; i < 4; ++i){
            int row = i * 32 + srow;
            int dstg = sg ^ (row & 7);
            ushort8 va = *(const ushort8*)&M[(size_t)(nb + row) * 512 + kb + sg * 8];
            ushort8 vb = *(const ushort8*)&M[(size_t)(mb + row) * 512 + kb + sg * 8];
            ushort8 wa, wb;
            #pragma unroll
            for (int j = 0; j < 8; ++j){
                wa[j] = f2bf(bf2f(va[j]) * dv[j]);
                wb[j] = f2bf(bf2f(vb[j]) * dv[j]);
            }
            *(ushort8*)&At[row * 64 + dstg * 8] = wa;
            *(ushort8*)&Bt[row * 64 + dstg * 8] = wb;
        }
        __syncthreads();
        #pragma unroll
        for (int kh = 0; kh < 2; ++kh){
            bf16x8 af[4], bfr[4];
            #pragma unroll
            for (int fi = 0; fi < 4; ++fi){
                int row = wr + fi * 16 + (l & 15);
                int g = (kh * 4 + (l >> 4)) ^ (row & 7);
                af[fi] = *(const bf16x8*)&At[row * 64 + g * 8];
            }
            #pragma unroll
            for (int fj = 0; fj < 4; ++fj){
                int row = wc + fj * 16 + (l & 15);
                int g = (kh * 4 + (l >> 4)) ^ (row & 7);
                bfr[fj] = *(const bf16x8*)&Bt[row * 64 + g * 8];
            }
            #pragma unroll
            for (int fi = 0; fi < 4; ++fi)
                #pragma unroll
                for (int fj = 0; fj < 4; ++fj)
                    acc[fi][fj] = __builtin_amdgcn_mfma_f32_16x16x32_bf16(af[fi], bfr[fj], acc[fi][fj], 0, 0, 0);
        }
    }
    #pragma unroll
    for (int fi = 0; fi < 4; ++fi){
        #pragma unroll
        for (int r = 0; r < 4; ++r){
            int n = nb + wr + fi * 16 + (l >> 4) * 4 + r;
            float* orow = oe + (bc + n) * 512 + mb + wc + (l & 15);
            #pragma unroll
            for (int fj = 0; fj < 4; ++fj) orow[fj * 16] = acc[fi][fj][r];
        }
    }
}

extern "C" void kernel_launch(void* const* d_in, const int* in_sizes, int n_in,
                              void* d_out, int out_size, void* d_ws, size_t ws_size,
                              hipStream_t stream) {
    const float* inp = (const float*)d_in[0];
    const float* w1  = (const float*)d_in[1];
    const float* b1  = (const float*)d_in[2];
    const float* w2  = (const float*)d_in[3];
    const float* b2  = (const float*)d_in[4];
    const float* wqk = (const float*)d_in[5];

    float* out_nf   = (float*)d_out;                       // [16][512][128]
    float* out_edge = out_nf + (size_t)16 * 512 * 128;     // [16][8][512][512]

    char* ws = (char*)d_ws;
    float* inv_s = (float*)ws;                             // 256 floats
    // region A (134 MB): q/k bf16 during kQK2/kS2, then reused as bf16 NR
    unsigned short* qb  = (unsigned short*)(ws + 4096);            // [16][8][512][128] bf16
    unsigned short* kbuf = qb + (size_t)16 * 8 * 512 * 128;        // [16][8][512][128] bf16
    unsigned short* nrb = qb;                                       // [16][8][512][512] bf16 (aliases q+k)
    // region B (134 MB): attn bf16; G aliases it (dead before attn written)
    unsigned short* attnb = (unsigned short*)(ws + 4096 + (size_t)134 * 1024 * 1024);
    unsigned short* Gb  = attnb;                                    // [256][256][256] bf16 (33.5 MB)
    float* csum = (float*)(attnb + (size_t)16 * 8 * 512 * 512);    // [16][8][512]
    unsigned short* nfb  = (unsigned short*)(csum + (size_t)16 * 8 * 512);  // [16][512][128] bf16 (2 MB)
    unsigned short* wqkT = nfb + (size_t)16 * 512 * 128;                    // [2048][128] bf16 (0.5 MB)

    kG  <<<256, 512, 0, stream>>>(w1, w2, Gb);
    kP3 <<<256, 512, 0, stream>>>(w1, w2, Gb, inv_s);
    kMLP<<<128, 256, 0, stream>>>(inp, w1, b1, w2, b2, inv_s, out_nf, nfb);
    kWT <<<8, 256, 0, stream>>>(wqk, wqkT);
    kQK2<<<dim3(16, 8, 4), 256, 0, stream>>>(nfb, wqkT, qb, kbuf);
    kS2 <<<dim3(16, 8, 8), 256, 0, stream>>>(qb, kbuf, attnb);
    kTN <<<8192, 256, 0, stream>>>(attnb, nrb);
    kC  <<<dim3(16, 8), 1024, 0, stream>>>(nrb, csum);
    kF  <<<dim3(16, 8, 16), 256, 0, stream>>>(nrb, csum, out_edge);
}